// Round 3
// baseline (4253.256 us; speedup 1.0000x reference)
//
#include <hip/hip_runtime.h>
#include <math.h>

#define SELU_SCALE 1.0507009873554805f
#define SELU_ALPHA 1.6732632423543772f

__device__ __forceinline__ float selu_f(float x){
    return x > 0.f ? SELU_SCALE * x : SELU_SCALE * SELU_ALPHA * expm1f(x);
}

__device__ __forceinline__ float warp_sum(float v){
    #pragma unroll
    for(int o=32;o>0;o>>=1) v += __shfl_down(v,o,64);
    return v;
}
__device__ __forceinline__ float warp_max(float v){
    #pragma unroll
    for(int o=32;o>0;o>>=1) v = fmaxf(v,__shfl_down(v,o,64));
    return v;
}

__device__ __forceinline__ void block_sum2(float &a, float &b, float* sred, int nw){
    int lane = threadIdx.x & 63, w = threadIdx.x >> 6;
    a = warp_sum(a); b = warp_sum(b);
    __syncthreads();
    if(lane==0){ sred[w]=a; sred[16+w]=b; }
    __syncthreads();
    if(w==0){
        float x = (lane<nw)? sred[lane] : 0.f;
        float y = (lane<nw)? sred[16+lane] : 0.f;
        x = warp_sum(x); y = warp_sum(y);
        if(lane==0){ sred[0]=x; sred[16]=y; }
    }
    __syncthreads();
    a = sred[0]; b = sred[16];
}

__device__ __forceinline__ float block_max_f(float v, float* sred, int nw){
    int lane = threadIdx.x & 63, w = threadIdx.x >> 6;
    v = warp_max(v);
    __syncthreads();
    if(lane==0) sred[w]=v;
    __syncthreads();
    if(w==0){
        float x = (lane<nw)? sred[lane] : -INFINITY;
        x = warp_max(x);
        if(lane==0) sred[0]=x;
    }
    __syncthreads();
    return sred[0];
}

// ============ Stage 1: conv1(1->32) + SELU + GN(1ch/grp) + maxpool(2,4)
// grid (4 ocq, 1024 s), block 512: tid = oh(2)*256 + yg(4)*64 + x(64).
// thread: 4 oc x 18-row column strip. acc=72 regs.
__global__ __launch_bounds__(512,2) void k_conv1(
    const float* __restrict__ x, const float* __restrict__ w, const float* __restrict__ bias,
    const float* __restrict__ g, const float* __restrict__ be, float* __restrict__ out)
{
    int ocq = blockIdx.x, s = blockIdx.y, tid = threadIdx.x;
    int x_ = tid & 63, yg = (tid >> 6) & 3, oh = tid >> 8;
    int wv_id = tid >> 6;
    __shared__ float sin_[77*68];
    __shared__ float sw[24*8];          // [khw][8oc]
    __shared__ float sred[8][4][2];     // [wave][oc-in-half][sum/sq]
    if(tid < 192){ int khw = tid>>3, o = tid&7; sw[tid] = w[(ocq*8+o)*24 + khw]; }
    for(int i=tid;i<77*68;i+=512) sin_[i]=0.f;
    __syncthreads();
    const float* xs = x + (size_t)s*4608;
    for(int i=tid;i<4608;i+=512){ int r=i>>6, cc=i&63; sin_[(r+2)*68 + (cc+1)] = xs[i]; }
    __syncthreads();

    float acc[4][18];
    #pragma unroll
    for(int o=0;o<4;o++){
        float bb = bias[ocq*8+oh*4+o];
        #pragma unroll
        for(int p=0;p<18;p++) acc[o][p]=bb;
    }
    int y0 = yg*18;
    for(int kw=0;kw<4;kw++){
        float col[23];
        #pragma unroll
        for(int r=0;r<23;r++) col[r] = sin_[(y0+r)*68 + x_ + kw];
        #pragma unroll
        for(int kh=0;kh<6;kh++){
            float4 wa = *(const float4*)(sw + (kh*4+kw)*8 + oh*4);
            float wvv[4] = {wa.x,wa.y,wa.z,wa.w};
            #pragma unroll
            for(int p=0;p<18;p++){
                float v = col[p+kh];
                #pragma unroll
                for(int o=0;o<4;o++) acc[o][p] = fmaf(v, wvv[o], acc[o][p]);
            }
        }
    }
    // SELU + per-oc partial stats (this wave: 18 rows x 64 cols)
    #pragma unroll
    for(int o=0;o<4;o++){
        float a=0.f,b=0.f;
        #pragma unroll
        for(int p=0;p<18;p++){
            float v = selu_f(acc[o][p]); acc[o][p]=v;
            a += v; b += v*v;
        }
        #pragma unroll
        for(int off=1;off<64;off<<=1){ a += __shfl_xor(a,off); b += __shfl_xor(b,off); }
        if(x_==0){ sred[wv_id][o][0]=a; sred[wv_id][o][1]=b; }
    }
    __syncthreads();
    float* o_ = out + ((size_t)s*32 + ocq*8 + oh*4)*576;
    #pragma unroll
    for(int o=0;o<4;o++){
        float ts=0.f, tq=0.f;
        #pragma unroll
        for(int yy=0;yy<4;yy++){ ts += sred[oh*4+yy][o][0]; tq += sred[oh*4+yy][o][1]; }
        float mean = ts*(1.f/4608.f);
        float var  = tq*(1.f/4608.f) - mean*mean;
        float inv  = rsqrtf(var + 1e-5f);
        int oc = ocq*8+oh*4+o;
        float sc = g[oc]*inv, sh = be[oc] - mean*sc;
        #pragma unroll
        for(int p=0;p<18;p++) acc[o][p] = acc[o][p]*sc + sh;
        #pragma unroll
        for(int py=0;py<9;py++){
            float m = fmaxf(acc[o][2*py],acc[o][2*py+1]);
            m = fmaxf(m, __shfl_xor(m,1));
            m = fmaxf(m, __shfl_xor(m,2));
            if((x_&3)==0) o_[o*576 + (yg*9+py)*16 + (x_>>2)] = m;
        }
    }
}

// ============ Stage 2: conv2(32->64) + SELU + GN(2ch/grp) + maxpool(3,4)
// grid (1024 s), block 512: tid = ocsub(8 waves)*64 + yg(4)*16 + x(16).
// thread: 8 oc x 9-row strip. acc=72 regs. wave owns 8 oc + all 576 px.
__global__ __launch_bounds__(512,2) void k_conv2(
    const float* __restrict__ in, const float* __restrict__ w2, const float* __restrict__ bias,
    const float* __restrict__ g, const float* __restrict__ be, float* __restrict__ out)
{
    int s = blockIdx.x, tid = threadIdx.x;
    int x_ = tid & 15, yg = (tid >> 4) & 3, ocsub = tid >> 6;
    __shared__ float sinc[4*820];       // [icl][41*20]
    __shared__ float swc[4*24*64];      // [icl][khw][64oc]
    const float* ibase = in + (size_t)s*18432;
    float acc[8][9];
    #pragma unroll
    for(int o=0;o<8;o++){
        float bb = bias[ocsub*8+o];
        #pragma unroll
        for(int p=0;p<9;p++) acc[o][p]=bb;
    }
    int y0 = yg*9;
    for(int ic0=0; ic0<32; ic0+=4){
        __syncthreads();
        for(int i=tid;i<3280;i+=512){
            int icl = i/820, rem = i - icl*820;
            int r = rem/20, cc = rem - r*20;
            int ir = r-2, icc = cc-1;
            float v = 0.f;
            if(ir>=0 && ir<36 && icc>=0 && icc<16) v = ibase[(ic0+icl)*576 + ir*16 + icc];
            sinc[i]=v;
        }
        for(int i=tid;i<6144;i+=512){
            int icl = i/1536, rem = i - icl*1536;
            int khw = rem>>6, oc = rem&63;
            swc[i] = w2[(size_t)oc*768 + (ic0+icl)*24 + khw];
        }
        __syncthreads();
        for(int icl=0; icl<4; icl++){
            for(int kw=0;kw<4;kw++){
                float col[14];
                #pragma unroll
                for(int r=0;r<14;r++) col[r] = sinc[icl*820 + (y0+r)*20 + x_ + kw];
                #pragma unroll
                for(int kh=0;kh<6;kh++){
                    const float4* wp = (const float4*)(swc + (icl*24 + kh*4+kw)*64 + ocsub*8);
                    float4 wa = wp[0], wb = wp[1];
                    float wvv[8] = {wa.x,wa.y,wa.z,wa.w,wb.x,wb.y,wb.z,wb.w};
                    #pragma unroll
                    for(int p=0;p<9;p++){
                        float v = col[p+kh];
                        #pragma unroll
                        for(int o=0;o<8;o++) acc[o][p] = fmaf(v, wvv[o], acc[o][p]);
                    }
                }
            }
        }
    }
    // SELU + GN stats: group = 2 oc, full wave (4yg x 16x lanes cover 576 px)
    float gs[4], gq[4];
    #pragma unroll
    for(int gl=0; gl<4; gl++){
        float a=0.f,b=0.f;
        #pragma unroll
        for(int oo=0;oo<2;oo++){
            int o = gl*2+oo;
            #pragma unroll
            for(int p=0;p<9;p++){
                float v = selu_f(acc[o][p]); acc[o][p]=v;
                a += v; b += v*v;
            }
        }
        #pragma unroll
        for(int off=1;off<64;off<<=1){ a += __shfl_xor(a,off); b += __shfl_xor(b,off); }
        gs[gl]=a; gq[gl]=b;
    }
    float* ob = out + ((size_t)s*64 + ocsub*8)*48;
    #pragma unroll
    for(int o=0;o<8;o++){
        int gl = o>>1;
        float mean = gs[gl]*(1.f/1152.f);
        float var  = gq[gl]*(1.f/1152.f) - mean*mean;
        float inv  = rsqrtf(var + 1e-5f);
        int oc = ocsub*8+o;
        float sc = g[oc]*inv, sh = be[oc] - mean*sc;
        #pragma unroll
        for(int p=0;p<9;p++) acc[o][p] = acc[o][p]*sc + sh;
        // pool 3x4: 3 rows in-thread, 4 cols across lanes
        #pragma unroll
        for(int py=0;py<3;py++){
            float m = fmaxf(fmaxf(acc[o][3*py],acc[o][3*py+1]),acc[o][3*py+2]);
            m = fmaxf(m, __shfl_xor(m,1));
            m = fmaxf(m, __shfl_xor(m,2));
            if((x_&3)==0) ob[o*48 + (yg*3+py)*4 + (x_>>2)] = m;
        }
    }
}

// ============ Stage 3: conv3(64->128) + SELU + GN(4ch/grp) + maxpool(3,2)
// grid (256 sq of 4 samples), block 512: tid = sL(4)*128 + ocsub(32)*4 + x(4).
// thread: 4 oc x 12 rows x 1 col. acc=48 regs. GN group == ocsub chunk.
__global__ __launch_bounds__(512,2) void k_conv3(
    const float* __restrict__ in, const float* __restrict__ w3, const float* __restrict__ bias,
    const float* __restrict__ g, const float* __restrict__ be, float* __restrict__ e0)
{
    int sq = blockIdx.x, tid = threadIdx.x;
    int x_ = tid & 3, ocsub = (tid >> 2) & 31, sL = tid >> 7;
    __shared__ float sinb[4*64*48];     // [sL][ic][12*4] 49KB
    __shared__ float swc[2*24*128];     // [icl][khw][128oc] 24KB
    for(int i=tid;i<12288;i+=512) sinb[i] = in[(size_t)sq*12288 + i];
    float acc[4][12];
    #pragma unroll
    for(int o=0;o<4;o++){
        float bb = bias[ocsub*4+o];
        #pragma unroll
        for(int p=0;p<12;p++) acc[o][p]=bb;
    }
    const float* sbase = sinb + sL*3072;
    for(int ic0=0; ic0<64; ic0+=2){
        __syncthreads();
        for(int i=tid;i<6144;i+=512){
            int icl = i/3072, rem = i - icl*3072;
            int khw = rem>>7, oc = rem&127;
            swc[i] = w3[(size_t)oc*1536 + (ic0+icl)*24 + khw];
        }
        __syncthreads();
        for(int icl=0; icl<2; icl++){
            const float* ib = sbase + (ic0+icl)*48;
            for(int kw=0;kw<4;kw++){
                int xx = x_ + kw - 1;
                bool xv = (xx>=0 && xx<4);
                float col[17];
                #pragma unroll
                for(int r=0;r<17;r++){
                    int ir = r-2;
                    bool vld = xv && ir>=0 && ir<12;
                    int off = vld ? (ir*4+xx) : 0;
                    float v = ib[off];
                    col[r] = vld ? v : 0.f;
                }
                #pragma unroll
                for(int kh=0;kh<6;kh++){
                    float4 wa = *(const float4*)(swc + (icl*24 + kh*4+kw)*128 + ocsub*4);
                    float wvv[4] = {wa.x,wa.y,wa.z,wa.w};
                    #pragma unroll
                    for(int p=0;p<12;p++){
                        float v = col[p+kh];
                        #pragma unroll
                        for(int o=0;o<4;o++) acc[o][p] = fmaf(v, wvv[o], acc[o][p]);
                    }
                }
            }
        }
    }
    // SELU + GN stats: group = this thread's 4 oc, over 48 px (4 x-lanes)
    float a=0.f,b=0.f;
    #pragma unroll
    for(int o=0;o<4;o++){
        #pragma unroll
        for(int p=0;p<12;p++){
            float v = selu_f(acc[o][p]); acc[o][p]=v;
            a += v; b += v*v;
        }
    }
    a += __shfl_xor(a,1); a += __shfl_xor(a,2);
    b += __shfl_xor(b,1); b += __shfl_xor(b,2);
    float mean = a*(1.f/192.f);
    float var  = b*(1.f/192.f) - mean*mean;
    float inv  = rsqrtf(var + 1e-5f);
    float* eb_ = e0 + (size_t)(sq*4+sL)*1024 + ocsub*4*8;
    #pragma unroll
    for(int o=0;o<4;o++){
        int oc = ocsub*4+o;
        float sc = g[oc]*inv, sh = be[oc] - mean*sc;
        #pragma unroll
        for(int p=0;p<12;p++) acc[o][p] = acc[o][p]*sc + sh;
        // pool 3x2: 3 rows in-thread, 2 cols across lanes
        #pragma unroll
        for(int py=0;py<4;py++){
            float m = fmaxf(fmaxf(acc[o][3*py],acc[o][3*py+1]),acc[o][3*py+2]);
            m = fmaxf(m, __shfl_xor(m,1));
            if((x_&1)==0) eb_[o*8 + py*2 + (x_>>1)] = m;
        }
    }
}

// ---------------- transpose helper: dst[c*R+r] = src[r*C+c]
__global__ void k_transpose(const float* __restrict__ src, float* __restrict__ dst, int R, int C){
    int idx = blockIdx.x*256 + threadIdx.x;
    if(idx < R*C){ int r = idx / C, c = idx % C; dst[c*R + r] = src[idx]; }
}

// ---------------- FC1 + SELU + row l2norm. wt is [1024][128]
__global__ __launch_bounds__(128) void k_fc1(
    const float* __restrict__ e0, const float* __restrict__ wt,
    const float* __restrict__ bias, float* __restrict__ e)
{
    int s = blockIdx.x, j = threadIdx.x;
    __shared__ float se[1024];
    __shared__ float sred[32];
    for(int i=j;i<1024;i+=128) se[i] = e0[(size_t)s*1024+i];
    __syncthreads();
    float acc = bias[j];
    for(int i=0;i<1024;i++) acc += se[i]*wt[i*128+j];
    float v = selu_f(acc);
    float a = v*v, b = 0.f;
    block_sum2(a,b,sred,2);
    float den = fmaxf(sqrtf(a), 1e-12f);
    e[(size_t)s*128+j] = v/den;
}

// ---------------- q,k,v projections + SELU; k gets positional encoding added
__global__ __launch_bounds__(128) void k_qkv(
    const float* __restrict__ e,
    const float* __restrict__ wqt, const float* __restrict__ bq,
    const float* __restrict__ wkt, const float* __restrict__ bk,
    const float* __restrict__ wvt, const float* __restrict__ bv,
    float* __restrict__ q, float* __restrict__ kp, float* __restrict__ v)
{
    int s = blockIdx.x, j = threadIdx.x;
    __shared__ float se[128];
    se[j] = e[(size_t)s*128+j];
    __syncthreads();
    float aq = bq[j], ak = bk[j], av = bv[j];
    for(int i=0;i<128;i++){
        float f = se[i];
        aq += f*wqt[i*128+j];
        ak += f*wkt[i*128+j];
        av += f*wvt[i*128+j];
    }
    aq = selu_f(aq); ak = selu_f(ak); av = selu_f(av);
    int i2 = j & ~1;
    float div = expf(-(float)i2 * 0.07195578412155481f); // ln(10000)/128
    float ang = (float)s * div;
    float pe = (j & 1) ? cosf(ang) : sinf(ang);
    q[(size_t)s*128+j]  = aq;
    kp[(size_t)s*128+j] = ak + pe;
    v[(size_t)s*128+j]  = av;
}

// ---------------- scores + softmax row
__global__ __launch_bounds__(256) void k_attn(
    const float* __restrict__ q, const float* __restrict__ kp, float* __restrict__ attn)
{
    int s = blockIdx.x, tid = threadIdx.x;
    __shared__ float sq_[128];
    __shared__ float sred[32];
    if(tid < 128) sq_[tid] = q[(size_t)s*128+tid];
    __syncthreads();
    float val[4];
    const float4* qr = (const float4*)sq_;
    #pragma unroll
    for(int k2=0;k2<4;k2++){
        int t = tid + k2*256;
        const float4* kr = (const float4*)(kp + (size_t)t*128);
        float acc=0.f;
        #pragma unroll 8
        for(int i=0;i<32;i++){
            float4 a=qr[i], b=kr[i];
            acc += a.x*b.x + a.y*b.y + a.z*b.z + a.w*b.w;
        }
        val[k2] = acc * 0.08838834764831845f; // 1/sqrt(128)
    }
    float m = fmaxf(fmaxf(val[0],val[1]), fmaxf(val[2],val[3]));
    m = block_max_f(m,sred,4);
    float lsum=0.f, dummy=0.f;
    #pragma unroll
    for(int k2=0;k2<4;k2++){ val[k2]=expf(val[k2]-m); lsum+=val[k2]; }
    block_sum2(lsum,dummy,sred,4);
    float invs = 1.f/lsum;
    #pragma unroll
    for(int k2=0;k2<4;k2++) attn[(size_t)s*1024 + tid + k2*256] = val[k2]*invs;
}

// ---------------- av = attn @ v
__global__ __launch_bounds__(128) void k_av(
    const float* __restrict__ attn, const float* __restrict__ v, float* __restrict__ av)
{
    int s = blockIdx.x, j = threadIdx.x;
    __shared__ float sa[1024];
    for(int i=j;i<1024;i+=128) sa[i] = attn[(size_t)s*1024+i];
    __syncthreads();
    float acc=0.f;
    for(int t=0;t<1024;t++) acc += sa[t]*v[t*128+j];
    av[(size_t)s*128+j] = acc;
}

// ---------------- column pipeline: n1 = ||av[:,j]||, out = av/n1 + e, n2, ea = out/n2
__global__ __launch_bounds__(256) void k_colpipe(
    const float* __restrict__ av, const float* __restrict__ e, float* __restrict__ ea)
{
    int j = blockIdx.x, t = threadIdx.x;
    __shared__ float sred[4];
    float v[4];
    float ss = 0.f;
    #pragma unroll
    for(int k=0;k<4;k++){
        v[k] = av[(size_t)(t + 256*k)*128 + j];
        ss += v[k]*v[k];
    }
    #pragma unroll
    for(int off=1;off<64;off<<=1) ss += __shfl_xor(ss,off);
    int lane = t & 63, w = t >> 6;
    if(lane==0) sred[w]=ss;
    __syncthreads();
    float n1 = fmaxf(sqrtf(sred[0]+sred[1]+sred[2]+sred[3]), 1e-12f);
    __syncthreads();
    float ss2 = 0.f;
    #pragma unroll
    for(int k=0;k<4;k++){
        float o = v[k]/n1 + e[(size_t)(t + 256*k)*128 + j];
        v[k] = o;
        ss2 += o*o;
    }
    #pragma unroll
    for(int off=1;off<64;off<<=1) ss2 += __shfl_xor(ss2,off);
    if(lane==0) sred[w]=ss2;
    __syncthreads();
    float n2 = fmaxf(sqrtf(sred[0]+sred[1]+sred[2]+sred[3]), 1e-12f);
    #pragma unroll
    for(int k=0;k<4;k++) ea[(size_t)(t + 256*k)*128 + j] = v[k]/n2;
}

// ---------------- sq[s] = ||ea[s,:]||^2
__global__ __launch_bounds__(128) void k_sq(const float* __restrict__ ea, float* __restrict__ sq){
    int s = blockIdx.x, j = threadIdx.x;
    __shared__ float sred[32];
    float v = ea[(size_t)s*128+j];
    float a=v*v, b=0.f;
    block_sum2(a,b,sred,2);
    if(j==0) sq[s]=a;
}

// ---------------- pairwise d2 + global max(d2) via atomic bits-max
__global__ __launch_bounds__(256) void k_gram(
    const float* __restrict__ ea, const float* __restrict__ sq,
    float* __restrict__ d2, unsigned int* __restrict__ maxbits)
{
    int j0 = blockIdx.x*32, i0 = blockIdx.y*32, tid = threadIdx.x;
    __shared__ float sa[32*128];
    __shared__ float sb[32*128];
    __shared__ float sred[32];
    for(int idx=tid;idx<4096;idx+=256){
        sa[idx] = ea[(size_t)i0*128 + idx];
        sb[idx] = ea[(size_t)j0*128 + idx];
    }
    __syncthreads();
    float lm = 0.f;
    #pragma unroll
    for(int k2=0;k2<4;k2++){
        int p = tid + k2*256;
        int li = p>>5, lj = p&31;
        const float4* A = (const float4*)(sa + li*128);
        const float4* B = (const float4*)(sb + lj*128);
        float acc=0.f;
        #pragma unroll 8
        for(int i=0;i<32;i++){
            float4 a=A[i], b=B[i];
            acc += a.x*b.x + a.y*b.y + a.z*b.z + a.w*b.w;
        }
        float dd = fmaxf(sq[i0+li] + sq[j0+lj] - 2.f*acc, 0.f);
        d2[(size_t)(i0+li)*1024 + j0+lj] = dd;
        lm = fmaxf(lm, dd);
    }
    lm = block_max_f(lm,sred,4);
    if(tid==0) atomicMax(maxbits, __float_as_uint(lm));
}

// ---------------- out = 1 - sqrt(d2+eps)/maxd
__global__ __launch_bounds__(256) void k_final(
    const float* __restrict__ d2, const unsigned int* __restrict__ maxbits, float* __restrict__ out)
{
    int idx = blockIdx.x*256 + threadIdx.x;
    float md = sqrtf(__uint_as_float(*maxbits) + 1e-12f);
    out[idx] = 1.f - sqrtf(d2[idx] + 1e-12f)/md;
}

extern "C" void kernel_launch(void* const* d_in, const int* in_sizes, int n_in,
                              void* d_out, int out_size, void* d_ws, size_t ws_size,
                              hipStream_t stream)
{
    const float* x   = (const float*)d_in[0];
    const float* c1w = (const float*)d_in[1];  const float* c1b = (const float*)d_in[2];
    const float* g1g = (const float*)d_in[3];  const float* g1b = (const float*)d_in[4];
    const float* c2w = (const float*)d_in[5];  const float* c2b = (const float*)d_in[6];
    const float* g2g = (const float*)d_in[7];  const float* g2b = (const float*)d_in[8];
    const float* c3w = (const float*)d_in[9];  const float* c3b = (const float*)d_in[10];
    const float* g3g = (const float*)d_in[11]; const float* g3b = (const float*)d_in[12];
    const float* f1w = (const float*)d_in[13]; const float* f1b = (const float*)d_in[14];
    const float* wq  = (const float*)d_in[15]; const float* bq  = (const float*)d_in[16];
    const float* wk  = (const float*)d_in[17]; const float* bk  = (const float*)d_in[18];
    const float* wv  = (const float*)d_in[19]; const float* bv  = (const float*)d_in[20];

    float* W = (float*)d_ws;
    float* e0   = W;                 // 1,048,576
    float* attn = W + 1048576;       // 1,048,576
    float* avb  = W + 2097152;       //   131,072
    float* eab  = W + 2228224;       //   131,072
    float* d2b  = W + 2359296;       // 1,048,576
    float* buf1 = W;                 // stage1 out (dead before e0 written)
    float* buf2 = W + 18874368;      // stage2 out
    float* wt   = W + 22020096;
    float* wqt  = W + 22151168;
    float* wkt  = W + 22167552;
    float* wvt  = W + 22183936;
    float* eb   = W + 22200320;
    float* qb   = W + 22331392;
    float* kpb  = W + 22462464;
    float* vb   = W + 22593536;
    float* sqb  = W + 22724608;
    unsigned int* maxb = (unsigned int*)(W + 22725632);

    k_transpose<<<512,256,0,stream>>>(f1w, wt, 128, 1024);
    k_transpose<<<64,256,0,stream>>>(wq, wqt, 128, 128);
    k_transpose<<<64,256,0,stream>>>(wk, wkt, 128, 128);
    k_transpose<<<64,256,0,stream>>>(wv, wvt, 128, 128);

    k_conv1<<<dim3(4,1024),512,0,stream>>>(x,   c1w,c1b,g1g,g1b, buf1);
    k_conv2<<<1024,512,0,stream>>>(buf1,c2w,c2b,g2g,g2b, buf2);
    k_conv3<<<256,512,0,stream>>>(buf2,c3w,c3b,g3g,g3b, e0);

    k_fc1<<<1024,128,0,stream>>>(e0, wt, f1b, eb);
    k_qkv<<<1024,128,0,stream>>>(eb, wqt,bq, wkt,bk, wvt,bv, qb,kpb,vb);
    k_attn<<<1024,256,0,stream>>>(qb, kpb, attn);
    k_av<<<1024,128,0,stream>>>(attn, vb, avb);

    hipMemsetAsync(maxb, 0, 4, stream);
    k_colpipe<<<128,256,0,stream>>>(avb, eb, eab);
    k_sq<<<1024,128,0,stream>>>(eab, sqb);
    k_gram<<<dim3(32,32),256,0,stream>>>(eab, sqb, d2b, maxb);
    k_final<<<4096,256,0,stream>>>(d2b, maxb, (float*)d_out);
}

// Round 4
// 1676.080 us; speedup vs baseline: 2.5376x; 2.5376x over previous
//
#include <hip/hip_runtime.h>
#include <math.h>

#define SELU_SCALE 1.0507009873554805f
#define SELU_ALPHA 1.6732632423543772f

__device__ __forceinline__ float selu_f(float x){
    return x > 0.f ? SELU_SCALE * x : SELU_SCALE * SELU_ALPHA * expm1f(x);
}

__device__ __forceinline__ float warp_sum(float v){
    #pragma unroll
    for(int o=32;o>0;o>>=1) v += __shfl_down(v,o,64);
    return v;
}
__device__ __forceinline__ float warp_max(float v){
    #pragma unroll
    for(int o=32;o>0;o>>=1) v = fmaxf(v,__shfl_down(v,o,64));
    return v;
}

__device__ __forceinline__ void block_sum2(float &a, float &b, float* sred, int nw){
    int lane = threadIdx.x & 63, w = threadIdx.x >> 6;
    a = warp_sum(a); b = warp_sum(b);
    __syncthreads();
    if(lane==0){ sred[w]=a; sred[16+w]=b; }
    __syncthreads();
    if(w==0){
        float x = (lane<nw)? sred[lane] : 0.f;
        float y = (lane<nw)? sred[16+lane] : 0.f;
        x = warp_sum(x); y = warp_sum(y);
        if(lane==0){ sred[0]=x; sred[16]=y; }
    }
    __syncthreads();
    a = sred[0]; b = sred[16];
}

__device__ __forceinline__ float block_max_f(float v, float* sred, int nw){
    int lane = threadIdx.x & 63, w = threadIdx.x >> 6;
    v = warp_max(v);
    __syncthreads();
    if(lane==0) sred[w]=v;
    __syncthreads();
    if(w==0){
        float x = (lane<nw)? sred[lane] : -INFINITY;
        x = warp_max(x);
        if(lane==0) sred[0]=x;
    }
    __syncthreads();
    return sred[0];
}

// ============ Stage 1: conv1(1->32) + SELU + GN(1ch/grp) + maxpool(2,4)
// grid (4 ocq, 1024 s), block 512: tid = oh(2)*256 + yg(4)*64 + x(64).
// thread: 4 oc x 18-row column strip. acc=72 regs.
// NOTE: #pragma unroll 1 on the kw loop is load-bearing: full unroll keeps
// 4x col[23] live -> ~170 VGPR live -> spill (3 GB scratch traffic, round 3).
__global__ __launch_bounds__(512,2) void k_conv1(
    const float* __restrict__ x, const float* __restrict__ w, const float* __restrict__ bias,
    const float* __restrict__ g, const float* __restrict__ be, float* __restrict__ out)
{
    int ocq = blockIdx.x, s = blockIdx.y, tid = threadIdx.x;
    int x_ = tid & 63, yg = (tid >> 6) & 3, oh = tid >> 8;
    int wv_id = tid >> 6;
    __shared__ float sin_[77*68];
    __shared__ float sw[24*8];          // [khw][8oc]
    __shared__ float sred[8][4][2];     // [wave][oc-in-half][sum/sq]
    if(tid < 192){ int khw = tid>>3, o = tid&7; sw[tid] = w[(ocq*8+o)*24 + khw]; }
    for(int i=tid;i<77*68;i+=512) sin_[i]=0.f;
    __syncthreads();
    const float* xs = x + (size_t)s*4608;
    for(int i=tid;i<4608;i+=512){ int r=i>>6, cc=i&63; sin_[(r+2)*68 + (cc+1)] = xs[i]; }
    __syncthreads();

    float acc[4][18];
    #pragma unroll
    for(int o=0;o<4;o++){
        float bb = bias[ocq*8+oh*4+o];
        #pragma unroll
        for(int p=0;p<18;p++) acc[o][p]=bb;
    }
    int y0 = yg*18;
    #pragma unroll 1
    for(int kw=0;kw<4;kw++){
        float col[23];
        #pragma unroll
        for(int r=0;r<23;r++) col[r] = sin_[(y0+r)*68 + x_ + kw];
        #pragma unroll
        for(int kh=0;kh<6;kh++){
            float4 wa = *(const float4*)(sw + (kh*4+kw)*8 + oh*4);
            float wvv[4] = {wa.x,wa.y,wa.z,wa.w};
            #pragma unroll
            for(int p=0;p<18;p++){
                float v = col[p+kh];
                #pragma unroll
                for(int o=0;o<4;o++) acc[o][p] = fmaf(v, wvv[o], acc[o][p]);
            }
        }
    }
    // SELU + per-oc partial stats (this wave: 18 rows x 64 cols)
    #pragma unroll
    for(int o=0;o<4;o++){
        float a=0.f,b=0.f;
        #pragma unroll
        for(int p=0;p<18;p++){
            float v = selu_f(acc[o][p]); acc[o][p]=v;
            a += v; b += v*v;
        }
        #pragma unroll
        for(int off=1;off<64;off<<=1){ a += __shfl_xor(a,off); b += __shfl_xor(b,off); }
        if(x_==0){ sred[wv_id][o][0]=a; sred[wv_id][o][1]=b; }
    }
    __syncthreads();
    float* o_ = out + ((size_t)s*32 + ocq*8 + oh*4)*576;
    #pragma unroll
    for(int o=0;o<4;o++){
        float ts=0.f, tq=0.f;
        #pragma unroll
        for(int yy=0;yy<4;yy++){ ts += sred[oh*4+yy][o][0]; tq += sred[oh*4+yy][o][1]; }
        float mean = ts*(1.f/4608.f);
        float var  = tq*(1.f/4608.f) - mean*mean;
        float inv  = rsqrtf(var + 1e-5f);
        int oc = ocq*8+oh*4+o;
        float sc = g[oc]*inv, sh = be[oc] - mean*sc;
        #pragma unroll
        for(int p=0;p<18;p++) acc[o][p] = acc[o][p]*sc + sh;
        #pragma unroll
        for(int py=0;py<9;py++){
            float m = fmaxf(acc[o][2*py],acc[o][2*py+1]);
            m = fmaxf(m, __shfl_xor(m,1));
            m = fmaxf(m, __shfl_xor(m,2));
            if((x_&3)==0) o_[o*576 + (yg*9+py)*16 + (x_>>2)] = m;
        }
    }
}

// ============ Stage 2: conv2(32->64) + SELU + GN(2ch/grp) + maxpool(3,4)
// grid (1024 s), block 512: tid = ocsub(8 waves)*64 + yg(4)*16 + x(16).
// thread: 8 oc x 9-row strip. acc=72 regs. wave owns 8 oc + all 576 px.
__global__ __launch_bounds__(512,2) void k_conv2(
    const float* __restrict__ in, const float* __restrict__ w2, const float* __restrict__ bias,
    const float* __restrict__ g, const float* __restrict__ be, float* __restrict__ out)
{
    int s = blockIdx.x, tid = threadIdx.x;
    int x_ = tid & 15, yg = (tid >> 4) & 3, ocsub = tid >> 6;
    __shared__ float sinc[4*820];       // [icl][41*20]
    __shared__ float swc[4*24*64];      // [icl][khw][64oc]
    const float* ibase = in + (size_t)s*18432;
    float acc[8][9];
    #pragma unroll
    for(int o=0;o<8;o++){
        float bb = bias[ocsub*8+o];
        #pragma unroll
        for(int p=0;p<9;p++) acc[o][p]=bb;
    }
    int y0 = yg*9;
    for(int ic0=0; ic0<32; ic0+=4){
        __syncthreads();
        for(int i=tid;i<3280;i+=512){
            int icl = i/820, rem = i - icl*820;
            int r = rem/20, cc = rem - r*20;
            int ir = r-2, icc = cc-1;
            float v = 0.f;
            if(ir>=0 && ir<36 && icc>=0 && icc<16) v = ibase[(ic0+icl)*576 + ir*16 + icc];
            sinc[i]=v;
        }
        for(int i=tid;i<6144;i+=512){
            int icl = i/1536, rem = i - icl*1536;
            int khw = rem>>6, oc = rem&63;
            swc[i] = w2[(size_t)oc*768 + (ic0+icl)*24 + khw];
        }
        __syncthreads();
        for(int icl=0; icl<4; icl++){
            for(int kw=0;kw<4;kw++){
                float col[14];
                #pragma unroll
                for(int r=0;r<14;r++) col[r] = sinc[icl*820 + (y0+r)*20 + x_ + kw];
                #pragma unroll
                for(int kh=0;kh<6;kh++){
                    const float4* wp = (const float4*)(swc + (icl*24 + kh*4+kw)*64 + ocsub*8);
                    float4 wa = wp[0], wb = wp[1];
                    float wvv[8] = {wa.x,wa.y,wa.z,wa.w,wb.x,wb.y,wb.z,wb.w};
                    #pragma unroll
                    for(int p=0;p<9;p++){
                        float v = col[p+kh];
                        #pragma unroll
                        for(int o=0;o<8;o++) acc[o][p] = fmaf(v, wvv[o], acc[o][p]);
                    }
                }
            }
        }
    }
    // SELU + GN stats: group = 2 oc, full wave (4yg x 16x lanes cover 576 px)
    float gs[4], gq[4];
    #pragma unroll
    for(int gl=0; gl<4; gl++){
        float a=0.f,b=0.f;
        #pragma unroll
        for(int oo=0;oo<2;oo++){
            int o = gl*2+oo;
            #pragma unroll
            for(int p=0;p<9;p++){
                float v = selu_f(acc[o][p]); acc[o][p]=v;
                a += v; b += v*v;
            }
        }
        #pragma unroll
        for(int off=1;off<32;off<<=1){ a += __shfl_xor(a,off); b += __shfl_xor(b,off); }
        a += __shfl_xor(a,32); b += __shfl_xor(b,32);
        gs[gl]=a; gq[gl]=b;
    }
    float* ob = out + ((size_t)s*64 + ocsub*8)*48;
    #pragma unroll
    for(int o=0;o<8;o++){
        int gl = o>>1;
        float mean = gs[gl]*(1.f/1152.f);
        float var  = gq[gl]*(1.f/1152.f) - mean*mean;
        float inv  = rsqrtf(var + 1e-5f);
        int oc = ocsub*8+o;
        float sc = g[oc]*inv, sh = be[oc] - mean*sc;
        #pragma unroll
        for(int p=0;p<9;p++) acc[o][p] = acc[o][p]*sc + sh;
        // pool 3x4: 3 rows in-thread, 4 cols across lanes
        #pragma unroll
        for(int py=0;py<3;py++){
            float m = fmaxf(fmaxf(acc[o][3*py],acc[o][3*py+1]),acc[o][3*py+2]);
            m = fmaxf(m, __shfl_xor(m,1));
            m = fmaxf(m, __shfl_xor(m,2));
            if((x_&3)==0) ob[o*48 + (yg*3+py)*4 + (x_>>2)] = m;
        }
    }
}

// ============ Stage 3: conv3(64->128) + SELU + GN(4ch/grp) + maxpool(3,2)
// grid (256 sq of 4 samples), block 512: tid = sL(4)*128 + ocsub(32)*4 + x(4).
// thread: 4 oc x 12 rows x 1 col. acc=48 regs. GN group == ocsub chunk.
__global__ __launch_bounds__(512,2) void k_conv3(
    const float* __restrict__ in, const float* __restrict__ w3, const float* __restrict__ bias,
    const float* __restrict__ g, const float* __restrict__ be, float* __restrict__ e0)
{
    int sq = blockIdx.x, tid = threadIdx.x;
    int x_ = tid & 3, ocsub = (tid >> 2) & 31, sL = tid >> 7;
    __shared__ float sinb[4*64*48];     // [sL][ic][12*4] 49KB
    __shared__ float swc[2*24*128];     // [icl][khw][128oc] 24KB
    for(int i=tid;i<12288;i+=512) sinb[i] = in[(size_t)sq*12288 + i];
    float acc[4][12];
    #pragma unroll
    for(int o=0;o<4;o++){
        float bb = bias[ocsub*4+o];
        #pragma unroll
        for(int p=0;p<12;p++) acc[o][p]=bb;
    }
    const float* sbase = sinb + sL*3072;
    for(int ic0=0; ic0<64; ic0+=2){
        __syncthreads();
        for(int i=tid;i<6144;i+=512){
            int icl = i/3072, rem = i - icl*3072;
            int khw = rem>>7, oc = rem&127;
            swc[i] = w3[(size_t)oc*1536 + (ic0+icl)*24 + khw];
        }
        __syncthreads();
        for(int icl=0; icl<2; icl++){
            const float* ib = sbase + (ic0+icl)*48;
            for(int kw=0;kw<4;kw++){
                int xx = x_ + kw - 1;
                bool xv = (xx>=0 && xx<4);
                float col[17];
                #pragma unroll
                for(int r=0;r<17;r++){
                    int ir = r-2;
                    bool vld = xv && ir>=0 && ir<12;
                    int off = vld ? (ir*4+xx) : 0;
                    float v = ib[off];
                    col[r] = vld ? v : 0.f;
                }
                #pragma unroll
                for(int kh=0;kh<6;kh++){
                    float4 wa = *(const float4*)(swc + (icl*24 + kh*4+kw)*128 + ocsub*4);
                    float wvv[4] = {wa.x,wa.y,wa.z,wa.w};
                    #pragma unroll
                    for(int p=0;p<12;p++){
                        float v = col[p+kh];
                        #pragma unroll
                        for(int o=0;o<4;o++) acc[o][p] = fmaf(v, wvv[o], acc[o][p]);
                    }
                }
            }
        }
    }
    // SELU + GN stats: group = this thread's 4 oc, over 48 px (4 x-lanes)
    float a=0.f,b=0.f;
    #pragma unroll
    for(int o=0;o<4;o++){
        #pragma unroll
        for(int p=0;p<12;p++){
            float v = selu_f(acc[o][p]); acc[o][p]=v;
            a += v; b += v*v;
        }
    }
    a += __shfl_xor(a,1); a += __shfl_xor(a,2);
    b += __shfl_xor(b,1); b += __shfl_xor(b,2);
    float mean = a*(1.f/192.f);
    float var  = b*(1.f/192.f) - mean*mean;
    float inv  = rsqrtf(var + 1e-5f);
    float* eb_ = e0 + (size_t)(sq*4+sL)*1024 + ocsub*4*8;
    #pragma unroll
    for(int o=0;o<4;o++){
        int oc = ocsub*4+o;
        float sc = g[oc]*inv, sh = be[oc] - mean*sc;
        #pragma unroll
        for(int p=0;p<12;p++) acc[o][p] = acc[o][p]*sc + sh;
        // pool 3x2: 3 rows in-thread, 2 cols across lanes
        #pragma unroll
        for(int py=0;py<4;py++){
            float m = fmaxf(fmaxf(acc[o][3*py],acc[o][3*py+1]),acc[o][3*py+2]);
            m = fmaxf(m, __shfl_xor(m,1));
            if((x_&1)==0) eb_[o*8 + py*2 + (x_>>1)] = m;
        }
    }
}

// ---------------- transpose helper: dst[c*R+r] = src[r*C+c]
__global__ void k_transpose(const float* __restrict__ src, float* __restrict__ dst, int R, int C){
    int idx = blockIdx.x*256 + threadIdx.x;
    if(idx < R*C){ int r = idx / C, c = idx % C; dst[c*R + r] = src[idx]; }
}

// ---------------- FC1 + SELU + row l2norm. wt is [1024][128]
__global__ __launch_bounds__(128) void k_fc1(
    const float* __restrict__ e0, const float* __restrict__ wt,
    const float* __restrict__ bias, float* __restrict__ e)
{
    int s = blockIdx.x, j = threadIdx.x;
    __shared__ float se[1024];
    __shared__ float sred[32];
    for(int i=j;i<1024;i+=128) se[i] = e0[(size_t)s*1024+i];
    __syncthreads();
    float acc = bias[j];
    for(int i=0;i<1024;i++) acc += se[i]*wt[i*128+j];
    float v = selu_f(acc);
    float a = v*v, b = 0.f;
    block_sum2(a,b,sred,2);
    float den = fmaxf(sqrtf(a), 1e-12f);
    e[(size_t)s*128+j] = v/den;
}

// ---------------- q,k,v projections + SELU; k gets positional encoding added
__global__ __launch_bounds__(128) void k_qkv(
    const float* __restrict__ e,
    const float* __restrict__ wqt, const float* __restrict__ bq,
    const float* __restrict__ wkt, const float* __restrict__ bk,
    const float* __restrict__ wvt, const float* __restrict__ bv,
    float* __restrict__ q, float* __restrict__ kp, float* __restrict__ v)
{
    int s = blockIdx.x, j = threadIdx.x;
    __shared__ float se[128];
    se[j] = e[(size_t)s*128+j];
    __syncthreads();
    float aq = bq[j], ak = bk[j], av = bv[j];
    for(int i=0;i<128;i++){
        float f = se[i];
        aq += f*wqt[i*128+j];
        ak += f*wkt[i*128+j];
        av += f*wvt[i*128+j];
    }
    aq = selu_f(aq); ak = selu_f(ak); av = selu_f(av);
    int i2 = j & ~1;
    float div = expf(-(float)i2 * 0.07195578412155481f); // ln(10000)/128
    float ang = (float)s * div;
    float pe = (j & 1) ? cosf(ang) : sinf(ang);
    q[(size_t)s*128+j]  = aq;
    kp[(size_t)s*128+j] = ak + pe;
    v[(size_t)s*128+j]  = av;
}

// ---------------- scores + softmax row
__global__ __launch_bounds__(256) void k_attn(
    const float* __restrict__ q, const float* __restrict__ kp, float* __restrict__ attn)
{
    int s = blockIdx.x, tid = threadIdx.x;
    __shared__ float sq_[128];
    __shared__ float sred[32];
    if(tid < 128) sq_[tid] = q[(size_t)s*128+tid];
    __syncthreads();
    float val[4];
    const float4* qr = (const float4*)sq_;
    #pragma unroll
    for(int k2=0;k2<4;k2++){
        int t = tid + k2*256;
        const float4* kr = (const float4*)(kp + (size_t)t*128);
        float acc=0.f;
        #pragma unroll 8
        for(int i=0;i<32;i++){
            float4 a=qr[i], b=kr[i];
            acc += a.x*b.x + a.y*b.y + a.z*b.z + a.w*b.w;
        }
        val[k2] = acc * 0.08838834764831845f; // 1/sqrt(128)
    }
    float m = fmaxf(fmaxf(val[0],val[1]), fmaxf(val[2],val[3]));
    m = block_max_f(m,sred,4);
    float lsum=0.f, dummy=0.f;
    #pragma unroll
    for(int k2=0;k2<4;k2++){ val[k2]=expf(val[k2]-m); lsum+=val[k2]; }
    block_sum2(lsum,dummy,sred,4);
    float invs = 1.f/lsum;
    #pragma unroll
    for(int k2=0;k2<4;k2++) attn[(size_t)s*1024 + tid + k2*256] = val[k2]*invs;
}

// ---------------- av = attn @ v  (split-K over 2 halves, block 256)
__global__ __launch_bounds__(256) void k_av(
    const float* __restrict__ attn, const float* __restrict__ v, float* __restrict__ av)
{
    int s = blockIdx.x, tid = threadIdx.x;
    int j = tid & 127, half = tid >> 7;
    __shared__ float sa[1024];
    __shared__ float spart[2][128];
    for(int i=tid;i<1024;i+=256) sa[i] = attn[(size_t)s*1024+i];
    __syncthreads();
    float acc=0.f;
    int t0 = half*512;
    for(int t=t0;t<t0+512;t++) acc += sa[t]*v[(size_t)t*128+j];
    spart[half][j] = acc;
    __syncthreads();
    if(half==0) av[(size_t)s*128+j] = spart[0][j] + spart[1][j];
}

// ---------------- column pipeline: n1 = ||av[:,j]||, out = av/n1 + e, n2, ea = out/n2
__global__ __launch_bounds__(256) void k_colpipe(
    const float* __restrict__ av, const float* __restrict__ e, float* __restrict__ ea)
{
    int j = blockIdx.x, t = threadIdx.x;
    __shared__ float sred[4];
    float v[4];
    float ss = 0.f;
    #pragma unroll
    for(int k=0;k<4;k++){
        v[k] = av[(size_t)(t + 256*k)*128 + j];
        ss += v[k]*v[k];
    }
    #pragma unroll
    for(int off=1;off<64;off<<=1) ss += __shfl_xor(ss,off);
    int lane = t & 63, w = t >> 6;
    if(lane==0) sred[w]=ss;
    __syncthreads();
    float n1 = fmaxf(sqrtf(sred[0]+sred[1]+sred[2]+sred[3]), 1e-12f);
    __syncthreads();
    float ss2 = 0.f;
    #pragma unroll
    for(int k=0;k<4;k++){
        float o = v[k]/n1 + e[(size_t)(t + 256*k)*128 + j];
        v[k] = o;
        ss2 += o*o;
    }
    #pragma unroll
    for(int off=1;off<64;off<<=1) ss2 += __shfl_xor(ss2,off);
    if(lane==0) sred[w]=ss2;
    __syncthreads();
    float n2 = fmaxf(sqrtf(sred[0]+sred[1]+sred[2]+sred[3]), 1e-12f);
    #pragma unroll
    for(int k=0;k<4;k++) ea[(size_t)(t + 256*k)*128 + j] = v[k]/n2;
}

// ---------------- sq[s] = ||ea[s,:]||^2
__global__ __launch_bounds__(128) void k_sq(const float* __restrict__ ea, float* __restrict__ sq){
    int s = blockIdx.x, j = threadIdx.x;
    __shared__ float sred[32];
    float v = ea[(size_t)s*128+j];
    float a=v*v, b=0.f;
    block_sum2(a,b,sred,2);
    if(j==0) sq[s]=a;
}

// ---------------- pairwise d2 + global max(d2) via atomic bits-max
__global__ __launch_bounds__(256) void k_gram(
    const float* __restrict__ ea, const float* __restrict__ sq,
    float* __restrict__ d2, unsigned int* __restrict__ maxbits)
{
    int j0 = blockIdx.x*32, i0 = blockIdx.y*32, tid = threadIdx.x;
    __shared__ float sa[32*128];
    __shared__ float sb[32*128];
    __shared__ float sred[32];
    for(int idx=tid;idx<4096;idx+=256){
        sa[idx] = ea[(size_t)i0*128 + idx];
        sb[idx] = ea[(size_t)j0*128 + idx];
    }
    __syncthreads();
    float lm = 0.f;
    #pragma unroll
    for(int k2=0;k2<4;k2++){
        int p = tid + k2*256;
        int li = p>>5, lj = p&31;
        const float4* A = (const float4*)(sa + li*128);
        const float4* B = (const float4*)(sb + lj*128);
        float acc=0.f;
        #pragma unroll 8
        for(int i=0;i<32;i++){
            float4 a=A[i], b=B[i];
            acc += a.x*b.x + a.y*b.y + a.z*b.z + a.w*b.w;
        }
        float dd = fmaxf(sq[i0+li] + sq[j0+lj] - 2.f*acc, 0.f);
        d2[(size_t)(i0+li)*1024 + j0+lj] = dd;
        lm = fmaxf(lm, dd);
    }
    lm = block_max_f(lm,sred,4);
    if(tid==0) atomicMax(maxbits, __float_as_uint(lm));
}

// ---------------- out = 1 - sqrt(d2+eps)/maxd
__global__ __launch_bounds__(256) void k_final(
    const float* __restrict__ d2, const unsigned int* __restrict__ maxbits, float* __restrict__ out)
{
    int idx = blockIdx.x*256 + threadIdx.x;
    float md = sqrtf(__uint_as_float(*maxbits) + 1e-12f);
    out[idx] = 1.f - sqrtf(d2[idx] + 1e-12f)/md;
}

extern "C" void kernel_launch(void* const* d_in, const int* in_sizes, int n_in,
                              void* d_out, int out_size, void* d_ws, size_t ws_size,
                              hipStream_t stream)
{
    const float* x   = (const float*)d_in[0];
    const float* c1w = (const float*)d_in[1];  const float* c1b = (const float*)d_in[2];
    const float* g1g = (const float*)d_in[3];  const float* g1b = (const float*)d_in[4];
    const float* c2w = (const float*)d_in[5];  const float* c2b = (const float*)d_in[6];
    const float* g2g = (const float*)d_in[7];  const float* g2b = (const float*)d_in[8];
    const float* c3w = (const float*)d_in[9];  const float* c3b = (const float*)d_in[10];
    const float* g3g = (const float*)d_in[11]; const float* g3b = (const float*)d_in[12];
    const float* f1w = (const float*)d_in[13]; const float* f1b = (const float*)d_in[14];
    const float* wq  = (const float*)d_in[15]; const float* bq  = (const float*)d_in[16];
    const float* wk  = (const float*)d_in[17]; const float* bk  = (const float*)d_in[18];
    const float* wv  = (const float*)d_in[19]; const float* bv  = (const float*)d_in[20];

    float* W = (float*)d_ws;
    float* e0   = W;                 // 1,048,576
    float* attn = W + 1048576;       // 1,048,576
    float* avb  = W + 2097152;       //   131,072
    float* eab  = W + 2228224;       //   131,072
    float* d2b  = W + 2359296;       // 1,048,576
    float* buf1 = W;                 // stage1 out (dead before e0 written)
    float* buf2 = W + 18874368;      // stage2 out
    float* wt   = W + 22020096;
    float* wqt  = W + 22151168;
    float* wkt  = W + 22167552;
    float* wvt  = W + 22183936;
    float* eb   = W + 22200320;
    float* qb   = W + 22331392;
    float* kpb  = W + 22462464;
    float* vb   = W + 22593536;
    float* sqb  = W + 22724608;
    unsigned int* maxb = (unsigned int*)(W + 22725632);

    k_transpose<<<512,256,0,stream>>>(f1w, wt, 128, 1024);
    k_transpose<<<64,256,0,stream>>>(wq, wqt, 128, 128);
    k_transpose<<<64,256,0,stream>>>(wk, wkt, 128, 128);
    k_transpose<<<64,256,0,stream>>>(wv, wvt, 128, 128);

    k_conv1<<<dim3(4,1024),512,0,stream>>>(x,   c1w,c1b,g1g,g1b, buf1);
    k_conv2<<<1024,512,0,stream>>>(buf1,c2w,c2b,g2g,g2b, buf2);
    k_conv3<<<256,512,0,stream>>>(buf2,c3w,c3b,g3g,g3b, e0);

    k_fc1<<<1024,128,0,stream>>>(e0, wt, f1b, eb);
    k_qkv<<<1024,128,0,stream>>>(eb, wqt,bq, wkt,bk, wvt,bv, qb,kpb,vb);
    k_attn<<<1024,256,0,stream>>>(qb, kpb, attn);
    k_av<<<1024,256,0,stream>>>(attn, vb, avb);

    hipMemsetAsync(maxb, 0, 4, stream);
    k_colpipe<<<128,256,0,stream>>>(avb, eb, eab);
    k_sq<<<1024,128,0,stream>>>(eab, sqb);
    k_gram<<<dim3(32,32),256,0,stream>>>(eab, sqb, d2b, maxb);
    k_final<<<4096,256,0,stream>>>(d2b, maxb, (float*)d_out);
}

// Round 6
// 688.366 us; speedup vs baseline: 6.1788x; 2.4349x over previous
//
#include <hip/hip_runtime.h>
#include <hip/hip_bf16.h>
#include <math.h>

#define SELU_SCALE 1.0507009873554805f
#define SELU_ALPHA 1.6732632423543772f

typedef __attribute__((ext_vector_type(8))) short short8;
typedef __attribute__((ext_vector_type(4))) float f32x4;

__device__ __forceinline__ float selu_f(float x){
    return x > 0.f ? SELU_SCALE * x : SELU_SCALE * SELU_ALPHA * expm1f(x);
}

__device__ __forceinline__ unsigned short bfc(float v){
    __hip_bfloat16 h = __float2bfloat16(v);
    return __builtin_bit_cast(unsigned short, h);
}

__device__ __forceinline__ float warp_sum(float v){
    #pragma unroll
    for(int o=32;o>0;o>>=1) v += __shfl_down(v,o,64);
    return v;
}
__device__ __forceinline__ float warp_max(float v){
    #pragma unroll
    for(int o=32;o>0;o>>=1) v = fmaxf(v,__shfl_down(v,o,64));
    return v;
}

__device__ __forceinline__ void block_sum2(float &a, float &b, float* sred, int nw){
    int lane = threadIdx.x & 63, w = threadIdx.x >> 6;
    a = warp_sum(a); b = warp_sum(b);
    __syncthreads();
    if(lane==0){ sred[w]=a; sred[16+w]=b; }
    __syncthreads();
    if(w==0){
        float x = (lane<nw)? sred[lane] : 0.f;
        float y = (lane<nw)? sred[16+lane] : 0.f;
        x = warp_sum(x); y = warp_sum(y);
        if(lane==0){ sred[0]=x; sred[16]=y; }
    }
    __syncthreads();
    a = sred[0]; b = sred[16];
}

__device__ __forceinline__ float block_max_f(float v, float* sred, int nw){
    int lane = threadIdx.x & 63, w = threadIdx.x >> 6;
    v = warp_max(v);
    __syncthreads();
    if(lane==0) sred[w]=v;
    __syncthreads();
    if(w==0){
        float x = (lane<nw)? sred[lane] : -INFINITY;
        x = warp_max(x);
        if(lane==0) sred[0]=x;
    }
    __syncthreads();
    return sred[0];
}

// ---------------- weight prep: w2 [64][32][6][4] -> w2bf [24][64][32] bf16
//                  w3 [128][64][6][4] -> w3bf [24][128][64] bf16
__global__ void k_prepw(const float* __restrict__ w2, const float* __restrict__ w3,
                        short* __restrict__ w2bf, short* __restrict__ w3bf){
    int idx = blockIdx.x*256 + threadIdx.x;
    if(idx < 49152){
        int t = idx >> 11;
        int rem = idx & 2047;
        int oc = rem >> 5, ic = rem & 31;
        w2bf[idx] = (short)bfc(w2[oc*768 + ic*24 + t]);
    }
    int j = idx - 49152;
    if(j >= 0 && j < 196608){
        int t = j >> 13;
        int rem = j & 8191;
        int oc = rem >> 6, ic = rem & 63;
        w3bf[j] = (short)bfc(w3[oc*1536 + ic*24 + t]);
    }
}

// ============ Stage 1: conv1(1->32) + SELU + GN(1ch/grp) + maxpool(2,4)  [fp32]
// NOTE: #pragma unroll 1 on the kw loop is load-bearing (prevents VGPR spill).
__global__ __launch_bounds__(512,2) void k_conv1(
    const float* __restrict__ x, const float* __restrict__ w, const float* __restrict__ bias,
    const float* __restrict__ g, const float* __restrict__ be, float* __restrict__ out)
{
    int ocq = blockIdx.x, s = blockIdx.y, tid = threadIdx.x;
    int x_ = tid & 63, yg = (tid >> 6) & 3, oh = tid >> 8;
    int wv_id = tid >> 6;
    __shared__ float sin_[77*68];
    __shared__ float sw[24*8];
    __shared__ float sred[8][4][2];
    if(tid < 192){ int khw = tid>>3, o = tid&7; sw[tid] = w[(ocq*8+o)*24 + khw]; }
    for(int i=tid;i<77*68;i+=512) sin_[i]=0.f;
    __syncthreads();
    const float* xs = x + (size_t)s*4608;
    for(int i=tid;i<4608;i+=512){ int r=i>>6, cc=i&63; sin_[(r+2)*68 + (cc+1)] = xs[i]; }
    __syncthreads();

    float acc[4][18];
    #pragma unroll
    for(int o=0;o<4;o++){
        float bb = bias[ocq*8+oh*4+o];
        #pragma unroll
        for(int p=0;p<18;p++) acc[o][p]=bb;
    }
    int y0 = yg*18;
    #pragma unroll 1
    for(int kw=0;kw<4;kw++){
        float col[23];
        #pragma unroll
        for(int r=0;r<23;r++) col[r] = sin_[(y0+r)*68 + x_ + kw];
        #pragma unroll
        for(int kh=0;kh<6;kh++){
            float4 wa = *(const float4*)(sw + (kh*4+kw)*8 + oh*4);
            float wvv[4] = {wa.x,wa.y,wa.z,wa.w};
            #pragma unroll
            for(int p=0;p<18;p++){
                float v = col[p+kh];
                #pragma unroll
                for(int o=0;o<4;o++) acc[o][p] = fmaf(v, wvv[o], acc[o][p]);
            }
        }
    }
    #pragma unroll
    for(int o=0;o<4;o++){
        float a=0.f,b=0.f;
        #pragma unroll
        for(int p=0;p<18;p++){
            float v = selu_f(acc[o][p]); acc[o][p]=v;
            a += v; b += v*v;
        }
        #pragma unroll
        for(int off=1;off<64;off<<=1){ a += __shfl_xor(a,off); b += __shfl_xor(b,off); }
        if(x_==0){ sred[wv_id][o][0]=a; sred[wv_id][o][1]=b; }
    }
    __syncthreads();
    float* o_ = out + ((size_t)s*32 + ocq*8 + oh*4)*576;
    #pragma unroll
    for(int o=0;o<4;o++){
        float ts=0.f, tq=0.f;
        #pragma unroll
        for(int yy=0;yy<4;yy++){ ts += sred[oh*4+yy][o][0]; tq += sred[oh*4+yy][o][1]; }
        float mean = ts*(1.f/4608.f);
        float var  = tq*(1.f/4608.f) - mean*mean;
        float inv  = rsqrtf(var + 1e-5f);
        int oc = ocq*8+oh*4+o;
        float sc = g[oc]*inv, sh = be[oc] - mean*sc;
        #pragma unroll
        for(int p=0;p<18;p++) acc[o][p] = acc[o][p]*sc + sh;
        #pragma unroll
        for(int py=0;py<9;py++){
            float m = fmaxf(acc[o][2*py],acc[o][2*py+1]);
            m = fmaxf(m, __shfl_xor(m,1));
            m = fmaxf(m, __shfl_xor(m,2));
            if((x_&3)==0) o_[o*576 + (yg*9+py)*16 + (x_>>2)] = m;
        }
    }
}

// ============ Stage 2 (MFMA): conv2(32->64) + SELU + GN(2ch/grp) + maxpool(3,4)
// grid (1024 s), block 512 = 8 waves: wave = ocp(2: 2 octiles each) x yq(4: 9 y-rows).
// Input staged channel-last bf16 LDS [R 41][C 20][ic 32] with XOR-swizzled 16B quarters.
// Per tap (kh,kw): A-frag (bf16 weights, global/L2, 1-tap prefetch); B-frag = 1 ds_read_b128.
__global__ __launch_bounds__(512,2) void k_conv2m(
    const float* __restrict__ in, const short* __restrict__ w2bf,
    const float* __restrict__ bias, const float* __restrict__ g,
    const float* __restrict__ be, float* __restrict__ out)
{
    int s = blockIdx.x, tid = threadIdx.x;
    int l = tid & 63, wv = tid >> 6;
    int ocp = wv >> 2, yq = wv & 3;
    int xc = l & 15, qr = l >> 4;
    __shared__ short sinb[26240];            // 41*20*32 bf16 = 52,480 B
    __shared__ float sred[2][4][2][4][2][2]; // [ocp][yq][o][q][grp][sum/sq]
    int* zp = (int*)sinb;
    for(int i=tid;i<13120;i+=512) zp[i]=0;
    __syncthreads();
    const float* ibase = in + (size_t)s*18432;
    #pragma unroll
    for(int h=0;h<2;h++){
        int ic = (wv*2+h)*2;
        #pragma unroll
        for(int k=0;k<9;k++){
            int px = l + 64*k;
            float v0 = ibase[ic*576 + px];
            float v1 = ibase[(ic+1)*576 + px];
            int R = (px>>4)+2, C = (px&15)+1;
            int key = (C>>1)&3;
            int q0 = ic>>3;
            int byteoff = (R*20+C)*64 + (((q0^key)&3)<<4) + (ic&7)*2;
            *(unsigned int*)((char*)sinb + byteoff) =
                (unsigned int)bfc(v0) | ((unsigned int)bfc(v1)<<16);
        }
    }
    __syncthreads();
    f32x4 acc[2][9];
    #pragma unroll
    for(int o=0;o<2;o++)
        #pragma unroll
        for(int yt=0;yt<9;yt++) acc[o][yt] = (f32x4){0.f,0.f,0.f,0.f};
    const short8* wb = (const short8*)w2bf;
    int arow = ocp*32 + xc;
    short8 a0 = wb[arow*4 + qr];
    short8 a1 = wb[(arow+16)*4 + qr];
    char* sb = (char*)sinb;
    for(int tap=0; tap<24; tap++){
        short8 na0, na1;
        if(tap<23){
            na0 = wb[((tap+1)*64 + arow)*4 + qr];
            na1 = wb[((tap+1)*64 + arow + 16)*4 + qr];
        }
        int kh = tap>>2, kw = tap&3;
        int C = xc + kw;
        int cb = C*64 + (((qr ^ ((C>>1)&3))&3)<<4);
        int rb = (yq*9 + kh)*1280;
        #pragma unroll
        for(int yt=0;yt<9;yt++){
            short8 bf_ = *(const short8*)(sb + rb + yt*1280 + cb);
            acc[0][yt] = __builtin_amdgcn_mfma_f32_16x16x32_bf16(a0, bf_, acc[0][yt], 0,0,0);
            acc[1][yt] = __builtin_amdgcn_mfma_f32_16x16x32_bf16(a1, bf_, acc[1][yt], 0,0,0);
        }
        a0 = na0; a1 = na1;
    }
    // epilogue: bias + SELU + GN stats + normalize + pool(3,4)
    #pragma unroll
    for(int o=0;o<2;o++){
        int ocb = (ocp*2+o)*16 + qr*4;
        float b0 = bias[ocb], b1 = bias[ocb+1], b2 = bias[ocb+2], b3 = bias[ocb+3];
        float s0=0,q0=0,s1=0,q1=0;
        #pragma unroll
        for(int yt=0;yt<9;yt++){
            float v0=selu_f(acc[o][yt][0]+b0), v1=selu_f(acc[o][yt][1]+b1);
            float v2=selu_f(acc[o][yt][2]+b2), v3=selu_f(acc[o][yt][3]+b3);
            acc[o][yt][0]=v0; acc[o][yt][1]=v1; acc[o][yt][2]=v2; acc[o][yt][3]=v3;
            s0+=v0+v1; q0+=v0*v0+v1*v1; s1+=v2+v3; q1+=v2*v2+v3*v3;
        }
        #pragma unroll
        for(int off=1;off<16;off<<=1){
            s0+=__shfl_xor(s0,off); q0+=__shfl_xor(q0,off);
            s1+=__shfl_xor(s1,off); q1+=__shfl_xor(q1,off);
        }
        if(xc==0){
            sred[ocp][yq][o][qr][0][0]=s0; sred[ocp][yq][o][qr][0][1]=q0;
            sred[ocp][yq][o][qr][1][0]=s1; sred[ocp][yq][o][qr][1][1]=q1;
        }
    }
    __syncthreads();
    float* ob = out + (size_t)s*64*48;
    #pragma unroll
    for(int o=0;o<2;o++){
        #pragma unroll
        for(int grp=0;grp<2;grp++){
            float ts=0, tq=0;
            #pragma unroll
            for(int y2=0;y2<4;y2++){ ts += sred[ocp][y2][o][qr][grp][0]; tq += sred[ocp][y2][o][qr][grp][1]; }
            float mean = ts*(1.f/1152.f);
            float var  = tq*(1.f/1152.f) - mean*mean;
            float inv  = rsqrtf(var + 1e-5f);
            int oc0 = (ocp*2+o)*16 + qr*4 + grp*2;
            float sc0 = g[oc0]*inv,   sh0 = be[oc0]   - mean*sc0;
            float sc1 = g[oc0+1]*inv, sh1 = be[oc0+1] - mean*sc1;
            #pragma unroll
            for(int yt=0;yt<9;yt++){
                acc[o][yt][grp*2]   = acc[o][yt][grp*2]*sc0 + sh0;
                acc[o][yt][grp*2+1] = acc[o][yt][grp*2+1]*sc1 + sh1;
            }
        }
        #pragma unroll
        for(int r=0;r<4;r++){
            #pragma unroll
            for(int py=0;py<3;py++){
                float m = fmaxf(fmaxf(acc[o][3*py][r],acc[o][3*py+1][r]),acc[o][3*py+2][r]);
                m = fmaxf(m, __shfl_xor(m,1));
                m = fmaxf(m, __shfl_xor(m,2));
                if((xc&3)==0){
                    int oc = (ocp*2+o)*16 + qr*4 + r;
                    ob[(size_t)oc*48 + (yq*3+py)*4 + (xc>>2)] = m;
                }
            }
        }
    }
}

// ============ Stage 3 (MFMA): conv3(64->128) + SELU + GN(4ch/grp) + maxpool(3,2)
// grid (512: 2 samples/block), block 512 = 8 waves: wave = ocp(4: 2 octiles) x sL(2).
// LDS: input channel-last bf16 [2][R 17][C 8][ic 64], swizzled; reused as fp32 pool scratch.
__global__ __launch_bounds__(512,2) void k_conv3m(
    const float* __restrict__ in, const short* __restrict__ w3bf,
    const float* __restrict__ bias, const float* __restrict__ g,
    const float* __restrict__ be, float* __restrict__ e0)
{
    int sq = blockIdx.x, tid = threadIdx.x;
    int l = tid & 63, wv = tid >> 6;
    int ocp = wv >> 1, sL = wv & 1;
    int c = l & 15, qr = l >> 4;
    int yl = c >> 2, xl = c & 3;
    __shared__ char smem[49152];             // max(34816 input, 49152 pool scratch)
    short* sinb = (short*)smem;
    int* zp = (int*)smem;
    for(int i=tid;i<8704;i+=512) zp[i]=0;
    __syncthreads();
    const float* ibase = in + (size_t)sq*6144;
    for(int j=0;j<6;j++){
        int idx = tid + 512*j;
        int px = idx % 48;
        int rest = idx / 48;
        int icp = rest & 31, ss = rest >> 5;
        int ic = icp*2;
        float v0 = ibase[ss*3072 + ic*48 + px];
        float v1 = ibase[ss*3072 + (ic+1)*48 + px];
        int R = (px>>2)+2, C = (px&3)+1;
        int pos = ss*136 + R*8 + C;
        int key = ((R&1)<<2) | (C&3);
        int q0 = ic>>3;
        int byteoff = pos*128 + (((q0^key)&7)<<4) + (ic&7)*2;
        *(unsigned int*)(smem + byteoff) = (unsigned int)bfc(v0) | ((unsigned int)bfc(v1)<<16);
    }
    __syncthreads();
    f32x4 acc[2][3];
    #pragma unroll
    for(int o=0;o<2;o++)
        #pragma unroll
        for(int yt=0;yt<3;yt++) acc[o][yt] = (f32x4){0.f,0.f,0.f,0.f};
    const short8* wb = (const short8*)w3bf;
    int arow = ocp*32 + c;
    char* sb = smem + sL*17408;
    short8 a0 = wb[arow*8 + qr];
    short8 a1 = wb[(arow+16)*8 + qr];
    for(int t2=0; t2<48; t2++){
        short8 na0, na1;
        if(t2<47){
            int nt = t2+1;
            na0 = wb[((nt>>1)*128 + arow)*8 + (nt&1)*4 + qr];
            na1 = wb[((nt>>1)*128 + arow + 16)*8 + (nt&1)*4 + qr];
        }
        int tap = t2>>1, ks = t2&1;
        int kh = tap>>2, kw = tap&3;
        int C = xl + kw;
        int q0 = ks*4 + qr;
        #pragma unroll
        for(int yt=0;yt<3;yt++){
            int R = yt*4 + yl + kh;
            int key = ((R&1)<<2) | (C&3);
            short8 bf_ = *(const short8*)(sb + (R*8+C)*128 + (((q0^key)&7)<<4));
            acc[0][yt] = __builtin_amdgcn_mfma_f32_16x16x32_bf16(a0, bf_, acc[0][yt], 0,0,0);
            acc[1][yt] = __builtin_amdgcn_mfma_f32_16x16x32_bf16(a1, bf_, acc[1][yt], 0,0,0);
        }
        a0 = na0; a1 = na1;
    }
    // epilogue: bias + SELU + GN (group = lane's oc quad) + normalize
    #pragma unroll
    for(int o=0;o<2;o++){
        int ocb = (ocp*2+o)*16 + qr*4;
        float b0 = bias[ocb], b1 = bias[ocb+1], b2 = bias[ocb+2], b3 = bias[ocb+3];
        float ssum=0.f, ssq=0.f;
        #pragma unroll
        for(int yt=0;yt<3;yt++){
            float v0=selu_f(acc[o][yt][0]+b0), v1=selu_f(acc[o][yt][1]+b1);
            float v2=selu_f(acc[o][yt][2]+b2), v3=selu_f(acc[o][yt][3]+b3);
            acc[o][yt][0]=v0; acc[o][yt][1]=v1; acc[o][yt][2]=v2; acc[o][yt][3]=v3;
            ssum += v0+v1+v2+v3; ssq += v0*v0+v1*v1+v2*v2+v3*v3;
        }
        #pragma unroll
        for(int off=1;off<16;off<<=1){ ssum+=__shfl_xor(ssum,off); ssq+=__shfl_xor(ssq,off); }
        float mean = ssum*(1.f/192.f);
        float var  = ssq*(1.f/192.f) - mean*mean;
        float inv  = rsqrtf(var + 1e-5f);
        #pragma unroll
        for(int r=0;r<4;r++){
            int oc = ocb + r;
            float sc = g[oc]*inv, sh = be[oc] - mean*sc;
            #pragma unroll
            for(int yt=0;yt<3;yt++) acc[o][yt][r] = acc[o][yt][r]*sc + sh;
        }
    }
    __syncthreads();   // input LDS now dead; reuse as pool scratch
    float* scr = (float*)smem + wv*1536;
    #pragma unroll
    for(int o=0;o<2;o++)
        #pragma unroll
        for(int yt=0;yt<3;yt++)
            #pragma unroll
            for(int r=0;r<4;r++){
                int px = (yt*4+yl)*4 + xl;
                scr[o*768 + (qr*4+r)*48 + px] = acc[o][yt][r];
            }
    __syncthreads();
    // pool 3x2 from scratch: lane -> (o=l>>5, oc_l=(l>>1)&15, x2=l&1), 4 pools
    float* sr = (float*)smem + wv*1536 + (l>>5)*768 + ((l>>1)&15)*48;
    int x2 = l&1;
    float* eo = e0 + (size_t)(sq*2+sL)*1024 + ((size_t)(ocp*2 + (l>>5))*16 + ((l>>1)&15))*8;
    #pragma unroll
    for(int py=0;py<4;py++){
        float m = sr[(py*3)*4 + x2*2];
        m = fmaxf(m, sr[(py*3)*4 + x2*2+1]);
        m = fmaxf(m, sr[(py*3+1)*4 + x2*2]);
        m = fmaxf(m, sr[(py*3+1)*4 + x2*2+1]);
        m = fmaxf(m, sr[(py*3+2)*4 + x2*2]);
        m = fmaxf(m, sr[(py*3+2)*4 + x2*2+1]);
        eo[py*2 + x2] = m;
    }
}

// ---------------- transpose helper: dst[c*R+r] = src[r*C+c]
__global__ void k_transpose(const float* __restrict__ src, float* __restrict__ dst, int R, int C){
    int idx = blockIdx.x*256 + threadIdx.x;
    if(idx < R*C){ int r = idx / C, c = idx % C; dst[c*R + r] = src[idx]; }
}

// ---------------- FC1 + SELU + row l2norm. wt is [1024][128]
__global__ __launch_bounds__(128) void k_fc1(
    const float* __restrict__ e0, const float* __restrict__ wt,
    const float* __restrict__ bias, float* __restrict__ e)
{
    int s = blockIdx.x, j = threadIdx.x;
    __shared__ float se[1024];
    __shared__ float sred[32];
    for(int i=j;i<1024;i+=128) se[i] = e0[(size_t)s*1024+i];
    __syncthreads();
    float acc = bias[j];
    for(int i=0;i<1024;i++) acc += se[i]*wt[i*128+j];
    float v = selu_f(acc);
    float a = v*v, b = 0.f;
    block_sum2(a,b,sred,2);
    float den = fmaxf(sqrtf(a), 1e-12f);
    e[(size_t)s*128+j] = v/den;
}

// ---------------- q,k,v projections + SELU; k gets positional encoding added
__global__ __launch_bounds__(128) void k_qkv(
    const float* __restrict__ e,
    const float* __restrict__ wqt, const float* __restrict__ bq,
    const float* __restrict__ wkt, const float* __restrict__ bk,
    const float* __restrict__ wvt, const float* __restrict__ bv,
    float* __restrict__ q, float* __restrict__ kp, float* __restrict__ v)
{
    int s = blockIdx.x, j = threadIdx.x;
    __shared__ float se[128];
    se[j] = e[(size_t)s*128+j];
    __syncthreads();
    float aq = bq[j], ak = bk[j], av = bv[j];
    for(int i=0;i<128;i++){
        float f = se[i];
        aq += f*wqt[i*128+j];
        ak += f*wkt[i*128+j];
        av += f*wvt[i*128+j];
    }
    aq = selu_f(aq); ak = selu_f(ak); av = selu_f(av);
    int i2 = j & ~1;
    float div = expf(-(float)i2 * 0.07195578412155481f);
    float ang = (float)s * div;
    float pe = (j & 1) ? cosf(ang) : sinf(ang);
    q[(size_t)s*128+j]  = aq;
    kp[(size_t)s*128+j] = ak + pe;
    v[(size_t)s*128+j]  = av;
}

// ---------------- scores + softmax row
__global__ __launch_bounds__(256) void k_attn(
    const float* __restrict__ q, const float* __restrict__ kp, float* __restrict__ attn)
{
    int s = blockIdx.x, tid = threadIdx.x;
    __shared__ float sq_[128];
    __shared__ float sred[32];
    if(tid < 128) sq_[tid] = q[(size_t)s*128+tid];
    __syncthreads();
    float val[4];
    const float4* qr = (const float4*)sq_;
    #pragma unroll
    for(int k2=0;k2<4;k2++){
        int t = tid + k2*256;
        const float4* kr = (const float4*)(kp + (size_t)t*128);
        float acc=0.f;
        #pragma unroll 8
        for(int i=0;i<32;i++){
            float4 a=qr[i], b=kr[i];
            acc += a.x*b.x + a.y*b.y + a.z*b.z + a.w*b.w;
        }
        val[k2] = acc * 0.08838834764831845f;
    }
    float m = fmaxf(fmaxf(val[0],val[1]), fmaxf(val[2],val[3]));
    m = block_max_f(m,sred,4);
    float lsum=0.f, dummy=0.f;
    #pragma unroll
    for(int k2=0;k2<4;k2++){ val[k2]=expf(val[k2]-m); lsum+=val[k2]; }
    block_sum2(lsum,dummy,sred,4);
    float invs = 1.f/lsum;
    #pragma unroll
    for(int k2=0;k2<4;k2++) attn[(size_t)s*1024 + tid + k2*256] = val[k2]*invs;
}

// ---------------- av = attn @ v  (split-K over 2 halves, block 256)
__global__ __launch_bounds__(256) void k_av(
    const float* __restrict__ attn, const float* __restrict__ v, float* __restrict__ av)
{
    int s = blockIdx.x, tid = threadIdx.x;
    int j = tid & 127, half = tid >> 7;
    __shared__ float sa[1024];
    __shared__ float spart[2][128];
    for(int i=tid;i<1024;i+=256) sa[i] = attn[(size_t)s*1024+i];
    __syncthreads();
    float acc=0.f;
    int t0 = half*512;
    for(int t=t0;t<t0+512;t++) acc += sa[t]*v[(size_t)t*128+j];
    spart[half][j] = acc;
    __syncthreads();
    if(half==0) av[(size_t)s*128+j] = spart[0][j] + spart[1][j];
}

// ---------------- column pipeline: n1 = ||av[:,j]||, out = av/n1 + e, n2, ea = out/n2
__global__ __launch_bounds__(256) void k_colpipe(
    const float* __restrict__ av, const float* __restrict__ e, float* __restrict__ ea)
{
    int j = blockIdx.x, t = threadIdx.x;
    __shared__ float sred[4];
    float v[4];
    float ss = 0.f;
    #pragma unroll
    for(int k=0;k<4;k++){
        v[k] = av[(size_t)(t + 256*k)*128 + j];
        ss += v[k]*v[k];
    }
    #pragma unroll
    for(int off=1;off<64;off<<=1) ss += __shfl_xor(ss,off);
    int lane = t & 63, w = t >> 6;
    if(lane==0) sred[w]=ss;
    __syncthreads();
    float n1 = fmaxf(sqrtf(sred[0]+sred[1]+sred[2]+sred[3]), 1e-12f);
    __syncthreads();
    float ss2 = 0.f;
    #pragma unroll
    for(int k=0;k<4;k++){
        float o = v[k]/n1 + e[(size_t)(t + 256*k)*128 + j];
        v[k] = o;
        ss2 += o*o;
    }
    #pragma unroll
    for(int off=1;off<64;off<<=1) ss2 += __shfl_xor(ss2,off);
    if(lane==0) sred[w]=ss2;
    __syncthreads();
    float n2 = fmaxf(sqrtf(sred[0]+sred[1]+sred[2]+sred[3]), 1e-12f);
    #pragma unroll
    for(int k=0;k<4;k++) ea[(size_t)(t + 256*k)*128 + j] = v[k]/n2;
}

// ---------------- sq[s] = ||ea[s,:]||^2
__global__ __launch_bounds__(128) void k_sq(const float* __restrict__ ea, float* __restrict__ sq){
    int s = blockIdx.x, j = threadIdx.x;
    __shared__ float sred[32];
    float v = ea[(size_t)s*128+j];
    float a=v*v, b=0.f;
    block_sum2(a,b,sred,2);
    if(j==0) sq[s]=a;
}

// ---------------- pairwise d2 + global max(d2) via atomic bits-max
__global__ __launch_bounds__(256) void k_gram(
    const float* __restrict__ ea, const float* __restrict__ sq,
    float* __restrict__ d2, unsigned int* __restrict__ maxbits)
{
    int j0 = blockIdx.x*32, i0 = blockIdx.y*32, tid = threadIdx.x;
    __shared__ float sa[32*128];
    __shared__ float sb[32*128];
    __shared__ float sred[32];
    for(int idx=tid;idx<4096;idx+=256){
        sa[idx] = ea[(size_t)i0*128 + idx];
        sb[idx] = ea[(size_t)j0*128 + idx];
    }
    __syncthreads();
    float lm = 0.f;
    #pragma unroll
    for(int k2=0;k2<4;k2++){
        int p = tid + k2*256;
        int li = p>>5, lj = p&31;
        const float4* A = (const float4*)(sa + li*128);
        const float4* B = (const float4*)(sb + lj*128);
        float acc=0.f;
        #pragma unroll 8
        for(int i=0;i<32;i++){
            float4 a=A[i], b=B[i];
            acc += a.x*b.x + a.y*b.y + a.z*b.z + a.w*b.w;
        }
        float dd = fmaxf(sq[i0+li] + sq[j0+lj] - 2.f*acc, 0.f);
        d2[(size_t)(i0+li)*1024 + j0+lj] = dd;
        lm = fmaxf(lm, dd);
    }
    lm = block_max_f(lm,sred,4);
    if(tid==0) atomicMax(maxbits, __float_as_uint(lm));
}

// ---------------- out = 1 - sqrt(d2+eps)/maxd
__global__ __launch_bounds__(256) void k_final(
    const float* __restrict__ d2, const unsigned int* __restrict__ maxbits, float* __restrict__ out)
{
    int idx = blockIdx.x*256 + threadIdx.x;
    float md = sqrtf(__uint_as_float(*maxbits) + 1e-12f);
    out[idx] = 1.f - sqrtf(d2[idx] + 1e-12f)/md;
}

extern "C" void kernel_launch(void* const* d_in, const int* in_sizes, int n_in,
                              void* d_out, int out_size, void* d_ws, size_t ws_size,
                              hipStream_t stream)
{
    const float* x   = (const float*)d_in[0];
    const float* c1w = (const float*)d_in[1];  const float* c1b = (const float*)d_in[2];
    const float* g1g = (const float*)d_in[3];  const float* g1b = (const float*)d_in[4];
    const float* c2w = (const float*)d_in[5];  const float* c2b = (const float*)d_in[6];
    const float* g2g = (const float*)d_in[7];  const float* g2b = (const float*)d_in[8];
    const float* c3w = (const float*)d_in[9];  const float* c3b = (const float*)d_in[10];
    const float* g3g = (const float*)d_in[11]; const float* g3b = (const float*)d_in[12];
    const float* f1w = (const float*)d_in[13]; const float* f1b = (const float*)d_in[14];
    const float* wq  = (const float*)d_in[15]; const float* bq  = (const float*)d_in[16];
    const float* wk  = (const float*)d_in[17]; const float* bk  = (const float*)d_in[18];
    const float* wv  = (const float*)d_in[19]; const float* bv  = (const float*)d_in[20];

    float* W = (float*)d_ws;
    float* e0   = W;                 // 1,048,576
    float* attn = W + 1048576;       // 1,048,576
    float* avb  = W + 2097152;       //   131,072
    float* eab  = W + 2228224;       //   131,072
    float* d2b  = W + 2359296;       // 1,048,576
    float* buf1 = W;                 // stage1 out (75.5MB region, dead before e0 written)
    float* buf2 = W + 18874368;      // stage2 out
    float* wt   = W + 22020096;
    float* wqt  = W + 22151168;
    float* wkt  = W + 22167552;
    float* wvt  = W + 22183936;
    float* eb   = W + 22200320;
    float* qb   = W + 22331392;
    float* kpb  = W + 22462464;
    float* vb   = W + 22593536;
    float* sqb  = W + 22724608;
    unsigned int* maxb = (unsigned int*)(W + 22725632);
    short* w2bf = (short*)(W + 22725648);   // 49,152 bf16 = 24,576 floats
    short* w3bf = (short*)(W + 22750224);   // 196,608 bf16 = 98,304 floats (FIX: was overlapping w2bf)

    k_transpose<<<512,256,0,stream>>>(f1w, wt, 128, 1024);
    k_transpose<<<64,256,0,stream>>>(wq, wqt, 128, 128);
    k_transpose<<<64,256,0,stream>>>(wk, wkt, 128, 128);
    k_transpose<<<64,256,0,stream>>>(wv, wvt, 128, 128);
    k_prepw<<<960,256,0,stream>>>(c2w, c3w, w2bf, w3bf);

    k_conv1<<<dim3(4,1024),512,0,stream>>>(x, c1w,c1b,g1g,g1b, buf1);
    k_conv2m<<<1024,512,0,stream>>>(buf1, w2bf, c2b, g2g, g2b, buf2);
    k_conv3m<<<512,512,0,stream>>>(buf2, w3bf, c3b, g3g, g3b, e0);

    k_fc1<<<1024,128,0,stream>>>(e0, wt, f1b, eb);
    k_qkv<<<1024,128,0,stream>>>(eb, wqt,bq, wkt,bk, wvt,bv, qb,kpb,vb);
    k_attn<<<1024,256,0,stream>>>(qb, kpb, attn);
    k_av<<<1024,256,0,stream>>>(attn, vb, avb);

    hipMemsetAsync(maxb, 0, 4, stream);
    k_colpipe<<<128,256,0,stream>>>(avb, eb, eab);
    k_sq<<<1024,128,0,stream>>>(eab, sqb);
    k_gram<<<dim3(32,32),256,0,stream>>>(eab, sqb, d2b, maxb);
    k_final<<<4096,256,0,stream>>>(d2b, maxb, (float*)d_out);
}

// Round 7
// 506.342 us; speedup vs baseline: 8.4000x; 1.3595x over previous
//
#include <hip/hip_runtime.h>
#include <hip/hip_bf16.h>
#include <math.h>

#define SELU_SCALE 1.0507009873554805f
#define SELU_SA    1.7580993408473766f   // scale*alpha

typedef __attribute__((ext_vector_type(8))) short short8;
typedef __attribute__((ext_vector_type(4))) float f32x4;

// fast SELU: x>0 ? s*x : sa*exp(x)-sa   (hw v_exp_f32; ~1e-7 abs err for x<=0)
__device__ __forceinline__ float selu_f(float x){
    return x > 0.f ? SELU_SCALE * x : fmaf(SELU_SA, __expf(x), -SELU_SA);
}

__device__ __forceinline__ unsigned short bfc(float v){
    __hip_bfloat16 h = __float2bfloat16(v);
    return __builtin_bit_cast(unsigned short, h);
}

__device__ __forceinline__ float warp_sum(float v){
    #pragma unroll
    for(int o=32;o>0;o>>=1) v += __shfl_down(v,o,64);
    return v;
}
__device__ __forceinline__ float warp_max(float v){
    #pragma unroll
    for(int o=32;o>0;o>>=1) v = fmaxf(v,__shfl_down(v,o,64));
    return v;
}

__device__ __forceinline__ void block_sum2(float &a, float &b, float* sred, int nw){
    int lane = threadIdx.x & 63, w = threadIdx.x >> 6;
    a = warp_sum(a); b = warp_sum(b);
    __syncthreads();
    if(lane==0){ sred[w]=a; sred[16+w]=b; }
    __syncthreads();
    if(w==0){
        float x = (lane<nw)? sred[lane] : 0.f;
        float y = (lane<nw)? sred[16+lane] : 0.f;
        x = warp_sum(x); y = warp_sum(y);
        if(lane==0){ sred[0]=x; sred[16]=y; }
    }
    __syncthreads();
    a = sred[0]; b = sred[16];
}

__device__ __forceinline__ float block_max_f(float v, float* sred, int nw){
    int lane = threadIdx.x & 63, w = threadIdx.x >> 6;
    v = warp_max(v);
    __syncthreads();
    if(lane==0) sred[w]=v;
    __syncthreads();
    if(w==0){
        float x = (lane<nw)? sred[lane] : -INFINITY;
        x = warp_max(x);
        if(lane==0) sred[0]=x;
    }
    __syncthreads();
    return sred[0];
}

// ---------------- weight prep: w2 [64][32][6][4] -> w2bf [24][64][32] bf16
//                  w3 [128][64][6][4] -> w3bf [24][128][64] bf16
__global__ void k_prepw(const float* __restrict__ w2, const float* __restrict__ w3,
                        short* __restrict__ w2bf, short* __restrict__ w3bf){
    int idx = blockIdx.x*256 + threadIdx.x;
    if(idx < 49152){
        int t = idx >> 11;
        int rem = idx & 2047;
        int oc = rem >> 5, ic = rem & 31;
        w2bf[idx] = (short)bfc(w2[oc*768 + ic*24 + t]);
    }
    int j = idx - 49152;
    if(j >= 0 && j < 196608){
        int t = j >> 13;
        int rem = j & 8191;
        int oc = rem >> 6, ic = rem & 63;
        w3bf[j] = (short)bfc(w3[oc*1536 + ic*24 + t]);
    }
}

// ============ Stage 1: conv1(1->32) + SELU + GN(1ch/grp) + maxpool(2,4)  [fp32]
// grid (8 ocq, 1024 s), block 512: tid = oh(2)*256 + yg(4)*64 + x(64).
// thread: 2 oc x 18-row column strip. acc=36 regs -> 3-4 blocks/CU resident.
// NOTE: #pragma unroll 1 on the kw loop is load-bearing (prevents VGPR spill).
__global__ __launch_bounds__(512,4) void k_conv1(
    const float* __restrict__ x, const float* __restrict__ w, const float* __restrict__ bias,
    const float* __restrict__ g, const float* __restrict__ be, float* __restrict__ out)
{
    int ocq = blockIdx.x, s = blockIdx.y, tid = threadIdx.x;
    int x_ = tid & 63, yg = (tid >> 6) & 3, oh = tid >> 8;
    int wv_id = tid >> 6;
    __shared__ float sin_[77*68];
    __shared__ float sw[24*4];          // [khw][4oc]
    __shared__ float sred[8][2][2];     // [wave][oc-local][sum/sq]
    if(tid < 96){ int khw = tid>>2, o = tid&3; sw[tid] = w[(ocq*4+o)*24 + khw]; }
    for(int i=tid;i<77*68;i+=512) sin_[i]=0.f;
    __syncthreads();
    const float* xs = x + (size_t)s*4608;
    for(int i=tid;i<4608;i+=512){ int r=i>>6, cc=i&63; sin_[(r+2)*68 + (cc+1)] = xs[i]; }
    __syncthreads();

    float acc[2][18];
    #pragma unroll
    for(int o=0;o<2;o++){
        float bb = bias[ocq*4+oh*2+o];
        #pragma unroll
        for(int p=0;p<18;p++) acc[o][p]=bb;
    }
    int y0 = yg*18;
    #pragma unroll 1
    for(int kw=0;kw<4;kw++){
        float col[23];
        #pragma unroll
        for(int r=0;r<23;r++) col[r] = sin_[(y0+r)*68 + x_ + kw];
        #pragma unroll
        for(int kh=0;kh<6;kh++){
            float2 wa = *(const float2*)(sw + (kh*4+kw)*4 + oh*2);
            float wvv[2] = {wa.x,wa.y};
            #pragma unroll
            for(int p=0;p<18;p++){
                float v = col[p+kh];
                #pragma unroll
                for(int o=0;o<2;o++) acc[o][p] = fmaf(v, wvv[o], acc[o][p]);
            }
        }
    }
    // SELU + per-oc partial stats (this wave: 18 rows x 64 cols)
    #pragma unroll
    for(int o=0;o<2;o++){
        float a=0.f,b=0.f;
        #pragma unroll
        for(int p=0;p<18;p++){
            float v = selu_f(acc[o][p]); acc[o][p]=v;
            a += v; b += v*v;
        }
        #pragma unroll
        for(int off=1;off<64;off<<=1){ a += __shfl_xor(a,off); b += __shfl_xor(b,off); }
        if(x_==0){ sred[wv_id][o][0]=a; sred[wv_id][o][1]=b; }
    }
    __syncthreads();
    float* o_ = out + ((size_t)s*32 + ocq*4 + oh*2)*576;
    #pragma unroll
    for(int o=0;o<2;o++){
        float ts=0.f, tq=0.f;
        #pragma unroll
        for(int yy=0;yy<4;yy++){ ts += sred[oh*4+yy][o][0]; tq += sred[oh*4+yy][o][1]; }
        float mean = ts*(1.f/4608.f);
        float var  = tq*(1.f/4608.f) - mean*mean;
        float inv  = rsqrtf(var + 1e-5f);
        int oc = ocq*4+oh*2+o;
        float sc = g[oc]*inv, sh = be[oc] - mean*sc;
        #pragma unroll
        for(int p=0;p<18;p++) acc[o][p] = acc[o][p]*sc + sh;
        #pragma unroll
        for(int py=0;py<9;py++){
            float m = fmaxf(acc[o][2*py],acc[o][2*py+1]);
            m = fmaxf(m, __shfl_xor(m,1));
            m = fmaxf(m, __shfl_xor(m,2));
            if((x_&3)==0) o_[o*576 + (yg*9+py)*16 + (x_>>2)] = m;
        }
    }
}

// ============ Stage 2 (MFMA): conv2(32->64) + SELU + GN(2ch/grp) + maxpool(3,4)
__global__ __launch_bounds__(512,2) void k_conv2m(
    const float* __restrict__ in, const short* __restrict__ w2bf,
    const float* __restrict__ bias, const float* __restrict__ g,
    const float* __restrict__ be, float* __restrict__ out)
{
    int s = blockIdx.x, tid = threadIdx.x;
    int l = tid & 63, wv = tid >> 6;
    int ocp = wv >> 2, yq = wv & 3;
    int xc = l & 15, qr = l >> 4;
    __shared__ short sinb[26240];            // 41*20*32 bf16 = 52,480 B
    __shared__ float sred[2][4][2][4][2][2]; // [ocp][yq][o][q][grp][sum/sq]
    int* zp = (int*)sinb;
    for(int i=tid;i<13120;i+=512) zp[i]=0;
    __syncthreads();
    const float* ibase = in + (size_t)s*18432;
    #pragma unroll
    for(int h=0;h<2;h++){
        int ic = (wv*2+h)*2;
        #pragma unroll
        for(int k=0;k<9;k++){
            int px = l + 64*k;
            float v0 = ibase[ic*576 + px];
            float v1 = ibase[(ic+1)*576 + px];
            int R = (px>>4)+2, C = (px&15)+1;
            int key = (C>>1)&3;
            int q0 = ic>>3;
            int byteoff = (R*20+C)*64 + (((q0^key)&3)<<4) + (ic&7)*2;
            *(unsigned int*)((char*)sinb + byteoff) =
                (unsigned int)bfc(v0) | ((unsigned int)bfc(v1)<<16);
        }
    }
    __syncthreads();
    f32x4 acc[2][9];
    #pragma unroll
    for(int o=0;o<2;o++)
        #pragma unroll
        for(int yt=0;yt<9;yt++) acc[o][yt] = (f32x4){0.f,0.f,0.f,0.f};
    const short8* wb = (const short8*)w2bf;
    int arow = ocp*32 + xc;
    short8 a0 = wb[arow*4 + qr];
    short8 a1 = wb[(arow+16)*4 + qr];
    char* sb = (char*)sinb;
    for(int tap=0; tap<24; tap++){
        short8 na0, na1;
        if(tap<23){
            na0 = wb[((tap+1)*64 + arow)*4 + qr];
            na1 = wb[((tap+1)*64 + arow + 16)*4 + qr];
        }
        int kh = tap>>2, kw = tap&3;
        int C = xc + kw;
        int cb = C*64 + (((qr ^ ((C>>1)&3))&3)<<4);
        int rb = (yq*9 + kh)*1280;
        #pragma unroll
        for(int yt=0;yt<9;yt++){
            short8 bf_ = *(const short8*)(sb + rb + yt*1280 + cb);
            acc[0][yt] = __builtin_amdgcn_mfma_f32_16x16x32_bf16(a0, bf_, acc[0][yt], 0,0,0);
            acc[1][yt] = __builtin_amdgcn_mfma_f32_16x16x32_bf16(a1, bf_, acc[1][yt], 0,0,0);
        }
        a0 = na0; a1 = na1;
    }
    // epilogue: bias + SELU + GN stats + normalize + pool(3,4)
    #pragma unroll
    for(int o=0;o<2;o++){
        int ocb = (ocp*2+o)*16 + qr*4;
        float b0 = bias[ocb], b1 = bias[ocb+1], b2 = bias[ocb+2], b3 = bias[ocb+3];
        float s0=0,q0=0,s1=0,q1=0;
        #pragma unroll
        for(int yt=0;yt<9;yt++){
            float v0=selu_f(acc[o][yt][0]+b0), v1=selu_f(acc[o][yt][1]+b1);
            float v2=selu_f(acc[o][yt][2]+b2), v3=selu_f(acc[o][yt][3]+b3);
            acc[o][yt][0]=v0; acc[o][yt][1]=v1; acc[o][yt][2]=v2; acc[o][yt][3]=v3;
            s0+=v0+v1; q0+=v0*v0+v1*v1; s1+=v2+v3; q1+=v2*v2+v3*v3;
        }
        #pragma unroll
        for(int off=1;off<16;off<<=1){
            s0+=__shfl_xor(s0,off); q0+=__shfl_xor(q0,off);
            s1+=__shfl_xor(s1,off); q1+=__shfl_xor(q1,off);
        }
        if(xc==0){
            sred[ocp][yq][o][qr][0][0]=s0; sred[ocp][yq][o][qr][0][1]=q0;
            sred[ocp][yq][o][qr][1][0]=s1; sred[ocp][yq][o][qr][1][1]=q1;
        }
    }
    __syncthreads();
    float* ob = out + (size_t)s*64*48;
    #pragma unroll
    for(int o=0;o<2;o++){
        #pragma unroll
        for(int grp=0;grp<2;grp++){
            float ts=0, tq=0;
            #pragma unroll
            for(int y2=0;y2<4;y2++){ ts += sred[ocp][y2][o][qr][grp][0]; tq += sred[ocp][y2][o][qr][grp][1]; }
            float mean = ts*(1.f/1152.f);
            float var  = tq*(1.f/1152.f) - mean*mean;
            float inv  = rsqrtf(var + 1e-5f);
            int oc0 = (ocp*2+o)*16 + qr*4 + grp*2;
            float sc0 = g[oc0]*inv,   sh0 = be[oc0]   - mean*sc0;
            float sc1 = g[oc0+1]*inv, sh1 = be[oc0+1] - mean*sc1;
            #pragma unroll
            for(int yt=0;yt<9;yt++){
                acc[o][yt][grp*2]   = acc[o][yt][grp*2]*sc0 + sh0;
                acc[o][yt][grp*2+1] = acc[o][yt][grp*2+1]*sc1 + sh1;
            }
        }
        #pragma unroll
        for(int r=0;r<4;r++){
            #pragma unroll
            for(int py=0;py<3;py++){
                float m = fmaxf(fmaxf(acc[o][3*py][r],acc[o][3*py+1][r]),acc[o][3*py+2][r]);
                m = fmaxf(m, __shfl_xor(m,1));
                m = fmaxf(m, __shfl_xor(m,2));
                if((xc&3)==0){
                    int oc = (ocp*2+o)*16 + qr*4 + r;
                    ob[(size_t)oc*48 + (yq*3+py)*4 + (xc>>2)] = m;
                }
            }
        }
    }
}

// ============ Stage 3 (MFMA): conv3(64->128) + SELU + GN(4ch/grp) + maxpool(3,2)
__global__ __launch_bounds__(512,2) void k_conv3m(
    const float* __restrict__ in, const short* __restrict__ w3bf,
    const float* __restrict__ bias, const float* __restrict__ g,
    const float* __restrict__ be, float* __restrict__ e0)
{
    int sq = blockIdx.x, tid = threadIdx.x;
    int l = tid & 63, wv = tid >> 6;
    int ocp = wv >> 1, sL = wv & 1;
    int c = l & 15, qr = l >> 4;
    int yl = c >> 2, xl = c & 3;
    __shared__ char smem[49152];             // max(34816 input, 49152 pool scratch)
    short* sinb = (short*)smem;
    int* zp = (int*)smem;
    for(int i=tid;i<8704;i+=512) zp[i]=0;
    __syncthreads();
    const float* ibase = in + (size_t)sq*6144;
    for(int j=0;j<6;j++){
        int idx = tid + 512*j;
        int px = idx % 48;
        int rest = idx / 48;
        int icp = rest & 31, ss = rest >> 5;
        int ic = icp*2;
        float v0 = ibase[ss*3072 + ic*48 + px];
        float v1 = ibase[ss*3072 + (ic+1)*48 + px];
        int R = (px>>2)+2, C = (px&3)+1;
        int pos = ss*136 + R*8 + C;
        int key = ((R&1)<<2) | (C&3);
        int q0 = ic>>3;
        int byteoff = pos*128 + (((q0^key)&7)<<4) + (ic&7)*2;
        *(unsigned int*)(smem + byteoff) = (unsigned int)bfc(v0) | ((unsigned int)bfc(v1)<<16);
    }
    __syncthreads();
    f32x4 acc[2][3];
    #pragma unroll
    for(int o=0;o<2;o++)
        #pragma unroll
        for(int yt=0;yt<3;yt++) acc[o][yt] = (f32x4){0.f,0.f,0.f,0.f};
    const short8* wb = (const short8*)w3bf;
    int arow = ocp*32 + c;
    char* sb = smem + sL*17408;
    short8 a0 = wb[arow*8 + qr];
    short8 a1 = wb[(arow+16)*8 + qr];
    for(int t2=0; t2<48; t2++){
        short8 na0, na1;
        if(t2<47){
            int nt = t2+1;
            na0 = wb[((nt>>1)*128 + arow)*8 + (nt&1)*4 + qr];
            na1 = wb[((nt>>1)*128 + arow + 16)*8 + (nt&1)*4 + qr];
        }
        int tap = t2>>1, ks = t2&1;
        int kh = tap>>2, kw = tap&3;
        int C = xl + kw;
        int q0 = ks*4 + qr;
        #pragma unroll
        for(int yt=0;yt<3;yt++){
            int R = yt*4 + yl + kh;
            int key = ((R&1)<<2) | (C&3);
            short8 bf_ = *(const short8*)(sb + (R*8+C)*128 + (((q0^key)&7)<<4));
            acc[0][yt] = __builtin_amdgcn_mfma_f32_16x16x32_bf16(a0, bf_, acc[0][yt], 0,0,0);
            acc[1][yt] = __builtin_amdgcn_mfma_f32_16x16x32_bf16(a1, bf_, acc[1][yt], 0,0,0);
        }
        a0 = na0; a1 = na1;
    }
    // epilogue: bias + SELU + GN (group = lane's oc quad) + normalize
    #pragma unroll
    for(int o=0;o<2;o++){
        int ocb = (ocp*2+o)*16 + qr*4;
        float b0 = bias[ocb], b1 = bias[ocb+1], b2 = bias[ocb+2], b3 = bias[ocb+3];
        float ssum=0.f, ssq=0.f;
        #pragma unroll
        for(int yt=0;yt<3;yt++){
            float v0=selu_f(acc[o][yt][0]+b0), v1=selu_f(acc[o][yt][1]+b1);
            float v2=selu_f(acc[o][yt][2]+b2), v3=selu_f(acc[o][yt][3]+b3);
            acc[o][yt][0]=v0; acc[o][yt][1]=v1; acc[o][yt][2]=v2; acc[o][yt][3]=v3;
            ssum += v0+v1+v2+v3; ssq += v0*v0+v1*v1+v2*v2+v3*v3;
        }
        #pragma unroll
        for(int off=1;off<16;off<<=1){ ssum+=__shfl_xor(ssum,off); ssq+=__shfl_xor(ssq,off); }
        float mean = ssum*(1.f/192.f);
        float var  = ssq*(1.f/192.f) - mean*mean;
        float inv  = rsqrtf(var + 1e-5f);
        #pragma unroll
        for(int r=0;r<4;r++){
            int oc = ocb + r;
            float sc = g[oc]*inv, sh = be[oc] - mean*sc;
            #pragma unroll
            for(int yt=0;yt<3;yt++) acc[o][yt][r] = acc[o][yt][r]*sc + sh;
        }
    }
    __syncthreads();   // input LDS now dead; reuse as pool scratch
    float* scr = (float*)smem + wv*1536;
    #pragma unroll
    for(int o=0;o<2;o++)
        #pragma unroll
        for(int yt=0;yt<3;yt++)
            #pragma unroll
            for(int r=0;r<4;r++){
                int px = (yt*4+yl)*4 + xl;
                scr[o*768 + (qr*4+r)*48 + px] = acc[o][yt][r];
            }
    __syncthreads();
    float* sr = (float*)smem + wv*1536 + (l>>5)*768 + ((l>>1)&15)*48;
    int x2 = l&1;
    float* eo = e0 + (size_t)(sq*2+sL)*1024 + ((size_t)(ocp*2 + (l>>5))*16 + ((l>>1)&15))*8;
    #pragma unroll
    for(int py=0;py<4;py++){
        float m = sr[(py*3)*4 + x2*2];
        m = fmaxf(m, sr[(py*3)*4 + x2*2+1]);
        m = fmaxf(m, sr[(py*3+1)*4 + x2*2]);
        m = fmaxf(m, sr[(py*3+1)*4 + x2*2+1]);
        m = fmaxf(m, sr[(py*3+2)*4 + x2*2]);
        m = fmaxf(m, sr[(py*3+2)*4 + x2*2+1]);
        eo[py*2 + x2] = m;
    }
}

// ---------------- transpose helper: dst[c*R+r] = src[r*C+c]
__global__ void k_transpose(const float* __restrict__ src, float* __restrict__ dst, int R, int C){
    int idx = blockIdx.x*256 + threadIdx.x;
    if(idx < R*C){ int r = idx / C, c = idx % C; dst[c*R + r] = src[idx]; }
}

// ---------------- FC1 + SELU + row l2norm. wt is [1024][128]. 256 thr split-K.
__global__ __launch_bounds__(256) void k_fc1(
    const float* __restrict__ e0, const float* __restrict__ wt,
    const float* __restrict__ bias, float* __restrict__ e)
{
    int s = blockIdx.x, tid = threadIdx.x;
    int j = tid & 127, half = tid >> 7;
    __shared__ float se[1024];
    __shared__ float sp[2][128];
    __shared__ float sred[2];
    for(int i=tid;i<1024;i+=256) se[i] = e0[(size_t)s*1024+i];
    __syncthreads();
    float acc = half ? 0.f : bias[j];
    const float* wp = wt + (size_t)half*512*128 + j;
    const float* sep = se + half*512;
    #pragma unroll 8
    for(int i=0;i<512;i++) acc += sep[i]*wp[(size_t)i*128];
    sp[half][j] = acc;
    __syncthreads();
    if(half==0){
        float v = selu_f(sp[0][j]+sp[1][j]);
        float a = v*v;
        #pragma unroll
        for(int o=1;o<64;o<<=1) a += __shfl_xor(a,o);
        if((j&63)==0) sred[j>>6]=a;
    }
    __syncthreads();
    if(half==0){
        float den = fmaxf(sqrtf(sred[0]+sred[1]), 1e-12f);
        float v = selu_f(sp[0][j]+sp[1][j]);
        e[(size_t)s*128+j] = v/den;
    }
}

// ---------------- q,k,v projections + SELU; k gets positional encoding. 256 thr split-K.
__global__ __launch_bounds__(256) void k_qkv(
    const float* __restrict__ e,
    const float* __restrict__ wqt, const float* __restrict__ bq,
    const float* __restrict__ wkt, const float* __restrict__ bk,
    const float* __restrict__ wvt, const float* __restrict__ bv,
    float* __restrict__ q, float* __restrict__ kp, float* __restrict__ v)
{
    int s = blockIdx.x, tid = threadIdx.x;
    int j = tid & 127, half = tid >> 7;
    __shared__ float se[128];
    __shared__ float sp[3][2][128];
    if(tid < 128) se[tid] = e[(size_t)s*128+tid];
    __syncthreads();
    float aq = half?0.f:bq[j], ak = half?0.f:bk[j], av = half?0.f:bv[j];
    int i0 = half*64;
    #pragma unroll 8
    for(int i=i0;i<i0+64;i++){
        float f = se[i];
        aq += f*wqt[i*128+j];
        ak += f*wkt[i*128+j];
        av += f*wvt[i*128+j];
    }
    sp[0][half][j]=aq; sp[1][half][j]=ak; sp[2][half][j]=av;
    __syncthreads();
    if(half==0){
        float vq = selu_f(sp[0][0][j]+sp[0][1][j]);
        float vk = selu_f(sp[1][0][j]+sp[1][1][j]);
        float vv = selu_f(sp[2][0][j]+sp[2][1][j]);
        int i2 = j & ~1;
        float div = __expf(-(float)i2 * 0.07195578412155481f);
        float ang = (float)s * div;
        float pe = (j & 1) ? cosf(ang) : sinf(ang);
        q[(size_t)s*128+j]  = vq;
        kp[(size_t)s*128+j] = vk + pe;
        v[(size_t)s*128+j]  = vv;
    }
}

// ---------------- scores + softmax row
__global__ __launch_bounds__(256) void k_attn(
    const float* __restrict__ q, const float* __restrict__ kp, float* __restrict__ attn)
{
    int s = blockIdx.x, tid = threadIdx.x;
    __shared__ float sq_[128];
    __shared__ float sred[32];
    if(tid < 128) sq_[tid] = q[(size_t)s*128+tid];
    __syncthreads();
    float val[4];
    const float4* qr = (const float4*)sq_;
    #pragma unroll
    for(int k2=0;k2<4;k2++){
        int t = tid + k2*256;
        const float4* kr = (const float4*)(kp + (size_t)t*128);
        float acc=0.f;
        #pragma unroll 8
        for(int i=0;i<32;i++){
            float4 a=qr[i], b=kr[i];
            acc += a.x*b.x + a.y*b.y + a.z*b.z + a.w*b.w;
        }
        val[k2] = acc * 0.08838834764831845f;
    }
    float m = fmaxf(fmaxf(val[0],val[1]), fmaxf(val[2],val[3]));
    m = block_max_f(m,sred,4);
    float lsum=0.f, dummy=0.f;
    #pragma unroll
    for(int k2=0;k2<4;k2++){ val[k2]=__expf(val[k2]-m); lsum+=val[k2]; }
    block_sum2(lsum,dummy,sred,4);
    float invs = 1.f/lsum;
    #pragma unroll
    for(int k2=0;k2<4;k2++) attn[(size_t)s*1024 + tid + k2*256] = val[k2]*invs;
}

// ---------------- av = attn @ v  (split-K over 2 halves, block 256)
__global__ __launch_bounds__(256) void k_av(
    const float* __restrict__ attn, const float* __restrict__ v, float* __restrict__ av)
{
    int s = blockIdx.x, tid = threadIdx.x;
    int j = tid & 127, half = tid >> 7;
    __shared__ float sa[1024];
    __shared__ float spart[2][128];
    for(int i=tid;i<1024;i+=256) sa[i] = attn[(size_t)s*1024+i];
    __syncthreads();
    float acc=0.f;
    int t0 = half*512;
    for(int t=t0;t<t0+512;t++) acc += sa[t]*v[(size_t)t*128+j];
    spart[half][j] = acc;
    __syncthreads();
    if(half==0) av[(size_t)s*128+j] = spart[0][j] + spart[1][j];
}

// ---------------- column pipeline: n1 = ||av[:,j]||, out = av/n1 + e, n2, ea = out/n2
__global__ __launch_bounds__(256) void k_colpipe(
    const float* __restrict__ av, const float* __restrict__ e, float* __restrict__ ea)
{
    int j = blockIdx.x, t = threadIdx.x;
    __shared__ float sred[4];
    float v[4];
    float ss = 0.f;
    #pragma unroll
    for(int k=0;k<4;k++){
        v[k] = av[(size_t)(t + 256*k)*128 + j];
        ss += v[k]*v[k];
    }
    #pragma unroll
    for(int off=1;off<64;off<<=1) ss += __shfl_xor(ss,off);
    int lane = t & 63, w = t >> 6;
    if(lane==0) sred[w]=ss;
    __syncthreads();
    float n1 = fmaxf(sqrtf(sred[0]+sred[1]+sred[2]+sred[3]), 1e-12f);
    __syncthreads();
    float ss2 = 0.f;
    #pragma unroll
    for(int k=0;k<4;k++){
        float o = v[k]/n1 + e[(size_t)(t + 256*k)*128 + j];
        v[k] = o;
        ss2 += o*o;
    }
    #pragma unroll
    for(int off=1;off<64;off<<=1) ss2 += __shfl_xor(ss2,off);
    if(lane==0) sred[w]=ss2;
    __syncthreads();
    float n2 = fmaxf(sqrtf(sred[0]+sred[1]+sred[2]+sred[3]), 1e-12f);
    #pragma unroll
    for(int k=0;k<4;k++) ea[(size_t)(t + 256*k)*128 + j] = v[k]/n2;
}

// ---------------- sq[s] = ||ea[s,:]||^2
__global__ __launch_bounds__(128) void k_sq(const float* __restrict__ ea, float* __restrict__ sq){
    int s = blockIdx.x, j = threadIdx.x;
    __shared__ float sred[32];
    float v = ea[(size_t)s*128+j];
    float a=v*v, b=0.f;
    block_sum2(a,b,sred,2);
    if(j==0) sq[s]=a;
}

// ---------------- pairwise d2 + global max(d2) via atomic bits-max
__global__ __launch_bounds__(256) void k_gram(
    const float* __restrict__ ea, const float* __restrict__ sq,
    float* __restrict__ d2, unsigned int* __restrict__ maxbits)
{
    int j0 = blockIdx.x*32, i0 = blockIdx.y*32, tid = threadIdx.x;
    __shared__ float sa[32*128];
    __shared__ float sb[32*128];
    __shared__ float sred[32];
    for(int idx=tid;idx<4096;idx+=256){
        sa[idx] = ea[(size_t)i0*128 + idx];
        sb[idx] = ea[(size_t)j0*128 + idx];
    }
    __syncthreads();
    float lm = 0.f;
    #pragma unroll
    for(int k2=0;k2<4;k2++){
        int p = tid + k2*256;
        int li = p>>5, lj = p&31;
        const float4* A = (const float4*)(sa + li*128);
        const float4* B = (const float4*)(sb + lj*128);
        float acc=0.f;
        #pragma unroll 8
        for(int i=0;i<32;i++){
            float4 a=A[i], b=B[i];
            acc += a.x*b.x + a.y*b.y + a.z*b.z + a.w*b.w;
        }
        float dd = fmaxf(sq[i0+li] + sq[j0+lj] - 2.f*acc, 0.f);
        d2[(size_t)(i0+li)*1024 + j0+lj] = dd;
        lm = fmaxf(lm, dd);
    }
    lm = block_max_f(lm,sred,4);
    if(tid==0) atomicMax(maxbits, __float_as_uint(lm));
}

// ---------------- out = 1 - sqrt(d2+eps)/maxd
__global__ __launch_bounds__(256) void k_final(
    const float* __restrict__ d2, const unsigned int* __restrict__ maxbits, float* __restrict__ out)
{
    int idx = blockIdx.x*256 + threadIdx.x;
    float md = sqrtf(__uint_as_float(*maxbits) + 1e-12f);
    out[idx] = 1.f - sqrtf(d2[idx] + 1e-12f)/md;
}

extern "C" void kernel_launch(void* const* d_in, const int* in_sizes, int n_in,
                              void* d_out, int out_size, void* d_ws, size_t ws_size,
                              hipStream_t stream)
{
    const float* x   = (const float*)d_in[0];
    const float* c1w = (const float*)d_in[1];  const float* c1b = (const float*)d_in[2];
    const float* g1g = (const float*)d_in[3];  const float* g1b = (const float*)d_in[4];
    const float* c2w = (const float*)d_in[5];  const float* c2b = (const float*)d_in[6];
    const float* g2g = (const float*)d_in[7];  const float* g2b = (const float*)d_in[8];
    const float* c3w = (const float*)d_in[9];  const float* c3b = (const float*)d_in[10];
    const float* g3g = (const float*)d_in[11]; const float* g3b = (const float*)d_in[12];
    const float* f1w = (const float*)d_in[13]; const float* f1b = (const float*)d_in[14];
    const float* wq  = (const float*)d_in[15]; const float* bq  = (const float*)d_in[16];
    const float* wk  = (const float*)d_in[17]; const float* bk  = (const float*)d_in[18];
    const float* wv  = (const float*)d_in[19]; const float* bv  = (const float*)d_in[20];

    float* W = (float*)d_ws;
    float* e0   = W;                 // 1,048,576
    float* attn = W + 1048576;       // 1,048,576
    float* avb  = W + 2097152;       //   131,072
    float* eab  = W + 2228224;       //   131,072
    float* d2b  = W + 2359296;       // 1,048,576
    float* buf1 = W;                 // stage1 out (dead before e0 written)
    float* buf2 = W + 18874368;      // stage2 out
    float* wt   = W + 22020096;
    float* wqt  = W + 22151168;
    float* wkt  = W + 22167552;
    float* wvt  = W + 22183936;
    float* eb   = W + 22200320;
    float* qb   = W + 22331392;
    float* kpb  = W + 22462464;
    float* vb   = W + 22593536;
    float* sqb  = W + 22724608;
    unsigned int* maxb = (unsigned int*)(W + 22725632);
    short* w2bf = (short*)(W + 22725648);   // 49,152 bf16 = 24,576 floats
    short* w3bf = (short*)(W + 22750224);   // 196,608 bf16 = 98,304 floats

    k_transpose<<<512,256,0,stream>>>(f1w, wt, 128, 1024);
    k_transpose<<<64,256,0,stream>>>(wq, wqt, 128, 128);
    k_transpose<<<64,256,0,stream>>>(wk, wkt, 128, 128);
    k_transpose<<<64,256,0,stream>>>(wv, wvt, 128, 128);
    k_prepw<<<960,256,0,stream>>>(c2w, c3w, w2bf, w3bf);

    k_conv1<<<dim3(8,1024),512,0,stream>>>(x, c1w,c1b,g1g,g1b, buf1);
    k_conv2m<<<1024,512,0,stream>>>(buf1, w2bf, c2b, g2g, g2b, buf2);
    k_conv3m<<<512,512,0,stream>>>(buf2, w3bf, c3b, g3g, g3b, e0);

    k_fc1<<<1024,256,0,stream>>>(e0, wt, f1b, eb);
    k_qkv<<<1024,256,0,stream>>>(eb, wqt,bq, wkt,bk, wvt,bv, qb,kpb,vb);
    k_attn<<<1024,256,0,stream>>>(qb, kpb, attn);
    k_av<<<1024,256,0,stream>>>(attn, vb, avb);

    hipMemsetAsync(maxb, 0, 4, stream);
    k_colpipe<<<128,256,0,stream>>>(avb, eb, eab);
    k_sq<<<1024,128,0,stream>>>(eab, sqb);
    k_gram<<<dim3(32,32),256,0,stream>>>(eab, sqb, d2b, maxb);
    k_final<<<4096,256,0,stream>>>(d2b, maxb, (float*)d_out);
}

// Round 8
// 422.408 us; speedup vs baseline: 10.0691x; 1.1987x over previous
//
#include <hip/hip_runtime.h>
#include <hip/hip_bf16.h>
#include <math.h>

#define SELU_SCALE 1.0507009873554805f
#define SELU_SA    1.7580993408473766f   // scale*alpha

typedef __attribute__((ext_vector_type(8))) short short8;
typedef __attribute__((ext_vector_type(4))) short short4v;
typedef __attribute__((ext_vector_type(4))) float f32x4;

// fast SELU: x>0 ? s*x : sa*exp(x)-sa   (hw v_exp_f32; ~1e-7 abs err for x<=0)
__device__ __forceinline__ float selu_f(float x){
    return x > 0.f ? SELU_SCALE * x : fmaf(SELU_SA, __expf(x), -SELU_SA);
}

__device__ __forceinline__ unsigned short bfc(float v){
    __hip_bfloat16 h = __float2bfloat16(v);
    return __builtin_bit_cast(unsigned short, h);
}
__device__ __forceinline__ float f_bf(unsigned short u){
    unsigned int x = ((unsigned int)u) << 16;
    return __builtin_bit_cast(float, x);
}

__device__ __forceinline__ float warp_sum(float v){
    #pragma unroll
    for(int o=32;o>0;o>>=1) v += __shfl_down(v,o,64);
    return v;
}
__device__ __forceinline__ float warp_max(float v){
    #pragma unroll
    for(int o=32;o>0;o>>=1) v = fmaxf(v,__shfl_down(v,o,64));
    return v;
}

__device__ __forceinline__ void block_sum2(float &a, float &b, float* sred, int nw){
    int lane = threadIdx.x & 63, w = threadIdx.x >> 6;
    a = warp_sum(a); b = warp_sum(b);
    __syncthreads();
    if(lane==0){ sred[w]=a; sred[16+w]=b; }
    __syncthreads();
    if(w==0){
        float x = (lane<nw)? sred[lane] : 0.f;
        float y = (lane<nw)? sred[16+lane] : 0.f;
        x = warp_sum(x); y = warp_sum(y);
        if(lane==0){ sred[0]=x; sred[16]=y; }
    }
    __syncthreads();
    a = sred[0]; b = sred[16];
}

__device__ __forceinline__ float block_max_f(float v, float* sred, int nw){
    int lane = threadIdx.x & 63, w = threadIdx.x >> 6;
    v = warp_max(v);
    __syncthreads();
    if(lane==0) sred[w]=v;
    __syncthreads();
    if(w==0){
        float x = (lane<nw)? sred[lane] : -INFINITY;
        x = warp_max(x);
        if(lane==0) sred[0]=x;
    }
    __syncthreads();
    return sred[0];
}

// ---------------- unified weight prep (replaces 4 transposes + prepw):
// wt[1024][128] <- f1w[128][1024]; wqt/wkt/wvt transposed; w2bf [24][64][32];
// w3bf [24][128][64]; w1bf [32 oc][32 k] (k>=24 zero-padded).
__global__ void k_prep(const float* __restrict__ f1w, const float* __restrict__ wq,
                       const float* __restrict__ wk, const float* __restrict__ wv,
                       const float* __restrict__ w1, const float* __restrict__ w2,
                       const float* __restrict__ w3,
                       float* __restrict__ wt, float* __restrict__ wqt,
                       float* __restrict__ wkt, float* __restrict__ wvt,
                       short* __restrict__ w1bf, short* __restrict__ w2bf,
                       short* __restrict__ w3bf){
    int idx = blockIdx.x*256 + threadIdx.x;
    if(idx < 131072){ int r = idx >> 10, cc = idx & 1023; wt[cc*128 + r] = f1w[idx]; return; }
    idx -= 131072;
    if(idx < 16384){ int r = idx >> 7, cc = idx & 127; wqt[cc*128 + r] = wq[idx]; return; }
    idx -= 16384;
    if(idx < 16384){ int r = idx >> 7, cc = idx & 127; wkt[cc*128 + r] = wk[idx]; return; }
    idx -= 16384;
    if(idx < 16384){ int r = idx >> 7, cc = idx & 127; wvt[cc*128 + r] = wv[idx]; return; }
    idx -= 16384;
    if(idx < 49152){
        int t = idx >> 11, rem = idx & 2047;
        int oc = rem >> 5, ic = rem & 31;
        w2bf[idx] = (short)bfc(w2[oc*768 + ic*24 + t]);
        return;
    }
    idx -= 49152;
    if(idx < 196608){
        int t = idx >> 13, rem = idx & 8191;
        int oc = rem >> 6, ic = rem & 63;
        w3bf[idx] = (short)bfc(w3[oc*1536 + ic*24 + t]);
        return;
    }
    idx -= 196608;
    if(idx < 1024){
        int oc = idx >> 5, k = idx & 31;
        w1bf[idx] = (k < 24) ? (short)bfc(w1[oc*24 + k]) : (short)0;
    }
}

// ============ Stage 1 (MFMA): conv1(1->32) + SELU + GN(1ch/grp) + maxpool(2,4)
// 1 block = 1 sample, 768 thr = 12 waves. GEMM: out[32oc][4608px], K=32 (24 taps + 8 zero).
// LDS sdup[79 rows][4 off][16 xq] = packed 4 horiz taps per pixel (bf16 x4 = 8B).
// B-tile = 16 pixels at x=4c+off (strided) -> each lane's 8 results per row-pair = one
// 2x4 pool window -> in-lane pooling (max AND min; affine sign-selected after GN stats).
__global__ __launch_bounds__(768,1) void k_conv1m(
    const float* __restrict__ x, const short* __restrict__ w1bf,
    const float* __restrict__ bias, const float* __restrict__ g,
    const float* __restrict__ be, float* __restrict__ out)
{
    int s = blockIdx.x, tid = threadIdx.x;
    int l = tid & 63, wv = tid >> 6;          // wv 0..11
    int c = l & 15, qr = l >> 4;
    __shared__ char smem[117504];
    short* sdup = (short*)smem;               // 79*512 = 40448 B
    char* pmaxb = smem + 40448;               // [576 win][32 oc] bf16 = 36864
    char* pminb = smem + 77312;               // 36864 -> ends 114176
    float* sredf = (float*)(smem + 114176);   // [12][4][8][2] = 768 floats
    __shared__ float scsh[64];                // [32 oc][sc,sh]

    const float* xs = x + (size_t)s*4608;
    // stage packs: sdup[yp][off=xx&3][xq=xx>>2] = {inP[yp][xx..xx+3]} (zero-padded)
    for(int i = tid; i < 5056; i += 768){
        int yp = i >> 6, xx = i & 63;
        unsigned long long pk = 0ull;
        if(yp >= 2 && yp < 74){
            const float* row = xs + (yp-2)*64;
            #pragma unroll
            for(int t=0;t<4;t++){
                int cp = xx + t;
                float f = (cp>=1 && cp<65) ? row[cp-1] : 0.f;
                pk |= (unsigned long long)bfc(f) << (16*t);
            }
        }
        *(unsigned long long*)((char*)sdup + yp*512 + (xx&3)*128 + (xx>>2)*8) = pk;
    }
    // A-frags (both oc tiles) + bias
    short8 a0 = *(const short8*)(w1bf + c*32 + qr*8);
    short8 a1 = *(const short8*)(w1bf + (16+c)*32 + qr*8);
    float bias8[8];
    #pragma unroll
    for(int t=0;t<2;t++)
        #pragma unroll
        for(int r=0;r<4;r++) bias8[t*4+r] = bias[t*16 + qr*4 + r];
    float ssum8[8], ssq8[8];
    #pragma unroll
    for(int i=0;i<8;i++){ ssum8[i]=0.f; ssq8[i]=0.f; }
    __syncthreads();

    #pragma unroll 1
    for(int u=0; u<3; u++){
        int py = wv*3 + u;                    // 12 waves x 3 = 36 row-pairs
        float pmx[8], pmn[8];
        #pragma unroll
        for(int i=0;i<8;i++){ pmx[i]=-INFINITY; pmn[i]=INFINITY; }
        #pragma unroll
        for(int off=0; off<4; off++){
            const char* bb = (const char*)sdup + off*128 + c*8;
            #pragma unroll
            for(int rr=0; rr<2; rr++){
                int y = py*2 + rr;
                short4v lo = *(const short4v*)(bb + (y+2*qr)*512);
                short4v hi = *(const short4v*)(bb + (y+2*qr+1)*512);
                short8 bfrag = __builtin_shufflevector(lo, hi, 0,1,2,3,4,5,6,7);
                f32x4 d0 = __builtin_amdgcn_mfma_f32_16x16x32_bf16(a0, bfrag, (f32x4){0.f,0.f,0.f,0.f}, 0,0,0);
                f32x4 d1 = __builtin_amdgcn_mfma_f32_16x16x32_bf16(a1, bfrag, (f32x4){0.f,0.f,0.f,0.f}, 0,0,0);
                #pragma unroll
                for(int r=0;r<4;r++){
                    float v0 = selu_f(d0[r] + bias8[r]);
                    float v1 = selu_f(d1[r] + bias8[4+r]);
                    ssum8[r]   += v0; ssq8[r]   = fmaf(v0,v0,ssq8[r]);
                    ssum8[4+r] += v1; ssq8[4+r] = fmaf(v1,v1,ssq8[4+r]);
                    pmx[r]   = fmaxf(pmx[r],   v0); pmn[r]   = fminf(pmn[r],   v0);
                    pmx[4+r] = fmaxf(pmx[4+r], v1); pmn[4+r] = fminf(pmn[4+r], v1);
                }
            }
        }
        int base = (py*16 + c)*64;            // bytes: 32 oc * 2B per window
        #pragma unroll
        for(int t=0;t<2;t++){
            unsigned long long mpk=0ull, npk=0ull;
            #pragma unroll
            for(int r=0;r<4;r++){
                mpk |= (unsigned long long)bfc(pmx[t*4+r]) << (16*r);
                npk |= (unsigned long long)bfc(pmn[t*4+r]) << (16*r);
            }
            *(unsigned long long*)(pmaxb + base + t*32 + qr*8) = mpk;
            *(unsigned long long*)(pminb + base + t*32 + qr*8) = npk;
        }
    }
    // stats: reduce over the 16 c-lanes (xor<16 stays within quarter-wave group)
    #pragma unroll
    for(int off=1; off<16; off<<=1){
        #pragma unroll
        for(int i=0;i<8;i++){
            ssum8[i] += __shfl_xor(ssum8[i], off);
            ssq8[i]  += __shfl_xor(ssq8[i],  off);
        }
    }
    if(c == 0){
        #pragma unroll
        for(int i=0;i<8;i++){
            sredf[((wv*4 + qr)*8 + i)*2]     = ssum8[i];
            sredf[((wv*4 + qr)*8 + i)*2 + 1] = ssq8[i];
        }
    }
    __syncthreads();
    if(tid < 32){
        int oc = tid;
        int t = oc >> 4, rem = oc & 15, q = rem >> 2, r = rem & 3;
        int i = t*4 + r;
        float sum=0.f, sq=0.f;
        for(int w=0; w<12; w++){
            sum += sredf[((w*4+q)*8+i)*2];
            sq  += sredf[((w*4+q)*8+i)*2+1];
        }
        float mean = sum*(1.f/4608.f);
        float var  = sq*(1.f/4608.f) - mean*mean;
        float inv  = rsqrtf(var + 1e-5f);
        float sc = g[oc]*inv;
        scsh[oc*2]   = sc;
        scsh[oc*2+1] = be[oc] - mean*sc;
    }
    __syncthreads();
    // writeout: pooled (max if sc>=0 else min) * sc + sh -> buf1 [s][oc][576] fp32
    float* ob = out + (size_t)s*18432;
    for(int i = tid; i < 18432; i += 768){
        int oc = i / 576, wpx = i - oc*576;
        float sc = scsh[oc*2], sh = scsh[oc*2+1];
        int boff = wpx*64 + oc*2;
        float vm = f_bf(*(unsigned short*)(pmaxb + boff));
        float vn = f_bf(*(unsigned short*)(pminb + boff));
        ob[i] = fmaf(sc, (sc >= 0.f) ? vm : vn, sh);
    }
}

// ============ Stage 2 (MFMA): conv2(32->64) + SELU + GN(2ch/grp) + maxpool(3,4)
__global__ __launch_bounds__(512,2) void k_conv2m(
    const float* __restrict__ in, const short* __restrict__ w2bf,
    const float* __restrict__ bias, const float* __restrict__ g,
    const float* __restrict__ be, float* __restrict__ out)
{
    int s = blockIdx.x, tid = threadIdx.x;
    int l = tid & 63, wv = tid >> 6;
    int ocp = wv >> 2, yq = wv & 3;
    int xc = l & 15, qr = l >> 4;
    __shared__ short sinb[26240];            // 41*20*32 bf16 = 52,480 B
    __shared__ float sred[2][4][2][4][2][2]; // [ocp][yq][o][q][grp][sum/sq]
    int* zp = (int*)sinb;
    for(int i=tid;i<13120;i+=512) zp[i]=0;
    __syncthreads();
    const float* ibase = in + (size_t)s*18432;
    #pragma unroll
    for(int h=0;h<2;h++){
        int ic = (wv*2+h)*2;
        #pragma unroll
        for(int k=0;k<9;k++){
            int px = l + 64*k;
            float v0 = ibase[ic*576 + px];
            float v1 = ibase[(ic+1)*576 + px];
            int R = (px>>4)+2, C = (px&15)+1;
            int key = (C>>1)&3;
            int q0 = ic>>3;
            int byteoff = (R*20+C)*64 + (((q0^key)&3)<<4) + (ic&7)*2;
            *(unsigned int*)((char*)sinb + byteoff) =
                (unsigned int)bfc(v0) | ((unsigned int)bfc(v1)<<16);
        }
    }
    __syncthreads();
    f32x4 acc[2][9];
    #pragma unroll
    for(int o=0;o<2;o++)
        #pragma unroll
        for(int yt=0;yt<9;yt++) acc[o][yt] = (f32x4){0.f,0.f,0.f,0.f};
    const short8* wb = (const short8*)w2bf;
    int arow = ocp*32 + xc;
    short8 a0 = wb[arow*4 + qr];
    short8 a1 = wb[(arow+16)*4 + qr];
    char* sb = (char*)sinb;
    for(int tap=0; tap<24; tap++){
        short8 na0, na1;
        if(tap<23){
            na0 = wb[((tap+1)*64 + arow)*4 + qr];
            na1 = wb[((tap+1)*64 + arow + 16)*4 + qr];
        }
        int kh = tap>>2, kw = tap&3;
        int C = xc + kw;
        int cb = C*64 + (((qr ^ ((C>>1)&3))&3)<<4);
        int rb = (yq*9 + kh)*1280;
        #pragma unroll
        for(int yt=0;yt<9;yt++){
            short8 bf_ = *(const short8*)(sb + rb + yt*1280 + cb);
            acc[0][yt] = __builtin_amdgcn_mfma_f32_16x16x32_bf16(a0, bf_, acc[0][yt], 0,0,0);
            acc[1][yt] = __builtin_amdgcn_mfma_f32_16x16x32_bf16(a1, bf_, acc[1][yt], 0,0,0);
        }
        a0 = na0; a1 = na1;
    }
    // epilogue: bias + SELU + GN stats + normalize + pool(3,4)
    #pragma unroll
    for(int o=0;o<2;o++){
        int ocb = (ocp*2+o)*16 + qr*4;
        float b0 = bias[ocb], b1 = bias[ocb+1], b2 = bias[ocb+2], b3 = bias[ocb+3];
        float s0=0,q0=0,s1=0,q1=0;
        #pragma unroll
        for(int yt=0;yt<9;yt++){
            float v0=selu_f(acc[o][yt][0]+b0), v1=selu_f(acc[o][yt][1]+b1);
            float v2=selu_f(acc[o][yt][2]+b2), v3=selu_f(acc[o][yt][3]+b3);
            acc[o][yt][0]=v0; acc[o][yt][1]=v1; acc[o][yt][2]=v2; acc[o][yt][3]=v3;
            s0+=v0+v1; q0+=v0*v0+v1*v1; s1+=v2+v3; q1+=v2*v2+v3*v3;
        }
        #pragma unroll
        for(int off=1;off<16;off<<=1){
            s0+=__shfl_xor(s0,off); q0+=__shfl_xor(q0,off);
            s1+=__shfl_xor(s1,off); q1+=__shfl_xor(q1,off);
        }
        if(xc==0){
            sred[ocp][yq][o][qr][0][0]=s0; sred[ocp][yq][o][qr][0][1]=q0;
            sred[ocp][yq][o][qr][1][0]=s1; sred[ocp][yq][o][qr][1][1]=q1;
        }
    }
    __syncthreads();
    float* ob = out + (size_t)s*64*48;
    #pragma unroll
    for(int o=0;o<2;o++){
        #pragma unroll
        for(int grp=0;grp<2;grp++){
            float ts=0, tq=0;
            #pragma unroll
            for(int y2=0;y2<4;y2++){ ts += sred[ocp][y2][o][qr][grp][0]; tq += sred[ocp][y2][o][qr][grp][1]; }
            float mean = ts*(1.f/1152.f);
            float var  = tq*(1.f/1152.f) - mean*mean;
            float inv  = rsqrtf(var + 1e-5f);
            int oc0 = (ocp*2+o)*16 + qr*4 + grp*2;
            float sc0 = g[oc0]*inv,   sh0 = be[oc0]   - mean*sc0;
            float sc1 = g[oc0+1]*inv, sh1 = be[oc0+1] - mean*sc1;
            #pragma unroll
            for(int yt=0;yt<9;yt++){
                acc[o][yt][grp*2]   = acc[o][yt][grp*2]*sc0 + sh0;
                acc[o][yt][grp*2+1] = acc[o][yt][grp*2+1]*sc1 + sh1;
            }
        }
        #pragma unroll
        for(int r=0;r<4;r++){
            #pragma unroll
            for(int py=0;py<3;py++){
                float m = fmaxf(fmaxf(acc[o][3*py][r],acc[o][3*py+1][r]),acc[o][3*py+2][r]);
                m = fmaxf(m, __shfl_xor(m,1));
                m = fmaxf(m, __shfl_xor(m,2));
                if((xc&3)==0){
                    int oc = (ocp*2+o)*16 + qr*4 + r;
                    ob[(size_t)oc*48 + (yq*3+py)*4 + (xc>>2)] = m;
                }
            }
        }
    }
}

// ============ Stage 3 (MFMA): conv3(64->128) + SELU + GN(4ch/grp) + maxpool(3,2)
__global__ __launch_bounds__(512,2) void k_conv3m(
    const float* __restrict__ in, const short* __restrict__ w3bf,
    const float* __restrict__ bias, const float* __restrict__ g,
    const float* __restrict__ be, float* __restrict__ e0)
{
    int sq = blockIdx.x, tid = threadIdx.x;
    int l = tid & 63, wv = tid >> 6;
    int ocp = wv >> 1, sL = wv & 1;
    int c = l & 15, qr = l >> 4;
    int yl = c >> 2, xl = c & 3;
    __shared__ char smem[49152];             // max(34816 input, 49152 pool scratch)
    short* sinb = (short*)smem;
    int* zp = (int*)smem;
    for(int i=tid;i<8704;i+=512) zp[i]=0;
    __syncthreads();
    const float* ibase = in + (size_t)sq*6144;
    for(int j=0;j<6;j++){
        int idx = tid + 512*j;
        int px = idx % 48;
        int rest = idx / 48;
        int icp = rest & 31, ss = rest >> 5;
        int ic = icp*2;
        float v0 = ibase[ss*3072 + ic*48 + px];
        float v1 = ibase[ss*3072 + (ic+1)*48 + px];
        int R = (px>>2)+2, C = (px&3)+1;
        int pos = ss*136 + R*8 + C;
        int key = ((R&1)<<2) | (C&3);
        int q0 = ic>>3;
        int byteoff = pos*128 + (((q0^key)&7)<<4) + (ic&7)*2;
        *(unsigned int*)(smem + byteoff) = (unsigned int)bfc(v0) | ((unsigned int)bfc(v1)<<16);
    }
    __syncthreads();
    f32x4 acc[2][3];
    #pragma unroll
    for(int o=0;o<2;o++)
        #pragma unroll
        for(int yt=0;yt<3;yt++) acc[o][yt] = (f32x4){0.f,0.f,0.f,0.f};
    const short8* wb = (const short8*)w3bf;
    int arow = ocp*32 + c;
    char* sb = smem + sL*17408;
    short8 a0 = wb[arow*8 + qr];
    short8 a1 = wb[(arow+16)*8 + qr];
    for(int t2=0; t2<48; t2++){
        short8 na0, na1;
        if(t2<47){
            int nt = t2+1;
            na0 = wb[((nt>>1)*128 + arow)*8 + (nt&1)*4 + qr];
            na1 = wb[((nt>>1)*128 + arow + 16)*8 + (nt&1)*4 + qr];
        }
        int tap = t2>>1, ks = t2&1;
        int kh = tap>>2, kw = tap&3;
        int C = xl + kw;
        int q0 = ks*4 + qr;
        #pragma unroll
        for(int yt=0;yt<3;yt++){
            int R = yt*4 + yl + kh;
            int key = ((R&1)<<2) | (C&3);
            short8 bf_ = *(const short8*)(sb + (R*8+C)*128 + (((q0^key)&7)<<4));
            acc[0][yt] = __builtin_amdgcn_mfma_f32_16x16x32_bf16(a0, bf_, acc[0][yt], 0,0,0);
            acc[1][yt] = __builtin_amdgcn_mfma_f32_16x16x32_bf16(a1, bf_, acc[1][yt], 0,0,0);
        }
        a0 = na0; a1 = na1;
    }
    // epilogue: bias + SELU + GN (group = lane's oc quad) + normalize
    #pragma unroll
    for(int o=0;o<2;o++){
        int ocb = (ocp*2+o)*16 + qr*4;
        float b0 = bias[ocb], b1 = bias[ocb+1], b2 = bias[ocb+2], b3 = bias[ocb+3];
        float ssum=0.f, ssq=0.f;
        #pragma unroll
        for(int yt=0;yt<3;yt++){
            float v0=selu_f(acc[o][yt][0]+b0), v1=selu_f(acc[o][yt][1]+b1);
            float v2=selu_f(acc[o][yt][2]+b2), v3=selu_f(acc[o][yt][3]+b3);
            acc[o][yt][0]=v0; acc[o][yt][1]=v1; acc[o][yt][2]=v2; acc[o][yt][3]=v3;
            ssum += v0+v1+v2+v3; ssq += v0*v0+v1*v1+v2*v2+v3*v3;
        }
        #pragma unroll
        for(int off=1;off<16;off<<=1){ ssum+=__shfl_xor(ssum,off); ssq+=__shfl_xor(ssq,off); }
        float mean = ssum*(1.f/192.f);
        float var  = ssq*(1.f/192.f) - mean*mean;
        float inv  = rsqrtf(var + 1e-5f);
        #pragma unroll
        for(int r=0;r<4;r++){
            int oc = ocb + r;
            float sc = g[oc]*inv, sh = be[oc] - mean*sc;
            #pragma unroll
            for(int yt=0;yt<3;yt++) acc[o][yt][r] = acc[o][yt][r]*sc + sh;
        }
    }
    __syncthreads();   // input LDS now dead; reuse as pool scratch
    float* scr = (float*)smem + wv*1536;
    #pragma unroll
    for(int o=0;o<2;o++)
        #pragma unroll
        for(int yt=0;yt<3;yt++)
            #pragma unroll
            for(int r=0;r<4;r++){
                int px = (yt*4+yl)*4 + xl;
                scr[o*768 + (qr*4+r)*48 + px] = acc[o][yt][r];
            }
    __syncthreads();
    float* sr = (float*)smem + wv*1536 + (l>>5)*768 + ((l>>1)&15)*48;
    int x2 = l&1;
    float* eo = e0 + (size_t)(sq*2+sL)*1024 + ((size_t)(ocp*2 + (l>>5))*16 + ((l>>1)&15))*8;
    #pragma unroll
    for(int py=0;py<4;py++){
        float m = sr[(py*3)*4 + x2*2];
        m = fmaxf(m, sr[(py*3)*4 + x2*2+1]);
        m = fmaxf(m, sr[(py*3+1)*4 + x2*2]);
        m = fmaxf(m, sr[(py*3+1)*4 + x2*2+1]);
        m = fmaxf(m, sr[(py*3+2)*4 + x2*2]);
        m = fmaxf(m, sr[(py*3+2)*4 + x2*2+1]);
        eo[py*2 + x2] = m;
    }
}

// ---------------- FC1 + SELU + row l2norm. wt is [1024][128]. 256 thr split-K.
__global__ __launch_bounds__(256) void k_fc1(
    const float* __restrict__ e0, const float* __restrict__ wt,
    const float* __restrict__ bias, float* __restrict__ e)
{
    int s = blockIdx.x, tid = threadIdx.x;
    int j = tid & 127, half = tid >> 7;
    __shared__ float se[1024];
    __shared__ float sp[2][128];
    __shared__ float sred[2];
    for(int i=tid;i<1024;i+=256) se[i] = e0[(size_t)s*1024+i];
    __syncthreads();
    float acc = half ? 0.f : bias[j];
    const float* wp = wt + (size_t)half*512*128 + j;
    const float* sep = se + half*512;
    #pragma unroll 8
    for(int i=0;i<512;i++) acc += sep[i]*wp[(size_t)i*128];
    sp[half][j] = acc;
    __syncthreads();
    if(half==0){
        float v = selu_f(sp[0][j]+sp[1][j]);
        float a = v*v;
        #pragma unroll
        for(int o=1;o<64;o<<=1) a += __shfl_xor(a,o);
        if((j&63)==0) sred[j>>6]=a;
    }
    __syncthreads();
    if(half==0){
        float den = fmaxf(sqrtf(sred[0]+sred[1]), 1e-12f);
        float v = selu_f(sp[0][j]+sp[1][j]);
        e[(size_t)s*128+j] = v/den;
    }
}

// ---------------- q,k,v projections + SELU; k gets positional encoding. 256 thr split-K.
__global__ __launch_bounds__(256) void k_qkv(
    const float* __restrict__ e,
    const float* __restrict__ wqt, const float* __restrict__ bq,
    const float* __restrict__ wkt, const float* __restrict__ bk,
    const float* __restrict__ wvt, const float* __restrict__ bv,
    float* __restrict__ q, float* __restrict__ kp, float* __restrict__ v)
{
    int s = blockIdx.x, tid = threadIdx.x;
    int j = tid & 127, half = tid >> 7;
    __shared__ float se[128];
    __shared__ float sp[3][2][128];
    if(tid < 128) se[tid] = e[(size_t)s*128+tid];
    __syncthreads();
    float aq = half?0.f:bq[j], ak = half?0.f:bk[j], av = half?0.f:bv[j];
    int i0 = half*64;
    #pragma unroll 8
    for(int i=i0;i<i0+64;i++){
        float f = se[i];
        aq += f*wqt[i*128+j];
        ak += f*wkt[i*128+j];
        av += f*wvt[i*128+j];
    }
    sp[0][half][j]=aq; sp[1][half][j]=ak; sp[2][half][j]=av;
    __syncthreads();
    if(half==0){
        float vq = selu_f(sp[0][0][j]+sp[0][1][j]);
        float vk = selu_f(sp[1][0][j]+sp[1][1][j]);
        float vv = selu_f(sp[2][0][j]+sp[2][1][j]);
        int i2 = j & ~1;
        float div = __expf(-(float)i2 * 0.07195578412155481f);
        float ang = (float)s * div;
        float pe = (j & 1) ? cosf(ang) : sinf(ang);
        q[(size_t)s*128+j]  = vq;
        kp[(size_t)s*128+j] = vk + pe;
        v[(size_t)s*128+j]  = vv;
    }
}

// ---------------- scores + softmax row
__global__ __launch_bounds__(256) void k_attn(
    const float* __restrict__ q, const float* __restrict__ kp, float* __restrict__ attn)
{
    int s = blockIdx.x, tid = threadIdx.x;
    __shared__ float sq_[128];
    __shared__ float sred[32];
    if(tid < 128) sq_[tid] = q[(size_t)s*128+tid];
    __syncthreads();
    float val[4];
    const float4* qr = (const float4*)sq_;
    #pragma unroll
    for(int k2=0;k2<4;k2++){
        int t = tid + k2*256;
        const float4* kr = (const float4*)(kp + (size_t)t*128);
        float acc=0.f;
        #pragma unroll 8
        for(int i=0;i<32;i++){
            float4 a=qr[i], b=kr[i];
            acc += a.x*b.x + a.y*b.y + a.z*b.z + a.w*b.w;
        }
        val[k2] = acc * 0.08838834764831845f;
    }
    float m = fmaxf(fmaxf(val[0],val[1]), fmaxf(val[2],val[3]));
    m = block_max_f(m,sred,4);
    float lsum=0.f, dummy=0.f;
    #pragma unroll
    for(int k2=0;k2<4;k2++){ val[k2]=__expf(val[k2]-m); lsum+=val[k2]; }
    block_sum2(lsum,dummy,sred,4);
    float invs = 1.f/lsum;
    #pragma unroll
    for(int k2=0;k2<4;k2++) attn[(size_t)s*1024 + tid + k2*256] = val[k2]*invs;
}

// ---------------- av = attn @ v  (split-K over 2 halves, block 256)
__global__ __launch_bounds__(256) void k_av(
    const float* __restrict__ attn, const float* __restrict__ v, float* __restrict__ av)
{
    int s = blockIdx.x, tid = threadIdx.x;
    int j = tid & 127, half = tid >> 7;
    __shared__ float sa[1024];
    __shared__ float spart[2][128];
    for(int i=tid;i<1024;i+=256) sa[i] = attn[(size_t)s*1024+i];
    __syncthreads();
    float acc=0.f;
    int t0 = half*512;
    for(int t=t0;t<t0+512;t++) acc += sa[t]*v[(size_t)t*128+j];
    spart[half][j] = acc;
    __syncthreads();
    if(half==0) av[(size_t)s*128+j] = spart[0][j] + spart[1][j];
}

// ---------------- column pipeline: n1 = ||av[:,j]||, out = av/n1 + e, n2, ea = out/n2
__global__ __launch_bounds__(256) void k_colpipe(
    const float* __restrict__ av, const float* __restrict__ e, float* __restrict__ ea)
{
    int j = blockIdx.x, t = threadIdx.x;
    __shared__ float sred[4];
    float v[4];
    float ss = 0.f;
    #pragma unroll
    for(int k=0;k<4;k++){
        v[k] = av[(size_t)(t + 256*k)*128 + j];
        ss += v[k]*v[k];
    }
    #pragma unroll
    for(int off=1;off<64;off<<=1) ss += __shfl_xor(ss,off);
    int lane = t & 63, w = t >> 6;
    if(lane==0) sred[w]=ss;
    __syncthreads();
    float n1 = fmaxf(sqrtf(sred[0]+sred[1]+sred[2]+sred[3]), 1e-12f);
    __syncthreads();
    float ss2 = 0.f;
    #pragma unroll
    for(int k=0;k<4;k++){
        float o = v[k]/n1 + e[(size_t)(t + 256*k)*128 + j];
        v[k] = o;
        ss2 += o*o;
    }
    #pragma unroll
    for(int off=1;off<64;off<<=1) ss2 += __shfl_xor(ss2,off);
    if(lane==0) sred[w]=ss2;
    __syncthreads();
    float n2 = fmaxf(sqrtf(sred[0]+sred[1]+sred[2]+sred[3]), 1e-12f);
    #pragma unroll
    for(int k=0;k<4;k++) ea[(size_t)(t + 256*k)*128 + j] = v[k]/n2;
}

// ---------------- sq[s] = ||ea[s,:]||^2
__global__ __launch_bounds__(128) void k_sq(const float* __restrict__ ea, float* __restrict__ sq){
    int s = blockIdx.x, j = threadIdx.x;
    __shared__ float sred[32];
    float v = ea[(size_t)s*128+j];
    float a=v*v, b=0.f;
    block_sum2(a,b,sred,2);
    if(j==0) sq[s]=a;
}

// ---------------- pairwise d2 + global max(d2) via atomic bits-max
__global__ __launch_bounds__(256) void k_gram(
    const float* __restrict__ ea, const float* __restrict__ sq,
    float* __restrict__ d2, unsigned int* __restrict__ maxbits)
{
    int j0 = blockIdx.x*32, i0 = blockIdx.y*32, tid = threadIdx.x;
    __shared__ float sa[32*128];
    __shared__ float sb[32*128];
    __shared__ float sred[32];
    for(int idx=tid;idx<4096;idx+=256){
        sa[idx] = ea[(size_t)i0*128 + idx];
        sb[idx] = ea[(size_t)j0*128 + idx];
    }
    __syncthreads();
    float lm = 0.f;
    #pragma unroll
    for(int k2=0;k2<4;k2++){
        int p = tid + k2*256;
        int li = p>>5, lj = p&31;
        const float4* A = (const float4*)(sa + li*128);
        const float4* B = (const float4*)(sb + lj*128);
        float acc=0.f;
        #pragma unroll 8
        for(int i=0;i<32;i++){
            float4 a=A[i], b=B[i];
            acc += a.x*b.x + a.y*b.y + a.z*b.z + a.w*b.w;
        }
        float dd = fmaxf(sq[i0+li] + sq[j0+lj] - 2.f*acc, 0.f);
        d2[(size_t)(i0+li)*1024 + j0+lj] = dd;
        lm = fmaxf(lm, dd);
    }
    lm = block_max_f(lm,sred,4);
    if(tid==0) atomicMax(maxbits, __float_as_uint(lm));
}

// ---------------- out = 1 - sqrt(d2+eps)/maxd
__global__ __launch_bounds__(256) void k_final(
    const float* __restrict__ d2, const unsigned int* __restrict__ maxbits, float* __restrict__ out)
{
    int idx = blockIdx.x*256 + threadIdx.x;
    float md = sqrtf(__uint_as_float(*maxbits) + 1e-12f);
    out[idx] = 1.f - sqrtf(d2[idx] + 1e-12f)/md;
}

extern "C" void kernel_launch(void* const* d_in, const int* in_sizes, int n_in,
                              void* d_out, int out_size, void* d_ws, size_t ws_size,
                              hipStream_t stream)
{
    const float* x   = (const float*)d_in[0];
    const float* c1w = (const float*)d_in[1];  const float* c1b = (const float*)d_in[2];
    const float* g1g = (const float*)d_in[3];  const float* g1b = (const float*)d_in[4];
    const float* c2w = (const float*)d_in[5];  const float* c2b = (const float*)d_in[6];
    const float* g2g = (const float*)d_in[7];  const float* g2b = (const float*)d_in[8];
    const float* c3w = (const float*)d_in[9];  const float* c3b = (const float*)d_in[10];
    const float* g3g = (const float*)d_in[11]; const float* g3b = (const float*)d_in[12];
    const float* f1w = (const float*)d_in[13]; const float* f1b = (const float*)d_in[14];
    const float* wq  = (const float*)d_in[15]; const float* bq  = (const float*)d_in[16];
    const float* wk  = (const float*)d_in[17]; const float* bk  = (const float*)d_in[18];
    const float* wv  = (const float*)d_in[19]; const float* bv  = (const float*)d_in[20];

    float* W = (float*)d_ws;
    float* e0   = W;                 // 1,048,576
    float* attn = W + 1048576;       // 1,048,576
    float* avb  = W + 2097152;       //   131,072
    float* eab  = W + 2228224;       //   131,072
    float* d2b  = W + 2359296;       // 1,048,576
    float* buf1 = W;                 // stage1 out (dead before e0 written)
    float* buf2 = W + 18874368;      // stage2 out
    float* wt   = W + 22020096;
    float* wqt  = W + 22151168;
    float* wkt  = W + 22167552;
    float* wvt  = W + 22183936;
    float* eb   = W + 22200320;
    float* qb   = W + 22331392;
    float* kpb  = W + 22462464;
    float* vb   = W + 22593536;
    float* sqb  = W + 22724608;
    unsigned int* maxb = (unsigned int*)(W + 22725632);
    short* w2bf = (short*)(W + 22725648);   // 49,152 bf16 = 24,576 floats
    short* w3bf = (short*)(W + 22750224);   // 196,608 bf16 = 98,304 floats
    short* w1bf = (short*)(W + 22848528);   // 1,024 bf16 = 512 floats

    k_prep<<<1670,256,0,stream>>>(f1w, wq, wk, wv, c1w, c2w, c3w,
                                  wt, wqt, wkt, wvt, w1bf, w2bf, w3bf);

    k_conv1m<<<1024,768,0,stream>>>(x, w1bf, c1b, g1g, g1b, buf1);
    k_conv2m<<<1024,512,0,stream>>>(buf1, w2bf, c2b, g2g, g2b, buf2);
    k_conv3m<<<512,512,0,stream>>>(buf2, w3bf, c3b, g3g, g3b, e0);

    k_fc1<<<1024,256,0,stream>>>(e0, wt, f1b, eb);
    k_qkv<<<1024,256,0,stream>>>(eb, wqt,bq, wkt,bk, wvt,bv, qb,kpb,vb);
    k_attn<<<1024,256,0,stream>>>(qb, kpb, attn);
    k_av<<<1024,256,0,stream>>>(attn, vb, avb);

    hipMemsetAsync(maxb, 0, 4, stream);
    k_colpipe<<<128,256,0,stream>>>(avb, eb, eab);
    k_sq<<<1024,128,0,stream>>>(eab, sqb);
    k_gram<<<dim3(32,32),256,0,stream>>>(eab, sqb, d2b, maxb);
    k_final<<<4096,256,0,stream>>>(d2b, maxb, (float*)d_out);
}

// Round 9
// 387.886 us; speedup vs baseline: 10.9652x; 1.0890x over previous
//
#include <hip/hip_runtime.h>
#include <hip/hip_bf16.h>
#include <math.h>

#define SELU_SCALE 1.0507009873554805f
#define SELU_SA    1.7580993408473766f   // scale*alpha

typedef __attribute__((ext_vector_type(8))) short short8;
typedef __attribute__((ext_vector_type(4))) short short4v;
typedef __attribute__((ext_vector_type(4))) float f32x4;

// fast SELU: x>0 ? s*x : sa*exp(x)-sa   (hw v_exp_f32; ~1e-7 abs err for x<=0)
__device__ __forceinline__ float selu_f(float x){
    return x > 0.f ? SELU_SCALE * x : fmaf(SELU_SA, __expf(x), -SELU_SA);
}

__device__ __forceinline__ unsigned short bfc(float v){
    __hip_bfloat16 h = __float2bfloat16(v);
    return __builtin_bit_cast(unsigned short, h);
}
__device__ __forceinline__ float f_bf(unsigned short u){
    unsigned int x = ((unsigned int)u) << 16;
    return __builtin_bit_cast(float, x);
}

__device__ __forceinline__ float warp_sum(float v){
    #pragma unroll
    for(int o=32;o>0;o>>=1) v += __shfl_down(v,o,64);
    return v;
}
__device__ __forceinline__ float warp_max(float v){
    #pragma unroll
    for(int o=32;o>0;o>>=1) v = fmaxf(v,__shfl_down(v,o,64));
    return v;
}

__device__ __forceinline__ void block_sum2(float &a, float &b, float* sred, int nw){
    int lane = threadIdx.x & 63, w = threadIdx.x >> 6;
    a = warp_sum(a); b = warp_sum(b);
    __syncthreads();
    if(lane==0){ sred[w]=a; sred[16+w]=b; }
    __syncthreads();
    if(w==0){
        float x = (lane<nw)? sred[lane] : 0.f;
        float y = (lane<nw)? sred[16+lane] : 0.f;
        x = warp_sum(x); y = warp_sum(y);
        if(lane==0){ sred[0]=x; sred[16]=y; }
    }
    __syncthreads();
    a = sred[0]; b = sred[16];
}

__device__ __forceinline__ float block_max_f(float v, float* sred, int nw){
    int lane = threadIdx.x & 63, w = threadIdx.x >> 6;
    v = warp_max(v);
    __syncthreads();
    if(lane==0) sred[w]=v;
    __syncthreads();
    if(w==0){
        float x = (lane<nw)? sred[lane] : -INFINITY;
        x = warp_max(x);
        if(lane==0) sred[0]=x;
    }
    __syncthreads();
    return sred[0];
}

// ---------------- unified weight prep
__global__ void k_prep(const float* __restrict__ f1w, const float* __restrict__ wq,
                       const float* __restrict__ wk, const float* __restrict__ wv,
                       const float* __restrict__ w1, const float* __restrict__ w2,
                       const float* __restrict__ w3,
                       float* __restrict__ wt, float* __restrict__ wqt,
                       float* __restrict__ wkt, float* __restrict__ wvt,
                       short* __restrict__ w1bf, short* __restrict__ w2bf,
                       short* __restrict__ w3bf){
    int idx = blockIdx.x*256 + threadIdx.x;
    if(idx < 131072){ int r = idx >> 10, cc = idx & 1023; wt[cc*128 + r] = f1w[idx]; return; }
    idx -= 131072;
    if(idx < 16384){ int r = idx >> 7, cc = idx & 127; wqt[cc*128 + r] = wq[idx]; return; }
    idx -= 16384;
    if(idx < 16384){ int r = idx >> 7, cc = idx & 127; wkt[cc*128 + r] = wk[idx]; return; }
    idx -= 16384;
    if(idx < 16384){ int r = idx >> 7, cc = idx & 127; wvt[cc*128 + r] = wv[idx]; return; }
    idx -= 16384;
    if(idx < 49152){
        int t = idx >> 11, rem = idx & 2047;
        int oc = rem >> 5, ic = rem & 31;
        w2bf[idx] = (short)bfc(w2[oc*768 + ic*24 + t]);
        return;
    }
    idx -= 49152;
    if(idx < 196608){
        int t = idx >> 13, rem = idx & 8191;
        int oc = rem >> 6, ic = rem & 63;
        w3bf[idx] = (short)bfc(w3[oc*1536 + ic*24 + t]);
        return;
    }
    idx -= 196608;
    if(idx < 1024){
        int oc = idx >> 5, k = idx & 31;
        w1bf[idx] = (k < 24) ? (short)bfc(w1[oc*24 + k]) : (short)0;
    }
}

// ============ Stage 1 (MFMA): conv1(1->32) + SELU + GN(1ch/grp) + maxpool(2,4)
// 1 block = 1 sample, 768 thr = 12 waves. GEMM: out[32oc][4608px], K=32 (24 taps + 8 zero).
// LDS sdup rows padded to 528 B (qr groups -> +8 banks, 2-way = free; was 4-way @512).
// pmax/pmin window stride 72 B (bank stride 18 -> 4-way; was 32-way @64 in the readout).
__global__ __launch_bounds__(768,1) void k_conv1m(
    const float* __restrict__ x, const short* __restrict__ w1bf,
    const float* __restrict__ bias, const float* __restrict__ g,
    const float* __restrict__ be, float* __restrict__ out)
{
    int s = blockIdx.x, tid = threadIdx.x;
    int l = tid & 63, wv = tid >> 6;          // wv 0..11
    int c = l & 15, qr = l >> 4;
    __shared__ char smem[127728];
    short* sdup = (short*)smem;               // 79 rows x 528 B = 41,712
    char* pmaxb = smem + 41712;               // [576 win x 72 B] = 41,472
    char* pminb = smem + 83184;               // 41,472
    float* sredf = (float*)(smem + 124656);   // [12][4][8][2] = 768 floats
    __shared__ float scsh[64];                // [32 oc][sc,sh]

    const float* xs = x + (size_t)s*4608;
    // stage packs: sdup[yp][off=xx&3][xq=xx>>2] = in_pad[yp][xx..xx+3] bf16x4
    for(int i = tid; i < 5056; i += 768){
        int yp = i >> 6, xx = i & 63;
        unsigned long long pk = 0ull;
        if(yp >= 2 && yp < 74){
            const float* row = xs + (yp-2)*64;
            #pragma unroll
            for(int t=0;t<4;t++){
                int cp = xx + t;
                float f = (cp>=1 && cp<65) ? row[cp-1] : 0.f;
                pk |= (unsigned long long)bfc(f) << (16*t);
            }
        }
        *(unsigned long long*)((char*)sdup + yp*528 + (xx&3)*128 + (xx>>2)*8) = pk;
    }
    short8 a0 = *(const short8*)(w1bf + c*32 + qr*8);
    short8 a1 = *(const short8*)(w1bf + (16+c)*32 + qr*8);
    float bias8[8];
    #pragma unroll
    for(int t=0;t<2;t++)
        #pragma unroll
        for(int r=0;r<4;r++) bias8[t*4+r] = bias[t*16 + qr*4 + r];
    float ssum8[8], ssq8[8];
    #pragma unroll
    for(int i=0;i<8;i++){ ssum8[i]=0.f; ssq8[i]=0.f; }
    __syncthreads();

    #pragma unroll 1
    for(int u=0; u<3; u++){
        int py = wv*3 + u;                    // 12 waves x 3 = 36 row-pairs
        float pmx[8], pmn[8];
        #pragma unroll
        for(int i=0;i<8;i++){ pmx[i]=-INFINITY; pmn[i]=INFINITY; }
        #pragma unroll
        for(int off=0; off<4; off++){
            const char* bb = (const char*)sdup + off*128 + c*8;
            #pragma unroll
            for(int rr=0; rr<2; rr++){
                int y = py*2 + rr;
                short4v lo = *(const short4v*)(bb + (y+2*qr)*528);
                short4v hi = *(const short4v*)(bb + (y+2*qr+1)*528);
                short8 bfrag = __builtin_shufflevector(lo, hi, 0,1,2,3,4,5,6,7);
                f32x4 d0 = __builtin_amdgcn_mfma_f32_16x16x32_bf16(a0, bfrag, (f32x4){0.f,0.f,0.f,0.f}, 0,0,0);
                f32x4 d1 = __builtin_amdgcn_mfma_f32_16x16x32_bf16(a1, bfrag, (f32x4){0.f,0.f,0.f,0.f}, 0,0,0);
                #pragma unroll
                for(int r=0;r<4;r++){
                    float v0 = selu_f(d0[r] + bias8[r]);
                    float v1 = selu_f(d1[r] + bias8[4+r]);
                    ssum8[r]   += v0; ssq8[r]   = fmaf(v0,v0,ssq8[r]);
                    ssum8[4+r] += v1; ssq8[4+r] = fmaf(v1,v1,ssq8[4+r]);
                    pmx[r]   = fmaxf(pmx[r],   v0); pmn[r]   = fminf(pmn[r],   v0);
                    pmx[4+r] = fmaxf(pmx[4+r], v1); pmn[4+r] = fminf(pmn[4+r], v1);
                }
            }
        }
        int base = (py*16 + c)*72;            // padded window stride
        #pragma unroll
        for(int t=0;t<2;t++){
            unsigned long long mpk=0ull, npk=0ull;
            #pragma unroll
            for(int r=0;r<4;r++){
                mpk |= (unsigned long long)bfc(pmx[t*4+r]) << (16*r);
                npk |= (unsigned long long)bfc(pmn[t*4+r]) << (16*r);
            }
            *(unsigned long long*)(pmaxb + base + t*32 + qr*8) = mpk;
            *(unsigned long long*)(pminb + base + t*32 + qr*8) = npk;
        }
    }
    #pragma unroll
    for(int off=1; off<16; off<<=1){
        #pragma unroll
        for(int i=0;i<8;i++){
            ssum8[i] += __shfl_xor(ssum8[i], off);
            ssq8[i]  += __shfl_xor(ssq8[i],  off);
        }
    }
    if(c == 0){
        #pragma unroll
        for(int i=0;i<8;i++){
            sredf[((wv*4 + qr)*8 + i)*2]     = ssum8[i];
            sredf[((wv*4 + qr)*8 + i)*2 + 1] = ssq8[i];
        }
    }
    __syncthreads();
    if(tid < 32){
        int oc = tid;
        int t = oc >> 4, rem = oc & 15, q = rem >> 2, r = rem & 3;
        int i = t*4 + r;
        float sum=0.f, sq=0.f;
        for(int w=0; w<12; w++){
            sum += sredf[((w*4+q)*8+i)*2];
            sq  += sredf[((w*4+q)*8+i)*2+1];
        }
        float mean = sum*(1.f/4608.f);
        float var  = sq*(1.f/4608.f) - mean*mean;
        float inv  = rsqrtf(var + 1e-5f);
        float sc = g[oc]*inv;
        scsh[oc*2]   = sc;
        scsh[oc*2+1] = be[oc] - mean*sc;
    }
    __syncthreads();
    float* ob = out + (size_t)s*18432;
    for(int i = tid; i < 18432; i += 768){
        int oc = i / 576, wpx = i - oc*576;
        float sc = scsh[oc*2], sh = scsh[oc*2+1];
        int boff = wpx*72 + oc*2;
        float vm = f_bf(*(unsigned short*)(pmaxb + boff));
        float vn = f_bf(*(unsigned short*)(pminb + boff));
        ob[i] = fmaf(sc, (sc >= 0.f) ? vm : vn, sh);
    }
}

// ============ Stage 2 (MFMA): conv2(32->64) + SELU + GN(2ch/grp) + maxpool(3,4)
__global__ __launch_bounds__(512,2) void k_conv2m(
    const float* __restrict__ in, const short* __restrict__ w2bf,
    const float* __restrict__ bias, const float* __restrict__ g,
    const float* __restrict__ be, float* __restrict__ out)
{
    int s = blockIdx.x, tid = threadIdx.x;
    int l = tid & 63, wv = tid >> 6;
    int ocp = wv >> 2, yq = wv & 3;
    int xc = l & 15, qr = l >> 4;
    __shared__ short sinb[26240];            // 41*20*32 bf16 = 52,480 B
    __shared__ float sred[2][4][2][4][2][2];
    int* zp = (int*)sinb;
    for(int i=tid;i<13120;i+=512) zp[i]=0;
    __syncthreads();
    const float* ibase = in + (size_t)s*18432;
    #pragma unroll
    for(int h=0;h<2;h++){
        int ic = (wv*2+h)*2;
        #pragma unroll
        for(int k=0;k<9;k++){
            int px = l + 64*k;
            float v0 = ibase[ic*576 + px];
            float v1 = ibase[(ic+1)*576 + px];
            int R = (px>>4)+2, C = (px&15)+1;
            int key = (C>>1)&3;
            int q0 = ic>>3;
            int byteoff = (R*20+C)*64 + (((q0^key)&3)<<4) + (ic&7)*2;
            *(unsigned int*)((char*)sinb + byteoff) =
                (unsigned int)bfc(v0) | ((unsigned int)bfc(v1)<<16);
        }
    }
    __syncthreads();
    f32x4 acc[2][9];
    #pragma unroll
    for(int o=0;o<2;o++)
        #pragma unroll
        for(int yt=0;yt<9;yt++) acc[o][yt] = (f32x4){0.f,0.f,0.f,0.f};
    const short8* wb = (const short8*)w2bf;
    int arow = ocp*32 + xc;
    short8 a0 = wb[arow*4 + qr];
    short8 a1 = wb[(arow+16)*4 + qr];
    char* sb = (char*)sinb;
    for(int tap=0; tap<24; tap++){
        short8 na0, na1;
        if(tap<23){
            na0 = wb[((tap+1)*64 + arow)*4 + qr];
            na1 = wb[((tap+1)*64 + arow + 16)*4 + qr];
        }
        int kh = tap>>2, kw = tap&3;
        int C = xc + kw;
        int cb = C*64 + (((qr ^ ((C>>1)&3))&3)<<4);
        int rb = (yq*9 + kh)*1280;
        #pragma unroll
        for(int yt=0;yt<9;yt++){
            short8 bf_ = *(const short8*)(sb + rb + yt*1280 + cb);
            acc[0][yt] = __builtin_amdgcn_mfma_f32_16x16x32_bf16(a0, bf_, acc[0][yt], 0,0,0);
            acc[1][yt] = __builtin_amdgcn_mfma_f32_16x16x32_bf16(a1, bf_, acc[1][yt], 0,0,0);
        }
        a0 = na0; a1 = na1;
    }
    #pragma unroll
    for(int o=0;o<2;o++){
        int ocb = (ocp*2+o)*16 + qr*4;
        float b0 = bias[ocb], b1 = bias[ocb+1], b2 = bias[ocb+2], b3 = bias[ocb+3];
        float s0=0,q0=0,s1=0,q1=0;
        #pragma unroll
        for(int yt=0;yt<9;yt++){
            float v0=selu_f(acc[o][yt][0]+b0), v1=selu_f(acc[o][yt][1]+b1);
            float v2=selu_f(acc[o][yt][2]+b2), v3=selu_f(acc[o][yt][3]+b3);
            acc[o][yt][0]=v0; acc[o][yt][1]=v1; acc[o][yt][2]=v2; acc[o][yt][3]=v3;
            s0+=v0+v1; q0+=v0*v0+v1*v1; s1+=v2+v3; q1+=v2*v2+v3*v3;
        }
        #pragma unroll
        for(int off=1;off<16;off<<=1){
            s0+=__shfl_xor(s0,off); q0+=__shfl_xor(q0,off);
            s1+=__shfl_xor(s1,off); q1+=__shfl_xor(q1,off);
        }
        if(xc==0){
            sred[ocp][yq][o][qr][0][0]=s0; sred[ocp][yq][o][qr][0][1]=q0;
            sred[ocp][yq][o][qr][1][0]=s1; sred[ocp][yq][o][qr][1][1]=q1;
        }
    }
    __syncthreads();
    float* ob = out + (size_t)s*64*48;
    #pragma unroll
    for(int o=0;o<2;o++){
        #pragma unroll
        for(int grp=0;grp<2;grp++){
            float ts=0, tq=0;
            #pragma unroll
            for(int y2=0;y2<4;y2++){ ts += sred[ocp][y2][o][qr][grp][0]; tq += sred[ocp][y2][o][qr][grp][1]; }
            float mean = ts*(1.f/1152.f);
            float var  = tq*(1.f/1152.f) - mean*mean;
            float inv  = rsqrtf(var + 1e-5f);
            int oc0 = (ocp*2+o)*16 + qr*4 + grp*2;
            float sc0 = g[oc0]*inv,   sh0 = be[oc0]   - mean*sc0;
            float sc1 = g[oc0+1]*inv, sh1 = be[oc0+1] - mean*sc1;
            #pragma unroll
            for(int yt=0;yt<9;yt++){
                acc[o][yt][grp*2]   = acc[o][yt][grp*2]*sc0 + sh0;
                acc[o][yt][grp*2+1] = acc[o][yt][grp*2+1]*sc1 + sh1;
            }
        }
        #pragma unroll
        for(int r=0;r<4;r++){
            #pragma unroll
            for(int py=0;py<3;py++){
                float m = fmaxf(fmaxf(acc[o][3*py][r],acc[o][3*py+1][r]),acc[o][3*py+2][r]);
                m = fmaxf(m, __shfl_xor(m,1));
                m = fmaxf(m, __shfl_xor(m,2));
                if((xc&3)==0){
                    int oc = (ocp*2+o)*16 + qr*4 + r;
                    ob[(size_t)oc*48 + (yq*3+py)*4 + (xc>>2)] = m;
                }
            }
        }
    }
}

// ============ Stage 3 (MFMA): conv3(64->128) + SELU + GN(4ch/grp) + maxpool(3,2)
__global__ __launch_bounds__(512,2) void k_conv3m(
    const float* __restrict__ in, const short* __restrict__ w3bf,
    const float* __restrict__ bias, const float* __restrict__ g,
    const float* __restrict__ be, float* __restrict__ e0)
{
    int sq = blockIdx.x, tid = threadIdx.x;
    int l = tid & 63, wv = tid >> 6;
    int ocp = wv >> 1, sL = wv & 1;
    int c = l & 15, qr = l >> 4;
    int yl = c >> 2, xl = c & 3;
    __shared__ char smem[49152];
    short* sinb = (short*)smem;
    int* zp = (int*)smem;
    for(int i=tid;i<8704;i+=512) zp[i]=0;
    __syncthreads();
    const float* ibase = in + (size_t)sq*6144;
    for(int j=0;j<6;j++){
        int idx = tid + 512*j;
        int px = idx % 48;
        int rest = idx / 48;
        int icp = rest & 31, ss = rest >> 5;
        int ic = icp*2;
        float v0 = ibase[ss*3072 + ic*48 + px];
        float v1 = ibase[ss*3072 + (ic+1)*48 + px];
        int R = (px>>2)+2, C = (px&3)+1;
        int pos = ss*136 + R*8 + C;
        int key = ((R&1)<<2) | (C&3);
        int q0 = ic>>3;
        int byteoff = pos*128 + (((q0^key)&7)<<4) + (ic&7)*2;
        *(unsigned int*)(smem + byteoff) = (unsigned int)bfc(v0) | ((unsigned int)bfc(v1)<<16);
    }
    __syncthreads();
    f32x4 acc[2][3];
    #pragma unroll
    for(int o=0;o<2;o++)
        #pragma unroll
        for(int yt=0;yt<3;yt++) acc[o][yt] = (f32x4){0.f,0.f,0.f,0.f};
    const short8* wb = (const short8*)w3bf;
    int arow = ocp*32 + c;
    char* sb = smem + sL*17408;
    short8 a0 = wb[arow*8 + qr];
    short8 a1 = wb[(arow+16)*8 + qr];
    for(int t2=0; t2<48; t2++){
        short8 na0, na1;
        if(t2<47){
            int nt = t2+1;
            na0 = wb[((nt>>1)*128 + arow)*8 + (nt&1)*4 + qr];
            na1 = wb[((nt>>1)*128 + arow + 16)*8 + (nt&1)*4 + qr];
        }
        int tap = t2>>1, ks = t2&1;
        int kh = tap>>2, kw = tap&3;
        int C = xl + kw;
        int q0 = ks*4 + qr;
        #pragma unroll
        for(int yt=0;yt<3;yt++){
            int R = yt*4 + yl + kh;
            int key = ((R&1)<<2) | (C&3);
            short8 bf_ = *(const short8*)(sb + (R*8+C)*128 + (((q0^key)&7)<<4));
            acc[0][yt] = __builtin_amdgcn_mfma_f32_16x16x32_bf16(a0, bf_, acc[0][yt], 0,0,0);
            acc[1][yt] = __builtin_amdgcn_mfma_f32_16x16x32_bf16(a1, bf_, acc[1][yt], 0,0,0);
        }
        a0 = na0; a1 = na1;
    }
    #pragma unroll
    for(int o=0;o<2;o++){
        int ocb = (ocp*2+o)*16 + qr*4;
        float b0 = bias[ocb], b1 = bias[ocb+1], b2 = bias[ocb+2], b3 = bias[ocb+3];
        float ssum=0.f, ssq=0.f;
        #pragma unroll
        for(int yt=0;yt<3;yt++){
            float v0=selu_f(acc[o][yt][0]+b0), v1=selu_f(acc[o][yt][1]+b1);
            float v2=selu_f(acc[o][yt][2]+b2), v3=selu_f(acc[o][yt][3]+b3);
            acc[o][yt][0]=v0; acc[o][yt][1]=v1; acc[o][yt][2]=v2; acc[o][yt][3]=v3;
            ssum += v0+v1+v2+v3; ssq += v0*v0+v1*v1+v2*v2+v3*v3;
        }
        #pragma unroll
        for(int off=1;off<16;off<<=1){ ssum+=__shfl_xor(ssum,off); ssq+=__shfl_xor(ssq,off); }
        float mean = ssum*(1.f/192.f);
        float var  = ssq*(1.f/192.f) - mean*mean;
        float inv  = rsqrtf(var + 1e-5f);
        #pragma unroll
        for(int r=0;r<4;r++){
            int oc = ocb + r;
            float sc = g[oc]*inv, sh = be[oc] - mean*sc;
            #pragma unroll
            for(int yt=0;yt<3;yt++) acc[o][yt][r] = acc[o][yt][r]*sc + sh;
        }
    }
    __syncthreads();
    float* scr = (float*)smem + wv*1536;
    #pragma unroll
    for(int o=0;o<2;o++)
        #pragma unroll
        for(int yt=0;yt<3;yt++)
            #pragma unroll
            for(int r=0;r<4;r++){
                int px = (yt*4+yl)*4 + xl;
                scr[o*768 + (qr*4+r)*48 + px] = acc[o][yt][r];
            }
    __syncthreads();
    float* sr = (float*)smem + wv*1536 + (l>>5)*768 + ((l>>1)&15)*48;
    int x2 = l&1;
    float* eo = e0 + (size_t)(sq*2+sL)*1024 + ((size_t)(ocp*2 + (l>>5))*16 + ((l>>1)&15))*8;
    #pragma unroll
    for(int py=0;py<4;py++){
        float m = sr[(py*3)*4 + x2*2];
        m = fmaxf(m, sr[(py*3)*4 + x2*2+1]);
        m = fmaxf(m, sr[(py*3+1)*4 + x2*2]);
        m = fmaxf(m, sr[(py*3+1)*4 + x2*2+1]);
        m = fmaxf(m, sr[(py*3+2)*4 + x2*2]);
        m = fmaxf(m, sr[(py*3+2)*4 + x2*2+1]);
        eo[py*2 + x2] = m;
    }
}

// ---------------- FC1 + SELU + row l2norm + QKV + PE  (fused; same s)
__global__ __launch_bounds__(256) void k_fcqkv(
    const float* __restrict__ e0, const float* __restrict__ wt,
    const float* __restrict__ bias, float* __restrict__ e,
    const float* __restrict__ wqt, const float* __restrict__ bq,
    const float* __restrict__ wkt, const float* __restrict__ bk,
    const float* __restrict__ wvt, const float* __restrict__ bv,
    float* __restrict__ q, float* __restrict__ kp, float* __restrict__ v)
{
    int s = blockIdx.x, tid = threadIdx.x;
    int j = tid & 127, half = tid >> 7;
    __shared__ float se[1024];
    __shared__ float sp[2][128];
    __shared__ float sred[2];
    __shared__ float se2[128];
    __shared__ float sp3[3][2][128];
    for(int i=tid;i<1024;i+=256) se[i] = e0[(size_t)s*1024+i];
    __syncthreads();
    float acc = half ? 0.f : bias[j];
    const float* wp = wt + (size_t)half*512*128 + j;
    const float* sep = se + half*512;
    #pragma unroll 8
    for(int i=0;i<512;i++) acc += sep[i]*wp[(size_t)i*128];
    sp[half][j] = acc;
    __syncthreads();
    if(half==0){
        float vv = selu_f(sp[0][j]+sp[1][j]);
        float a = vv*vv;
        #pragma unroll
        for(int o=1;o<64;o<<=1) a += __shfl_xor(a,o);
        if((j&63)==0) sred[j>>6]=a;
    }
    __syncthreads();
    if(half==0){
        float den = fmaxf(sqrtf(sred[0]+sred[1]), 1e-12f);
        float vv = selu_f(sp[0][j]+sp[1][j]);
        float ev = vv/den;
        se2[j] = ev;
        e[(size_t)s*128+j] = ev;
    }
    __syncthreads();
    float aq = half?0.f:bq[j], ak = half?0.f:bk[j], av = half?0.f:bv[j];
    int i0 = half*64;
    #pragma unroll 8
    for(int i=i0;i<i0+64;i++){
        float f = se2[i];
        aq += f*wqt[i*128+j];
        ak += f*wkt[i*128+j];
        av += f*wvt[i*128+j];
    }
    sp3[0][half][j]=aq; sp3[1][half][j]=ak; sp3[2][half][j]=av;
    __syncthreads();
    if(half==0){
        float vq = selu_f(sp3[0][0][j]+sp3[0][1][j]);
        float vk = selu_f(sp3[1][0][j]+sp3[1][1][j]);
        float vv = selu_f(sp3[2][0][j]+sp3[2][1][j]);
        int i2 = j & ~1;
        float div = __expf(-(float)i2 * 0.07195578412155481f);
        float ang = (float)s * div;
        float pe = (j & 1) ? cosf(ang) : sinf(ang);
        q[(size_t)s*128+j]  = vq;
        kp[(size_t)s*128+j] = vk + pe;
        v[(size_t)s*128+j]  = vv;
    }
}

// ---------------- fused scores + softmax + PV: av[s] = softmax(q_s K^T/sqrt(d)) @ V
__global__ __launch_bounds__(256) void k_attnav(
    const float* __restrict__ q, const float* __restrict__ kp,
    const float* __restrict__ v, float* __restrict__ av)
{
    int s = blockIdx.x, tid = threadIdx.x;
    __shared__ float sq_[128];
    __shared__ float sredm[32];
    __shared__ float spb[1024];
    __shared__ float spart[2][128];
    if(tid < 128) sq_[tid] = q[(size_t)s*128+tid];
    __syncthreads();
    float val[4];
    const float4* qr = (const float4*)sq_;
    #pragma unroll
    for(int k2=0;k2<4;k2++){
        int t = tid + k2*256;
        const float4* kr = (const float4*)(kp + (size_t)t*128);
        float acc=0.f;
        #pragma unroll 8
        for(int i=0;i<32;i++){
            float4 a=qr[i], b=kr[i];
            acc += a.x*b.x + a.y*b.y + a.z*b.z + a.w*b.w;
        }
        val[k2] = acc * 0.08838834764831845f;
    }
    float m = fmaxf(fmaxf(val[0],val[1]), fmaxf(val[2],val[3]));
    m = block_max_f(m,sredm,4);
    float lsum=0.f, dummy=0.f;
    #pragma unroll
    for(int k2=0;k2<4;k2++){ val[k2]=__expf(val[k2]-m); lsum+=val[k2]; }
    block_sum2(lsum,dummy,sredm,4);
    float invs = 1.f/lsum;
    #pragma unroll
    for(int k2=0;k2<4;k2++) spb[tid + k2*256] = val[k2]*invs;
    __syncthreads();
    int j = tid & 127, half = tid >> 7;
    float acc=0.f;
    int t0 = half*512;
    for(int t=t0;t<t0+512;t++) acc += spb[t]*v[(size_t)t*128+j];
    spart[half][j] = acc;
    __syncthreads();
    if(half==0) av[(size_t)s*128+j] = spart[0][j] + spart[1][j];
}

// ---------------- column pipeline: n1 = ||av[:,j]||, out = av/n1 + e, n2, ea = out/n2
__global__ __launch_bounds__(256) void k_colpipe(
    const float* __restrict__ av, const float* __restrict__ e, float* __restrict__ ea)
{
    int j = blockIdx.x, t = threadIdx.x;
    __shared__ float sred[4];
    float v[4];
    float ss = 0.f;
    #pragma unroll
    for(int k=0;k<4;k++){
        v[k] = av[(size_t)(t + 256*k)*128 + j];
        ss += v[k]*v[k];
    }
    #pragma unroll
    for(int off=1;off<64;off<<=1) ss += __shfl_xor(ss,off);
    int lane = t & 63, w = t >> 6;
    if(lane==0) sred[w]=ss;
    __syncthreads();
    float n1 = fmaxf(sqrtf(sred[0]+sred[1]+sred[2]+sred[3]), 1e-12f);
    __syncthreads();
    float ss2 = 0.f;
    #pragma unroll
    for(int k=0;k<4;k++){
        float o = v[k]/n1 + e[(size_t)(t + 256*k)*128 + j];
        v[k] = o;
        ss2 += o*o;
    }
    #pragma unroll
    for(int off=1;off<64;off<<=1) ss2 += __shfl_xor(ss2,off);
    if(lane==0) sred[w]=ss2;
    __syncthreads();
    float n2 = fmaxf(sqrtf(sred[0]+sred[1]+sred[2]+sred[3]), 1e-12f);
    #pragma unroll
    for(int k=0;k<4;k++) ea[(size_t)(t + 256*k)*128 + j] = v[k]/n2;
}

// ---------------- sq[s] = ||ea[s,:]||^2
__global__ __launch_bounds__(128) void k_sq(const float* __restrict__ ea, float* __restrict__ sq){
    int s = blockIdx.x, j = threadIdx.x;
    __shared__ float sred[32];
    float v = ea[(size_t)s*128+j];
    float a=v*v, b=0.f;
    block_sum2(a,b,sred,2);
    if(j==0) sq[s]=a;
}

// ---------------- pairwise d2 + global max(d2) via atomic bits-max
__global__ __launch_bounds__(256) void k_gram(
    const float* __restrict__ ea, const float* __restrict__ sq,
    float* __restrict__ d2, unsigned int* __restrict__ maxbits)
{
    int j0 = blockIdx.x*32, i0 = blockIdx.y*32, tid = threadIdx.x;
    __shared__ float sa[32*128];
    __shared__ float sb[32*128];
    __shared__ float sred[32];
    for(int idx=tid;idx<4096;idx+=256){
        sa[idx] = ea[(size_t)i0*128 + idx];
        sb[idx] = ea[(size_t)j0*128 + idx];
    }
    __syncthreads();
    float lm = 0.f;
    #pragma unroll
    for(int k2=0;k2<4;k2++){
        int p = tid + k2*256;
        int li = p>>5, lj = p&31;
        const float4* A = (const float4*)(sa + li*128);
        const float4* B = (const float4*)(sb + lj*128);
        float acc=0.f;
        #pragma unroll 8
        for(int i=0;i<32;i++){
            float4 a=A[i], b=B[i];
            acc += a.x*b.x + a.y*b.y + a.z*b.z + a.w*b.w;
        }
        float dd = fmaxf(sq[i0+li] + sq[j0+lj] - 2.f*acc, 0.f);
        d2[(size_t)(i0+li)*1024 + j0+lj] = dd;
        lm = fmaxf(lm, dd);
    }
    lm = block_max_f(lm,sred,4);
    if(tid==0) atomicMax(maxbits, __float_as_uint(lm));
}

// ---------------- out = 1 - sqrt(d2+eps)/maxd
__global__ __launch_bounds__(256) void k_final(
    const float* __restrict__ d2, const unsigned int* __restrict__ maxbits, float* __restrict__ out)
{
    int idx = blockIdx.x*256 + threadIdx.x;
    float md = sqrtf(__uint_as_float(*maxbits) + 1e-12f);
    out[idx] = 1.f - sqrtf(d2[idx] + 1e-12f)/md;
}

extern "C" void kernel_launch(void* const* d_in, const int* in_sizes, int n_in,
                              void* d_out, int out_size, void* d_ws, size_t ws_size,
                              hipStream_t stream)
{
    const float* x   = (const float*)d_in[0];
    const float* c1w = (const float*)d_in[1];  const float* c1b = (const float*)d_in[2];
    const float* g1g = (const float*)d_in[3];  const float* g1b = (const float*)d_in[4];
    const float* c2w = (const float*)d_in[5];  const float* c2b = (const float*)d_in[6];
    const float* g2g = (const float*)d_in[7];  const float* g2b = (const float*)d_in[8];
    const float* c3w = (const float*)d_in[9];  const float* c3b = (const float*)d_in[10];
    const float* g3g = (const float*)d_in[11]; const float* g3b = (const float*)d_in[12];
    const float* f1w = (const float*)d_in[13]; const float* f1b = (const float*)d_in[14];
    const float* wq  = (const float*)d_in[15]; const float* bq  = (const float*)d_in[16];
    const float* wk  = (const float*)d_in[17]; const float* bk  = (const float*)d_in[18];
    const float* wv  = (const float*)d_in[19]; const float* bv  = (const float*)d_in[20];

    float* W = (float*)d_ws;
    float* e0   = W;                 // 1,048,576
    float* avb  = W + 2097152;       //   131,072
    float* eab  = W + 2228224;       //   131,072
    float* d2b  = W + 2359296;       // 1,048,576
    float* buf1 = W;                 // stage1 out (dead before e0 written)
    float* buf2 = W + 18874368;      // stage2 out
    float* wt   = W + 22020096;
    float* wqt  = W + 22151168;
    float* wkt  = W + 22167552;
    float* wvt  = W + 22183936;
    float* eb   = W + 22200320;
    float* qb   = W + 22331392;
    float* kpb  = W + 22462464;
    float* vb   = W + 22593536;
    float* sqb  = W + 22724608;
    unsigned int* maxb = (unsigned int*)(W + 22725632);
    short* w2bf = (short*)(W + 22725648);   // 49,152 bf16
    short* w3bf = (short*)(W + 22750224);   // 196,608 bf16
    short* w1bf = (short*)(W + 22848528);   // 1,024 bf16

    k_prep<<<1670,256,0,stream>>>(f1w, wq, wk, wv, c1w, c2w, c3w,
                                  wt, wqt, wkt, wvt, w1bf, w2bf, w3bf);

    k_conv1m<<<1024,768,0,stream>>>(x, w1bf, c1b, g1g, g1b, buf1);
    k_conv2m<<<1024,512,0,stream>>>(buf1, w2bf, c2b, g2g, g2b, buf2);
    k_conv3m<<<512,512,0,stream>>>(buf2, w3bf, c3b, g3g, g3b, e0);

    k_fcqkv<<<1024,256,0,stream>>>(e0, wt, f1b, eb, wqt,bq, wkt,bk, wvt,bv, qb,kpb,vb);
    k_attnav<<<1024,256,0,stream>>>(qb, kpb, vb, avb);

    hipMemsetAsync(maxb, 0, 4, stream);
    k_colpipe<<<128,256,0,stream>>>(avb, eb, eab);
    k_sq<<<1024,128,0,stream>>>(eab, sqb);
    k_gram<<<dim3(32,32),256,0,stream>>>(eab, sqb, d2b, maxb);
    k_final<<<4096,256,0,stream>>>(d2b, maxb, (float*)d_out);
}

// Round 10
// 367.883 us; speedup vs baseline: 11.5614x; 1.0544x over previous
//
#include <hip/hip_runtime.h>
#include <hip/hip_bf16.h>
#include <math.h>

#define SELU_SCALE 1.0507009873554805f
#define SELU_SA    1.7580993408473766f   // scale*alpha

typedef __attribute__((ext_vector_type(8))) short short8;
typedef __attribute__((ext_vector_type(4))) short short4v;
typedef __attribute__((ext_vector_type(4))) float f32x4;

// fast SELU: x>0 ? s*x : sa*exp(x)-sa   (hw v_exp_f32; ~1e-7 abs err for x<=0)
__device__ __forceinline__ float selu_f(float x){
    return x > 0.f ? SELU_SCALE * x : fmaf(SELU_SA, __expf(x), -SELU_SA);
}

__device__ __forceinline__ unsigned short bfc(float v){
    __hip_bfloat16 h = __float2bfloat16(v);
    return __builtin_bit_cast(unsigned short, h);
}
__device__ __forceinline__ float f_bf(unsigned short u){
    unsigned int x = ((unsigned int)u) << 16;
    return __builtin_bit_cast(float, x);
}

__device__ __forceinline__ float warp_max(float v){
    #pragma unroll
    for(int o=32;o>0;o>>=1) v = fmaxf(v,__shfl_down(v,o,64));
    return v;
}

// ---------------- unified weight prep
__global__ void k_prep(const float* __restrict__ f1w, const float* __restrict__ wq,
                       const float* __restrict__ wk, const float* __restrict__ wv,
                       const float* __restrict__ w1, const float* __restrict__ w2,
                       const float* __restrict__ w3,
                       float* __restrict__ wt, float* __restrict__ wqt,
                       float* __restrict__ wkt, float* __restrict__ wvt,
                       short* __restrict__ w1bf, short* __restrict__ w2bf,
                       short* __restrict__ w3bf){
    int idx = blockIdx.x*256 + threadIdx.x;
    if(idx < 131072){ int r = idx >> 10, cc = idx & 1023; wt[cc*128 + r] = f1w[idx]; return; }
    idx -= 131072;
    if(idx < 16384){ int r = idx >> 7, cc = idx & 127; wqt[cc*128 + r] = wq[idx]; return; }
    idx -= 16384;
    if(idx < 16384){ int r = idx >> 7, cc = idx & 127; wkt[cc*128 + r] = wk[idx]; return; }
    idx -= 16384;
    if(idx < 16384){ int r = idx >> 7, cc = idx & 127; wvt[cc*128 + r] = wv[idx]; return; }
    idx -= 16384;
    if(idx < 49152){
        int t = idx >> 11, rem = idx & 2047;
        int oc = rem >> 5, ic = rem & 31;
        w2bf[idx] = (short)bfc(w2[oc*768 + ic*24 + t]);
        return;
    }
    idx -= 49152;
    if(idx < 196608){
        int t = idx >> 13, rem = idx & 8191;
        int oc = rem >> 6, ic = rem & 63;
        w3bf[idx] = (short)bfc(w3[oc*1536 + ic*24 + t]);
        return;
    }
    idx -= 196608;
    if(idx < 1024){
        int oc = idx >> 5, k = idx & 31;
        w1bf[idx] = (k < 24) ? (short)bfc(w1[oc*24 + k]) : (short)0;
    }
}

// ============ Stage 1 (MFMA): conv1(1->32) + SELU + GN(1ch/grp) + maxpool(2,4)
__global__ __launch_bounds__(768,1) void k_conv1m(
    const float* __restrict__ x, const short* __restrict__ w1bf,
    const float* __restrict__ bias, const float* __restrict__ g,
    const float* __restrict__ be, float* __restrict__ out)
{
    int s = blockIdx.x, tid = threadIdx.x;
    int l = tid & 63, wv = tid >> 6;          // wv 0..11
    int c = l & 15, qr = l >> 4;
    __shared__ char smem[127728];
    short* sdup = (short*)smem;               // 79 rows x 528 B = 41,712
    char* pmaxb = smem + 41712;               // [576 win x 72 B] = 41,472
    char* pminb = smem + 83184;               // 41,472
    float* sredf = (float*)(smem + 124656);   // [12][4][8][2] = 768 floats
    __shared__ float scsh[64];                // [32 oc][sc,sh]

    const float* xs = x + (size_t)s*4608;
    for(int i = tid; i < 5056; i += 768){
        int yp = i >> 6, xx = i & 63;
        unsigned long long pk = 0ull;
        if(yp >= 2 && yp < 74){
            const float* row = xs + (yp-2)*64;
            #pragma unroll
            for(int t=0;t<4;t++){
                int cp = xx + t;
                float f = (cp>=1 && cp<65) ? row[cp-1] : 0.f;
                pk |= (unsigned long long)bfc(f) << (16*t);
            }
        }
        *(unsigned long long*)((char*)sdup + yp*528 + (xx&3)*128 + (xx>>2)*8) = pk;
    }
    short8 a0 = *(const short8*)(w1bf + c*32 + qr*8);
    short8 a1 = *(const short8*)(w1bf + (16+c)*32 + qr*8);
    float bias8[8];
    #pragma unroll
    for(int t=0;t<2;t++)
        #pragma unroll
        for(int r=0;r<4;r++) bias8[t*4+r] = bias[t*16 + qr*4 + r];
    float ssum8[8], ssq8[8];
    #pragma unroll
    for(int i=0;i<8;i++){ ssum8[i]=0.f; ssq8[i]=0.f; }
    __syncthreads();

    #pragma unroll 1
    for(int u=0; u<3; u++){
        int py = wv*3 + u;                    // 12 waves x 3 = 36 row-pairs
        float pmx[8], pmn[8];
        #pragma unroll
        for(int i=0;i<8;i++){ pmx[i]=-INFINITY; pmn[i]=INFINITY; }
        #pragma unroll
        for(int off=0; off<4; off++){
            const char* bb = (const char*)sdup + off*128 + c*8;
            #pragma unroll
            for(int rr=0; rr<2; rr++){
                int y = py*2 + rr;
                short4v lo = *(const short4v*)(bb + (y+2*qr)*528);
                short4v hi = *(const short4v*)(bb + (y+2*qr+1)*528);
                short8 bfrag = __builtin_shufflevector(lo, hi, 0,1,2,3,4,5,6,7);
                f32x4 d0 = __builtin_amdgcn_mfma_f32_16x16x32_bf16(a0, bfrag, (f32x4){0.f,0.f,0.f,0.f}, 0,0,0);
                f32x4 d1 = __builtin_amdgcn_mfma_f32_16x16x32_bf16(a1, bfrag, (f32x4){0.f,0.f,0.f,0.f}, 0,0,0);
                #pragma unroll
                for(int r=0;r<4;r++){
                    float v0 = selu_f(d0[r] + bias8[r]);
                    float v1 = selu_f(d1[r] + bias8[4+r]);
                    ssum8[r]   += v0; ssq8[r]   = fmaf(v0,v0,ssq8[r]);
                    ssum8[4+r] += v1; ssq8[4+r] = fmaf(v1,v1,ssq8[4+r]);
                    pmx[r]   = fmaxf(pmx[r],   v0); pmn[r]   = fminf(pmn[r],   v0);
                    pmx[4+r] = fmaxf(pmx[4+r], v1); pmn[4+r] = fminf(pmn[4+r], v1);
                }
            }
        }
        int base = (py*16 + c)*72;
        #pragma unroll
        for(int t=0;t<2;t++){
            unsigned long long mpk=0ull, npk=0ull;
            #pragma unroll
            for(int r=0;r<4;r++){
                mpk |= (unsigned long long)bfc(pmx[t*4+r]) << (16*r);
                npk |= (unsigned long long)bfc(pmn[t*4+r]) << (16*r);
            }
            *(unsigned long long*)(pmaxb + base + t*32 + qr*8) = mpk;
            *(unsigned long long*)(pminb + base + t*32 + qr*8) = npk;
        }
    }
    #pragma unroll
    for(int off=1; off<16; off<<=1){
        #pragma unroll
        for(int i=0;i<8;i++){
            ssum8[i] += __shfl_xor(ssum8[i], off);
            ssq8[i]  += __shfl_xor(ssq8[i],  off);
        }
    }
    if(c == 0){
        #pragma unroll
        for(int i=0;i<8;i++){
            sredf[((wv*4 + qr)*8 + i)*2]     = ssum8[i];
            sredf[((wv*4 + qr)*8 + i)*2 + 1] = ssq8[i];
        }
    }
    __syncthreads();
    if(tid < 32){
        int oc = tid;
        int t = oc >> 4, rem = oc & 15, q = rem >> 2, r = rem & 3;
        int i = t*4 + r;
        float sum=0.f, sq=0.f;
        for(int w=0; w<12; w++){
            sum += sredf[((w*4+q)*8+i)*2];
            sq  += sredf[((w*4+q)*8+i)*2+1];
        }
        float mean = sum*(1.f/4608.f);
        float var  = sq*(1.f/4608.f) - mean*mean;
        float inv  = rsqrtf(var + 1e-5f);
        float sc = g[oc]*inv;
        scsh[oc*2]   = sc;
        scsh[oc*2+1] = be[oc] - mean*sc;
    }
    __syncthreads();
    float* ob = out + (size_t)s*18432;
    for(int i = tid; i < 18432; i += 768){
        int oc = i / 576, wpx = i - oc*576;
        float sc = scsh[oc*2], sh = scsh[oc*2+1];
        int boff = wpx*72 + oc*2;
        float vm = f_bf(*(unsigned short*)(pmaxb + boff));
        float vn = f_bf(*(unsigned short*)(pminb + boff));
        ob[i] = fmaf(sc, (sc >= 0.f) ? vm : vn, sh);
    }
}

// ============ Stage 2 (MFMA): conv2(32->64) + SELU + GN(2ch/grp) + maxpool(3,4)
__global__ __launch_bounds__(512,2) void k_conv2m(
    const float* __restrict__ in, const short* __restrict__ w2bf,
    const float* __restrict__ bias, const float* __restrict__ g,
    const float* __restrict__ be, float* __restrict__ out)
{
    int s = blockIdx.x, tid = threadIdx.x;
    int l = tid & 63, wv = tid >> 6;
    int ocp = wv >> 2, yq = wv & 3;
    int xc = l & 15, qr = l >> 4;
    __shared__ short sinb[26240];
    __shared__ float sred[2][4][2][4][2][2];
    int* zp = (int*)sinb;
    for(int i=tid;i<13120;i+=512) zp[i]=0;
    __syncthreads();
    const float* ibase = in + (size_t)s*18432;
    #pragma unroll
    for(int h=0;h<2;h++){
        int ic = (wv*2+h)*2;
        #pragma unroll
        for(int k=0;k<9;k++){
            int px = l + 64*k;
            float v0 = ibase[ic*576 + px];
            float v1 = ibase[(ic+1)*576 + px];
            int R = (px>>4)+2, C = (px&15)+1;
            int key = (C>>1)&3;
            int q0 = ic>>3;
            int byteoff = (R*20+C)*64 + (((q0^key)&3)<<4) + (ic&7)*2;
            *(unsigned int*)((char*)sinb + byteoff) =
                (unsigned int)bfc(v0) | ((unsigned int)bfc(v1)<<16);
        }
    }
    __syncthreads();
    f32x4 acc[2][9];
    #pragma unroll
    for(int o=0;o<2;o++)
        #pragma unroll
        for(int yt=0;yt<9;yt++) acc[o][yt] = (f32x4){0.f,0.f,0.f,0.f};
    const short8* wb = (const short8*)w2bf;
    int arow = ocp*32 + xc;
    short8 a0 = wb[arow*4 + qr];
    short8 a1 = wb[(arow+16)*4 + qr];
    char* sb = (char*)sinb;
    for(int tap=0; tap<24; tap++){
        short8 na0, na1;
        if(tap<23){
            na0 = wb[((tap+1)*64 + arow)*4 + qr];
            na1 = wb[((tap+1)*64 + arow + 16)*4 + qr];
        }
        int kh = tap>>2, kw = tap&3;
        int C = xc + kw;
        int cb = C*64 + (((qr ^ ((C>>1)&3))&3)<<4);
        int rb = (yq*9 + kh)*1280;
        #pragma unroll
        for(int yt=0;yt<9;yt++){
            short8 bf_ = *(const short8*)(sb + rb + yt*1280 + cb);
            acc[0][yt] = __builtin_amdgcn_mfma_f32_16x16x32_bf16(a0, bf_, acc[0][yt], 0,0,0);
            acc[1][yt] = __builtin_amdgcn_mfma_f32_16x16x32_bf16(a1, bf_, acc[1][yt], 0,0,0);
        }
        a0 = na0; a1 = na1;
    }
    #pragma unroll
    for(int o=0;o<2;o++){
        int ocb = (ocp*2+o)*16 + qr*4;
        float b0 = bias[ocb], b1 = bias[ocb+1], b2 = bias[ocb+2], b3 = bias[ocb+3];
        float s0=0,q0=0,s1=0,q1=0;
        #pragma unroll
        for(int yt=0;yt<9;yt++){
            float v0=selu_f(acc[o][yt][0]+b0), v1=selu_f(acc[o][yt][1]+b1);
            float v2=selu_f(acc[o][yt][2]+b2), v3=selu_f(acc[o][yt][3]+b3);
            acc[o][yt][0]=v0; acc[o][yt][1]=v1; acc[o][yt][2]=v2; acc[o][yt][3]=v3;
            s0+=v0+v1; q0+=v0*v0+v1*v1; s1+=v2+v3; q1+=v2*v2+v3*v3;
        }
        #pragma unroll
        for(int off=1;off<16;off<<=1){
            s0+=__shfl_xor(s0,off); q0+=__shfl_xor(q0,off);
            s1+=__shfl_xor(s1,off); q1+=__shfl_xor(q1,off);
        }
        if(xc==0){
            sred[ocp][yq][o][qr][0][0]=s0; sred[ocp][yq][o][qr][0][1]=q0;
            sred[ocp][yq][o][qr][1][0]=s1; sred[ocp][yq][o][qr][1][1]=q1;
        }
    }
    __syncthreads();
    float* ob = out + (size_t)s*64*48;
    #pragma unroll
    for(int o=0;o<2;o++){
        #pragma unroll
        for(int grp=0;grp<2;grp++){
            float ts=0, tq=0;
            #pragma unroll
            for(int y2=0;y2<4;y2++){ ts += sred[ocp][y2][o][qr][grp][0]; tq += sred[ocp][y2][o][qr][grp][1]; }
            float mean = ts*(1.f/1152.f);
            float var  = tq*(1.f/1152.f) - mean*mean;
            float inv  = rsqrtf(var + 1e-5f);
            int oc0 = (ocp*2+o)*16 + qr*4 + grp*2;
            float sc0 = g[oc0]*inv,   sh0 = be[oc0]   - mean*sc0;
            float sc1 = g[oc0+1]*inv, sh1 = be[oc0+1] - mean*sc1;
            #pragma unroll
            for(int yt=0;yt<9;yt++){
                acc[o][yt][grp*2]   = acc[o][yt][grp*2]*sc0 + sh0;
                acc[o][yt][grp*2+1] = acc[o][yt][grp*2+1]*sc1 + sh1;
            }
        }
        #pragma unroll
        for(int r=0;r<4;r++){
            #pragma unroll
            for(int py=0;py<3;py++){
                float m = fmaxf(fmaxf(acc[o][3*py][r],acc[o][3*py+1][r]),acc[o][3*py+2][r]);
                m = fmaxf(m, __shfl_xor(m,1));
                m = fmaxf(m, __shfl_xor(m,2));
                if((xc&3)==0){
                    int oc = (ocp*2+o)*16 + qr*4 + r;
                    ob[(size_t)oc*48 + (yq*3+py)*4 + (xc>>2)] = m;
                }
            }
        }
    }
}

// ============ Stage 3 (MFMA): conv3(64->128) + SELU + GN(4ch/grp) + maxpool(3,2)
__global__ __launch_bounds__(512,2) void k_conv3m(
    const float* __restrict__ in, const short* __restrict__ w3bf,
    const float* __restrict__ bias, const float* __restrict__ g,
    const float* __restrict__ be, float* __restrict__ e0)
{
    int sq = blockIdx.x, tid = threadIdx.x;
    int l = tid & 63, wv = tid >> 6;
    int ocp = wv >> 1, sL = wv & 1;
    int c = l & 15, qr = l >> 4;
    int yl = c >> 2, xl = c & 3;
    __shared__ char smem[49152];
    short* sinb = (short*)smem;
    int* zp = (int*)smem;
    for(int i=tid;i<8704;i+=512) zp[i]=0;
    __syncthreads();
    const float* ibase = in + (size_t)sq*6144;
    for(int j=0;j<6;j++){
        int idx = tid + 512*j;
        int px = idx % 48;
        int rest = idx / 48;
        int icp = rest & 31, ss = rest >> 5;
        int ic = icp*2;
        float v0 = ibase[ss*3072 + ic*48 + px];
        float v1 = ibase[ss*3072 + (ic+1)*48 + px];
        int R = (px>>2)+2, C = (px&3)+1;
        int pos = ss*136 + R*8 + C;
        int key = ((R&1)<<2) | (C&3);
        int q0 = ic>>3;
        int byteoff = pos*128 + (((q0^key)&7)<<4) + (ic&7)*2;
        *(unsigned int*)(smem + byteoff) = (unsigned int)bfc(v0) | ((unsigned int)bfc(v1)<<16);
    }
    __syncthreads();
    f32x4 acc[2][3];
    #pragma unroll
    for(int o=0;o<2;o++)
        #pragma unroll
        for(int yt=0;yt<3;yt++) acc[o][yt] = (f32x4){0.f,0.f,0.f,0.f};
    const short8* wb = (const short8*)w3bf;
    int arow = ocp*32 + c;
    char* sb = smem + sL*17408;
    short8 a0 = wb[arow*8 + qr];
    short8 a1 = wb[(arow+16)*8 + qr];
    for(int t2=0; t2<48; t2++){
        short8 na0, na1;
        if(t2<47){
            int nt = t2+1;
            na0 = wb[((nt>>1)*128 + arow)*8 + (nt&1)*4 + qr];
            na1 = wb[((nt>>1)*128 + arow + 16)*8 + (nt&1)*4 + qr];
        }
        int tap = t2>>1, ks = t2&1;
        int kh = tap>>2, kw = tap&3;
        int C = xl + kw;
        int q0 = ks*4 + qr;
        #pragma unroll
        for(int yt=0;yt<3;yt++){
            int R = yt*4 + yl + kh;
            int key = ((R&1)<<2) | (C&3);
            short8 bf_ = *(const short8*)(sb + (R*8+C)*128 + (((q0^key)&7)<<4));
            acc[0][yt] = __builtin_amdgcn_mfma_f32_16x16x32_bf16(a0, bf_, acc[0][yt], 0,0,0);
            acc[1][yt] = __builtin_amdgcn_mfma_f32_16x16x32_bf16(a1, bf_, acc[1][yt], 0,0,0);
        }
        a0 = na0; a1 = na1;
    }
    #pragma unroll
    for(int o=0;o<2;o++){
        int ocb = (ocp*2+o)*16 + qr*4;
        float b0 = bias[ocb], b1 = bias[ocb+1], b2 = bias[ocb+2], b3 = bias[ocb+3];
        float ssum=0.f, ssq=0.f;
        #pragma unroll
        for(int yt=0;yt<3;yt++){
            float v0=selu_f(acc[o][yt][0]+b0), v1=selu_f(acc[o][yt][1]+b1);
            float v2=selu_f(acc[o][yt][2]+b2), v3=selu_f(acc[o][yt][3]+b3);
            acc[o][yt][0]=v0; acc[o][yt][1]=v1; acc[o][yt][2]=v2; acc[o][yt][3]=v3;
            ssum += v0+v1+v2+v3; ssq += v0*v0+v1*v1+v2*v2+v3*v3;
        }
        #pragma unroll
        for(int off=1;off<16;off<<=1){ ssum+=__shfl_xor(ssum,off); ssq+=__shfl_xor(ssq,off); }
        float mean = ssum*(1.f/192.f);
        float var  = ssq*(1.f/192.f) - mean*mean;
        float inv  = rsqrtf(var + 1e-5f);
        #pragma unroll
        for(int r=0;r<4;r++){
            int oc = ocb + r;
            float sc = g[oc]*inv, sh = be[oc] - mean*sc;
            #pragma unroll
            for(int yt=0;yt<3;yt++) acc[o][yt][r] = acc[o][yt][r]*sc + sh;
        }
    }
    __syncthreads();
    float* scr = (float*)smem + wv*1536;
    #pragma unroll
    for(int o=0;o<2;o++)
        #pragma unroll
        for(int yt=0;yt<3;yt++)
            #pragma unroll
            for(int r=0;r<4;r++){
                int px = (yt*4+yl)*4 + xl;
                scr[o*768 + (qr*4+r)*48 + px] = acc[o][yt][r];
            }
    __syncthreads();
    float* sr = (float*)smem + wv*1536 + (l>>5)*768 + ((l>>1)&15)*48;
    int x2 = l&1;
    float* eo = e0 + (size_t)(sq*2+sL)*1024 + ((size_t)(ocp*2 + (l>>5))*16 + ((l>>1)&15))*8;
    #pragma unroll
    for(int py=0;py<4;py++){
        float m = sr[(py*3)*4 + x2*2];
        m = fmaxf(m, sr[(py*3)*4 + x2*2+1]);
        m = fmaxf(m, sr[(py*3+1)*4 + x2*2]);
        m = fmaxf(m, sr[(py*3+1)*4 + x2*2+1]);
        m = fmaxf(m, sr[(py*3+2)*4 + x2*2]);
        m = fmaxf(m, sr[(py*3+2)*4 + x2*2+1]);
        eo[py*2 + x2] = m;
    }
}

// ---------------- FC1 + SELU + l2norm + QKV + PE, batched 4 samples/block.
// 512 thr: j = tid&127, q4 = tid>>7 (K-split). Weights read once per block -> 4x reuse.
__global__ __launch_bounds__(512) void k_fcqkv(
    const float* __restrict__ e0, const float* __restrict__ wt,
    const float* __restrict__ bias, float* __restrict__ e,
    const float* __restrict__ wqt, const float* __restrict__ bq,
    const float* __restrict__ wkt, const float* __restrict__ bk,
    const float* __restrict__ wvt, const float* __restrict__ bv,
    float* __restrict__ q, float* __restrict__ kp, float* __restrict__ v)
{
    int s0 = blockIdx.x*4, tid = threadIdx.x;
    int j = tid & 127, q4 = tid >> 7;
    __shared__ float se[4][1024];        // 16 KB
    __shared__ float sp[4][4][128];      // 8 KB  [sl][q4][j]
    __shared__ float sredn[4][2];
    __shared__ float se2[4][128];        // 2 KB
    __shared__ float sp3[3][4][4][128];  // 24 KB
    for(int i=tid;i<4096;i+=512){
        int sl = i >> 10, ii = i & 1023;
        se[sl][ii] = e0[(size_t)(s0+sl)*1024 + ii];
    }
    __syncthreads();
    float acc[4] = {0.f,0.f,0.f,0.f};
    const float* wp = wt + (size_t)q4*256*128 + j;
    const int ibase = q4*256;
    #pragma unroll 4
    for(int i=0;i<256;i++){
        float w = wp[(size_t)i*128];
        #pragma unroll
        for(int sl=0;sl<4;sl++) acc[sl] = fmaf(se[sl][ibase+i], w, acc[sl]);
    }
    #pragma unroll
    for(int sl=0;sl<4;sl++) sp[sl][q4][j] = acc[sl];
    __syncthreads();
    int sl2 = q4, lane = tid & 63, wv_ = tid >> 6;
    float vfc = selu_f(bias[j] + sp[sl2][0][j] + sp[sl2][1][j] + sp[sl2][2][j] + sp[sl2][3][j]);
    float a = vfc*vfc;
    #pragma unroll
    for(int o=1;o<64;o<<=1) a += __shfl_xor(a, o);
    if(lane==0) sredn[sl2][wv_&1] = a;
    __syncthreads();
    float den = fmaxf(sqrtf(sredn[sl2][0]+sredn[sl2][1]), 1e-12f);
    float ev = vfc/den;
    se2[sl2][j] = ev;
    e[(size_t)(s0+sl2)*128 + j] = ev;
    __syncthreads();
    float aq[4]={0,0,0,0}, ak[4]={0,0,0,0}, av[4]={0,0,0,0};
    int i0b = q4*32;
    #pragma unroll 4
    for(int i=0;i<32;i++){
        float wqv = wqt[(i0b+i)*128 + j];
        float wkv = wkt[(i0b+i)*128 + j];
        float wvv = wvt[(i0b+i)*128 + j];
        #pragma unroll
        for(int sl=0;sl<4;sl++){
            float f = se2[sl][i0b+i];
            aq[sl] = fmaf(f, wqv, aq[sl]);
            ak[sl] = fmaf(f, wkv, ak[sl]);
            av[sl] = fmaf(f, wvv, av[sl]);
        }
    }
    #pragma unroll
    for(int sl=0;sl<4;sl++){
        sp3[0][sl][q4][j] = aq[sl];
        sp3[1][sl][q4][j] = ak[sl];
        sp3[2][sl][q4][j] = av[sl];
    }
    __syncthreads();
    float vq = selu_f(bq[j] + sp3[0][sl2][0][j]+sp3[0][sl2][1][j]+sp3[0][sl2][2][j]+sp3[0][sl2][3][j]);
    float vk = selu_f(bk[j] + sp3[1][sl2][0][j]+sp3[1][sl2][1][j]+sp3[1][sl2][2][j]+sp3[1][sl2][3][j]);
    float vv = selu_f(bv[j] + sp3[2][sl2][0][j]+sp3[2][sl2][1][j]+sp3[2][sl2][2][j]+sp3[2][sl2][3][j]);
    int i2 = j & ~1;
    float dv = __expf(-(float)i2 * 0.07195578412155481f);
    float ang = (float)(s0+sl2) * dv;
    float pe = (j & 1) ? cosf(ang) : sinf(ang);
    q[(size_t)(s0+sl2)*128+j]  = vq;
    kp[(size_t)(s0+sl2)*128+j] = vk + pe;
    v[(size_t)(s0+sl2)*128+j]  = vv;
}

// ---------------- fused attention, batched 4 samples/block (K/V read once -> 4x reuse)
__global__ __launch_bounds__(512) void k_attnav(
    const float* __restrict__ q, const float* __restrict__ kp,
    const float* __restrict__ v, float* __restrict__ av)
{
    int s0 = blockIdx.x*4, tid = threadIdx.x;
    __shared__ float4 sq4[4][32];        // 2 KB
    __shared__ float p[4][1024];         // 16 KB
    __shared__ float spart[4][4][128];   // 8 KB
    __shared__ float smx[4][2], ssm[4][2];
    ((float*)sq4)[tid] = q[(size_t)s0*128 + tid];
    __syncthreads();
    #pragma unroll
    for(int h=0;h<2;h++){
        int t = tid + h*512;
        const float4* kr = (const float4*)(kp + (size_t)t*128);
        float d[4] = {0.f,0.f,0.f,0.f};
        #pragma unroll 4
        for(int i=0;i<32;i++){
            float4 kv = kr[i];
            #pragma unroll
            for(int sl=0;sl<4;sl++){
                float4 qv = sq4[sl][i];
                d[sl] += kv.x*qv.x + kv.y*qv.y + kv.z*qv.z + kv.w*qv.w;
            }
        }
        #pragma unroll
        for(int sl=0;sl<4;sl++) p[sl][t] = d[sl]*0.08838834764831845f;
    }
    __syncthreads();
    int sl2 = tid>>7, t2 = tid&127, lane = tid&63, wv_ = tid>>6;
    float vals[8];
    float m = -INFINITY;
    #pragma unroll
    for(int k=0;k<8;k++){ vals[k] = p[sl2][t2 + k*128]; m = fmaxf(m, vals[k]); }
    #pragma unroll
    for(int o=1;o<64;o<<=1) m = fmaxf(m, __shfl_xor(m,o));
    if(lane==0) smx[sl2][wv_&1] = m;
    __syncthreads();
    m = fmaxf(smx[sl2][0], smx[sl2][1]);
    float lsum = 0.f;
    #pragma unroll
    for(int k=0;k<8;k++){ vals[k] = __expf(vals[k]-m); lsum += vals[k]; }
    #pragma unroll
    for(int o=1;o<64;o<<=1) lsum += __shfl_xor(lsum,o);
    if(lane==0) ssm[sl2][wv_&1] = lsum;
    __syncthreads();
    float invs = 1.f/(ssm[sl2][0]+ssm[sl2][1]);
    #pragma unroll
    for(int k=0;k<8;k++) p[sl2][t2+k*128] = vals[k]*invs;
    __syncthreads();
    int j = tid & 127, q4 = tid >> 7;
    float acc[4] = {0,0,0,0};
    int t0 = q4*256;
    #pragma unroll 2
    for(int t=t0;t<t0+256;t++){
        float vv = v[(size_t)t*128 + j];
        #pragma unroll
        for(int sl=0;sl<4;sl++) acc[sl] = fmaf(p[sl][t], vv, acc[sl]);
    }
    #pragma unroll
    for(int sl=0;sl<4;sl++) spart[sl][q4][j] = acc[sl];
    __syncthreads();
    av[(size_t)(s0+sl2)*128 + j] = spart[sl2][0][j]+spart[sl2][1][j]+spart[sl2][2][j]+spart[sl2][3][j];
}

// ---------------- column pipeline: 1024-thr blocks (1 row/thread) for TLP on strided loads
__global__ __launch_bounds__(1024) void k_colpipe(
    const float* __restrict__ av, const float* __restrict__ e, float* __restrict__ ea)
{
    int j = blockIdx.x, t = threadIdx.x;
    __shared__ float sred[16];
    int lane = t & 63, w = t >> 6;
    float vv = av[(size_t)t*128 + j];
    float ss = vv*vv;
    #pragma unroll
    for(int off=1;off<64;off<<=1) ss += __shfl_xor(ss,off);
    if(lane==0) sred[w]=ss;
    __syncthreads();
    float tot = 0.f;
    #pragma unroll
    for(int i=0;i<16;i++) tot += sred[i];
    float n1 = fmaxf(sqrtf(tot), 1e-12f);
    __syncthreads();
    float o = vv/n1 + e[(size_t)t*128 + j];
    float ss2 = o*o;
    #pragma unroll
    for(int off=1;off<64;off<<=1) ss2 += __shfl_xor(ss2,off);
    if(lane==0) sred[w]=ss2;
    __syncthreads();
    float tot2 = 0.f;
    #pragma unroll
    for(int i=0;i<16;i++) tot2 += sred[i];
    float n2 = fmaxf(sqrtf(tot2), 1e-12f);
    ea[(size_t)t*128 + j] = o/n2;
}

// ---------------- pairwise d2 (row norms computed in-block from staged tiles) + max
__global__ __launch_bounds__(256) void k_gram(
    const float* __restrict__ ea,
    float* __restrict__ d2, unsigned int* __restrict__ maxbits)
{
    int j0 = blockIdx.x*32, i0 = blockIdx.y*32, tid = threadIdx.x;
    __shared__ float sa[32*128];
    __shared__ float sb[32*128];
    __shared__ float sredm[32];
    __shared__ float sqa[32], sqb[32];
    for(int idx=tid;idx<4096;idx+=256){
        sa[idx] = ea[(size_t)i0*128 + idx];
        sb[idx] = ea[(size_t)j0*128 + idx];
    }
    __syncthreads();
    {
        int r = tid>>3, seg = tid&7;
        const float* A = sa + r*128 + seg*16;
        const float* B = sb + r*128 + seg*16;
        float pa=0.f, pb=0.f;
        #pragma unroll
        for(int i=0;i<16;i++){ pa = fmaf(A[i],A[i],pa); pb = fmaf(B[i],B[i],pb); }
        #pragma unroll
        for(int o=1;o<8;o<<=1){ pa += __shfl_xor(pa,o); pb += __shfl_xor(pb,o); }
        if(seg==0){ sqa[r]=pa; sqb[r]=pb; }
    }
    __syncthreads();
    float lm = 0.f;
    #pragma unroll
    for(int k2=0;k2<4;k2++){
        int pp = tid + k2*256;
        int li = pp>>5, lj = pp&31;
        const float4* A = (const float4*)(sa + li*128);
        const float4* B = (const float4*)(sb + lj*128);
        float acc=0.f;
        #pragma unroll 8
        for(int i=0;i<32;i++){
            float4 a=A[i], b=B[i];
            acc += a.x*b.x + a.y*b.y + a.z*b.z + a.w*b.w;
        }
        float dd = fmaxf(sqa[li] + sqb[lj] - 2.f*acc, 0.f);
        d2[(size_t)(i0+li)*1024 + j0+lj] = dd;
        lm = fmaxf(lm, dd);
    }
    lm = warp_max(lm);
    __syncthreads();
    if((tid&63)==0) sredm[tid>>6]=lm;
    __syncthreads();
    if(tid==0){
        float mm = fmaxf(fmaxf(sredm[0],sredm[1]),fmaxf(sredm[2],sredm[3]));
        atomicMax(maxbits, __float_as_uint(mm));
    }
}

// ---------------- out = 1 - sqrt(d2+eps)/maxd
__global__ __launch_bounds__(256) void k_final(
    const float* __restrict__ d2, const unsigned int* __restrict__ maxbits, float* __restrict__ out)
{
    int idx = blockIdx.x*256 + threadIdx.x;
    float md = sqrtf(__uint_as_float(*maxbits) + 1e-12f);
    out[idx] = 1.f - sqrtf(d2[idx] + 1e-12f)/md;
}

extern "C" void kernel_launch(void* const* d_in, const int* in_sizes, int n_in,
                              void* d_out, int out_size, void* d_ws, size_t ws_size,
                              hipStream_t stream)
{
    const float* x   = (const float*)d_in[0];
    const float* c1w = (const float*)d_in[1];  const float* c1b = (const float*)d_in[2];
    const float* g1g = (const float*)d_in[3];  const float* g1b = (const float*)d_in[4];
    const float* c2w = (const float*)d_in[5];  const float* c2b = (const float*)d_in[6];
    const float* g2g = (const float*)d_in[7];  const float* g2b = (const float*)d_in[8];
    const float* c3w = (const float*)d_in[9];  const float* c3b = (const float*)d_in[10];
    const float* g3g = (const float*)d_in[11]; const float* g3b = (const float*)d_in[12];
    const float* f1w = (const float*)d_in[13]; const float* f1b = (const float*)d_in[14];
    const float* wq  = (const float*)d_in[15]; const float* bq  = (const float*)d_in[16];
    const float* wk  = (const float*)d_in[17]; const float* bk  = (const float*)d_in[18];
    const float* wv  = (const float*)d_in[19]; const float* bv  = (const float*)d_in[20];

    float* W = (float*)d_ws;
    float* e0   = W;                 // 1,048,576
    float* avb  = W + 2097152;       //   131,072
    float* eab  = W + 2228224;       //   131,072
    float* d2b  = W + 2359296;       // 1,048,576
    float* buf1 = W;                 // stage1 out (dead before e0 written)
    float* buf2 = W + 18874368;      // stage2 out
    float* wt   = W + 22020096;
    float* wqt  = W + 22151168;
    float* wkt  = W + 22167552;
    float* wvt  = W + 22183936;
    float* eb   = W + 22200320;
    float* qb   = W + 22331392;
    float* kpb  = W + 22462464;
    float* vb   = W + 22593536;
    unsigned int* maxb = (unsigned int*)(W + 22725632);
    short* w2bf = (short*)(W + 22725648);   // 49,152 bf16
    short* w3bf = (short*)(W + 22750224);   // 196,608 bf16
    short* w1bf = (short*)(W + 22848528);   // 1,024 bf16

    k_prep<<<1670,256,0,stream>>>(f1w, wq, wk, wv, c1w, c2w, c3w,
                                  wt, wqt, wkt, wvt, w1bf, w2bf, w3bf);

    k_conv1m<<<1024,768,0,stream>>>(x, w1bf, c1b, g1g, g1b, buf1);
    k_conv2m<<<1024,512,0,stream>>>(buf1, w2bf, c2b, g2g, g2b, buf2);
    k_conv3m<<<512,512,0,stream>>>(buf2, w3bf, c3b, g3g, g3b, e0);

    k_fcqkv<<<256,512,0,stream>>>(e0, wt, f1b, eb, wqt,bq, wkt,bk, wvt,bv, qb,kpb,vb);
    k_attnav<<<256,512,0,stream>>>(qb, kpb, vb, avb);

    hipMemsetAsync(maxb, 0, 4, stream);
    k_colpipe<<<128,1024,0,stream>>>(avb, eb, eab);
    k_gram<<<dim3(32,32),256,0,stream>>>(eab, d2b, maxb);
    k_final<<<4096,256,0,stream>>>(d2b, maxb, (float*)d_out);
}

// Round 11
// 360.206 us; speedup vs baseline: 11.8078x; 1.0213x over previous
//
#include <hip/hip_runtime.h>
#include <hip/hip_bf16.h>
#include <math.h>

#define SELU_SCALE 1.0507009873554805f
#define SELU_SA    1.7580993408473766f   // scale*alpha

typedef __attribute__((ext_vector_type(8))) short short8;
typedef __attribute__((ext_vector_type(4))) short short4v;
typedef __attribute__((ext_vector_type(4))) float f32x4;

__device__ __forceinline__ float selu_f(float x){
    return x > 0.f ? SELU_SCALE * x : fmaf(SELU_SA, __expf(x), -SELU_SA);
}

__device__ __forceinline__ unsigned short bfc(float v){
    __hip_bfloat16 h = __float2bfloat16(v);
    return __builtin_bit_cast(unsigned short, h);
}
__device__ __forceinline__ float f_bf(unsigned short u){
    unsigned int x = ((unsigned int)u) << 16;
    return __builtin_bit_cast(float, x);
}

__device__ __forceinline__ float warp_max(float v){
    #pragma unroll
    for(int o=32;o>0;o>>=1) v = fmaxf(v,__shfl_down(v,o,64));
    return v;
}

// ---------------- unified weight prep
__global__ void k_prep(const float* __restrict__ f1w, const float* __restrict__ wq,
                       const float* __restrict__ wk, const float* __restrict__ wv,
                       const float* __restrict__ w1, const float* __restrict__ w2,
                       const float* __restrict__ w3,
                       float* __restrict__ wt, float* __restrict__ wqt,
                       float* __restrict__ wkt, float* __restrict__ wvt,
                       short* __restrict__ w1bf, short* __restrict__ w2bf,
                       short* __restrict__ w3bf){
    int idx = blockIdx.x*256 + threadIdx.x;
    if(idx < 131072){ int r = idx >> 10, cc = idx & 1023; wt[cc*128 + r] = f1w[idx]; return; }
    idx -= 131072;
    if(idx < 16384){ int r = idx >> 7, cc = idx & 127; wqt[cc*128 + r] = wq[idx]; return; }
    idx -= 16384;
    if(idx < 16384){ int r = idx >> 7, cc = idx & 127; wkt[cc*128 + r] = wk[idx]; return; }
    idx -= 16384;
    if(idx < 16384){ int r = idx >> 7, cc = idx & 127; wvt[cc*128 + r] = wv[idx]; return; }
    idx -= 16384;
    if(idx < 49152){
        int t = idx >> 11, rem = idx & 2047;
        int oc = rem >> 5, ic = rem & 31;
        w2bf[idx] = (short)bfc(w2[oc*768 + ic*24 + t]);
        return;
    }
    idx -= 49152;
    if(idx < 196608){
        int t = idx >> 13, rem = idx & 8191;
        int oc = rem >> 6, ic = rem & 63;
        w3bf[idx] = (short)bfc(w3[oc*1536 + ic*24 + t]);
        return;
    }
    idx -= 196608;
    if(idx < 1024){
        int oc = idx >> 5, k = idx & 31;
        w1bf[idx] = (k < 24) ? (short)bfc(w1[oc*24 + k]) : (short)0;
    }
}

// ============ Stage 1 (MFMA): conv1(1->32) + SELU + GN(1ch/grp) + maxpool(2,4)
// 1024 thr = 16 waves (fills the 16-wave/CU cap at VGPR<=128). Output bf16.
__global__ __launch_bounds__(1024,1) void k_conv1m(
    const float* __restrict__ x, const short* __restrict__ w1bf,
    const float* __restrict__ bias, const float* __restrict__ g,
    const float* __restrict__ be, unsigned short* __restrict__ out)
{
    int s = blockIdx.x, tid = threadIdx.x;
    int l = tid & 63, wv = tid >> 6;          // wv 0..15
    int c = l & 15, qr = l >> 4;
    __shared__ char smem[128752];
    short* sdup = (short*)smem;               // 79 rows x 528 B = 41,712
    char* pmaxb = smem + 41712;               // [576 win x 72 B] = 41,472
    char* pminb = smem + 83184;               // 41,472
    float* sredf = (float*)(smem + 124656);   // [16][4][8][2] = 1024 floats
    __shared__ float scsh[64];                // [32 oc][sc,sh]

    const float* xs = x + (size_t)s*4608;
    for(int i = tid; i < 5056; i += 1024){
        int yp = i >> 6, xx = i & 63;
        unsigned long long pk = 0ull;
        if(yp >= 2 && yp < 74){
            const float* row = xs + (yp-2)*64;
            #pragma unroll
            for(int t=0;t<4;t++){
                int cp = xx + t;
                float f = (cp>=1 && cp<65) ? row[cp-1] : 0.f;
                pk |= (unsigned long long)bfc(f) << (16*t);
            }
        }
        *(unsigned long long*)((char*)sdup + yp*528 + (xx&3)*128 + (xx>>2)*8) = pk;
    }
    short8 a0 = *(const short8*)(w1bf + c*32 + qr*8);
    short8 a1 = *(const short8*)(w1bf + (16+c)*32 + qr*8);
    float bias8[8];
    #pragma unroll
    for(int t=0;t<2;t++)
        #pragma unroll
        for(int r=0;r<4;r++) bias8[t*4+r] = bias[t*16 + qr*4 + r];
    float ssum8[8], ssq8[8];
    #pragma unroll
    for(int i=0;i<8;i++){ ssum8[i]=0.f; ssq8[i]=0.f; }
    __syncthreads();

    // wave->row-pair map: waves 0..3 take 3 pairs, waves 4..15 take 2 (36 total)
    int nu, py0;
    if(wv < 4){ nu = 3; py0 = wv*3; } else { nu = 2; py0 = 12 + (wv-4)*2; }
    #pragma unroll 1
    for(int u=0; u<nu; u++){
        int py = py0 + u;
        float pmx[8], pmn[8];
        #pragma unroll
        for(int i=0;i<8;i++){ pmx[i]=-INFINITY; pmn[i]=INFINITY; }
        #pragma unroll
        for(int off=0; off<4; off++){
            const char* bb = (const char*)sdup + off*128 + c*8;
            #pragma unroll
            for(int rr=0; rr<2; rr++){
                int y = py*2 + rr;
                short4v lo = *(const short4v*)(bb + (y+2*qr)*528);
                short4v hi = *(const short4v*)(bb + (y+2*qr+1)*528);
                short8 bfrag = __builtin_shufflevector(lo, hi, 0,1,2,3,4,5,6,7);
                f32x4 d0 = __builtin_amdgcn_mfma_f32_16x16x32_bf16(a0, bfrag, (f32x4){0.f,0.f,0.f,0.f}, 0,0,0);
                f32x4 d1 = __builtin_amdgcn_mfma_f32_16x16x32_bf16(a1, bfrag, (f32x4){0.f,0.f,0.f,0.f}, 0,0,0);
                #pragma unroll
                for(int r=0;r<4;r++){
                    float v0 = selu_f(d0[r] + bias8[r]);
                    float v1 = selu_f(d1[r] + bias8[4+r]);
                    ssum8[r]   += v0; ssq8[r]   = fmaf(v0,v0,ssq8[r]);
                    ssum8[4+r] += v1; ssq8[4+r] = fmaf(v1,v1,ssq8[4+r]);
                    pmx[r]   = fmaxf(pmx[r],   v0); pmn[r]   = fminf(pmn[r],   v0);
                    pmx[4+r] = fmaxf(pmx[4+r], v1); pmn[4+r] = fminf(pmn[4+r], v1);
                }
            }
        }
        int base = (py*16 + c)*72;
        #pragma unroll
        for(int t=0;t<2;t++){
            unsigned long long mpk=0ull, npk=0ull;
            #pragma unroll
            for(int r=0;r<4;r++){
                mpk |= (unsigned long long)bfc(pmx[t*4+r]) << (16*r);
                npk |= (unsigned long long)bfc(pmn[t*4+r]) << (16*r);
            }
            *(unsigned long long*)(pmaxb + base + t*32 + qr*8) = mpk;
            *(unsigned long long*)(pminb + base + t*32 + qr*8) = npk;
        }
    }
    #pragma unroll
    for(int off=1; off<16; off<<=1){
        #pragma unroll
        for(int i=0;i<8;i++){
            ssum8[i] += __shfl_xor(ssum8[i], off);
            ssq8[i]  += __shfl_xor(ssq8[i],  off);
        }
    }
    if(c == 0){
        #pragma unroll
        for(int i=0;i<8;i++){
            sredf[((wv*4 + qr)*8 + i)*2]     = ssum8[i];
            sredf[((wv*4 + qr)*8 + i)*2 + 1] = ssq8[i];
        }
    }
    __syncthreads();
    if(tid < 32){
        int oc = tid;
        int t = oc >> 4, rem = oc & 15, q = rem >> 2, r = rem & 3;
        int i = t*4 + r;
        float sum=0.f, sq=0.f;
        for(int w=0; w<16; w++){
            sum += sredf[((w*4+q)*8+i)*2];
            sq  += sredf[((w*4+q)*8+i)*2+1];
        }
        float mean = sum*(1.f/4608.f);
        float var  = sq*(1.f/4608.f) - mean*mean;
        float inv  = rsqrtf(var + 1e-5f);
        float sc = g[oc]*inv;
        scsh[oc*2]   = sc;
        scsh[oc*2+1] = be[oc] - mean*sc;
    }
    __syncthreads();
    unsigned short* ob = out + (size_t)s*18432;
    for(int i = tid; i < 18432; i += 1024){
        int oc = i / 576, wpx = i - oc*576;
        float sc = scsh[oc*2], sh = scsh[oc*2+1];
        int boff = wpx*72 + oc*2;
        float vm = f_bf(*(unsigned short*)(pmaxb + boff));
        float vn = f_bf(*(unsigned short*)(pminb + boff));
        ob[i] = bfc(fmaf(sc, (sc >= 0.f) ? vm : vn, sh));
    }
}

// ============ Fused stages 2+3 (MFMA): conv2+GN+pool -> LDS -> conv3+GN+pool -> e0
// 1 sample/block, 512 thr = 8 waves. Phase A = conv2 (waves: ocp(2) x yq(4)).
// Phase B = conv3 (each wave: 16 oc). conv2 output never touches global.
__global__ __launch_bounds__(512,2) void k_conv23(
    const unsigned short* __restrict__ in, const short* __restrict__ w2bf,
    const float* __restrict__ b2, const float* __restrict__ g2,
    const float* __restrict__ e2,
    const short* __restrict__ w3bf,
    const float* __restrict__ b3, const float* __restrict__ g3,
    const float* __restrict__ e3, float* __restrict__ e0)
{
    int s = blockIdx.x, tid = threadIdx.x;
    int l = tid & 63, wv = tid >> 6;
    int ocp = wv >> 2, yq = wv & 3;
    int xc = l & 15, qr = l >> 4;
    __shared__ char cs[69888];               // sinb 52480 (reused as pool scratch) + s3in 17408
    short* sinb = (short*)cs;
    char*  s3in = cs + 52480;
    __shared__ float sredA[2][4][2][4][2][2];
    for(int i=tid;i<17472;i+=512) ((int*)cs)[i] = 0;
    __syncthreads();
    const unsigned short* ibase = in + (size_t)s*18432;
    #pragma unroll
    for(int h=0;h<2;h++){
        int ic = (wv*2+h)*2;
        #pragma unroll
        for(int k=0;k<9;k++){
            int px = l + 64*k;
            unsigned int v0 = ibase[ic*576 + px];
            unsigned int v1 = ibase[(ic+1)*576 + px];
            int R = (px>>4)+2, C = (px&15)+1;
            int key = (C>>1)&3;
            int q0 = ic>>3;
            int byteoff = (R*20+C)*64 + (((q0^key)&3)<<4) + (ic&7)*2;
            *(unsigned int*)((char*)sinb + byteoff) = v0 | (v1<<16);
        }
    }
    __syncthreads();
    f32x4 acc[2][9];
    #pragma unroll
    for(int o=0;o<2;o++)
        #pragma unroll
        for(int yt=0;yt<9;yt++) acc[o][yt] = (f32x4){0.f,0.f,0.f,0.f};
    const short8* wb = (const short8*)w2bf;
    int arow = ocp*32 + xc;
    short8 a0 = wb[arow*4 + qr];
    short8 a1 = wb[(arow+16)*4 + qr];
    char* sb = (char*)sinb;
    for(int tap=0; tap<24; tap++){
        short8 na0, na1;
        if(tap<23){
            na0 = wb[((tap+1)*64 + arow)*4 + qr];
            na1 = wb[((tap+1)*64 + arow + 16)*4 + qr];
        }
        int kh = tap>>2, kw = tap&3;
        int C = xc + kw;
        int cb = C*64 + (((qr ^ ((C>>1)&3))&3)<<4);
        int rb = (yq*9 + kh)*1280;
        #pragma unroll
        for(int yt=0;yt<9;yt++){
            short8 bf_ = *(const short8*)(sb + rb + yt*1280 + cb);
            acc[0][yt] = __builtin_amdgcn_mfma_f32_16x16x32_bf16(a0, bf_, acc[0][yt], 0,0,0);
            acc[1][yt] = __builtin_amdgcn_mfma_f32_16x16x32_bf16(a1, bf_, acc[1][yt], 0,0,0);
        }
        a0 = na0; a1 = na1;
    }
    #pragma unroll
    for(int o=0;o<2;o++){
        int ocb = (ocp*2+o)*16 + qr*4;
        float b0 = b2[ocb], b1 = b2[ocb+1], bb2 = b2[ocb+2], b3_ = b2[ocb+3];
        float s0=0,q0s=0,s1=0,q1=0;
        #pragma unroll
        for(int yt=0;yt<9;yt++){
            float v0=selu_f(acc[o][yt][0]+b0), v1=selu_f(acc[o][yt][1]+b1);
            float v2=selu_f(acc[o][yt][2]+bb2), v3=selu_f(acc[o][yt][3]+b3_);
            acc[o][yt][0]=v0; acc[o][yt][1]=v1; acc[o][yt][2]=v2; acc[o][yt][3]=v3;
            s0+=v0+v1; q0s+=v0*v0+v1*v1; s1+=v2+v3; q1+=v2*v2+v3*v3;
        }
        #pragma unroll
        for(int off=1;off<16;off<<=1){
            s0+=__shfl_xor(s0,off); q0s+=__shfl_xor(q0s,off);
            s1+=__shfl_xor(s1,off); q1+=__shfl_xor(q1,off);
        }
        if(xc==0){
            sredA[ocp][yq][o][qr][0][0]=s0; sredA[ocp][yq][o][qr][0][1]=q0s;
            sredA[ocp][yq][o][qr][1][0]=s1; sredA[ocp][yq][o][qr][1][1]=q1;
        }
    }
    __syncthreads();
    #pragma unroll
    for(int o=0;o<2;o++){
        #pragma unroll
        for(int grp=0;grp<2;grp++){
            float ts=0, tq=0;
            #pragma unroll
            for(int y2=0;y2<4;y2++){ ts += sredA[ocp][y2][o][qr][grp][0]; tq += sredA[ocp][y2][o][qr][grp][1]; }
            float mean = ts*(1.f/1152.f);
            float var  = tq*(1.f/1152.f) - mean*mean;
            float inv  = rsqrtf(var + 1e-5f);
            int oc0 = (ocp*2+o)*16 + qr*4 + grp*2;
            float sc0 = g2[oc0]*inv,   sh0 = e2[oc0]   - mean*sc0;
            float sc1 = g2[oc0+1]*inv, sh1 = e2[oc0+1] - mean*sc1;
            #pragma unroll
            for(int yt=0;yt<9;yt++){
                acc[o][yt][grp*2]   = acc[o][yt][grp*2]*sc0 + sh0;
                acc[o][yt][grp*2+1] = acc[o][yt][grp*2+1]*sc1 + sh1;
            }
        }
        #pragma unroll
        for(int r=0;r<4;r++){
            #pragma unroll
            for(int py=0;py<3;py++){
                float m = fmaxf(fmaxf(acc[o][3*py][r],acc[o][3*py+1][r]),acc[o][3*py+2][r]);
                m = fmaxf(m, __shfl_xor(m,1));
                m = fmaxf(m, __shfl_xor(m,2));
                if((xc&3)==0){
                    int oc = (ocp*2+o)*16 + qr*4 + r;
                    int R = yq*3 + py + 2;
                    int C = (xc>>2) + 1;
                    int key = ((R&1)<<2) | (C&3);
                    int q0 = oc>>3;
                    *(unsigned short*)(s3in + (R*8+C)*128 + (((q0^key)&7)<<4) + (oc&7)*2) = bfc(m);
                }
            }
        }
    }
    __syncthreads();
    // -------- Phase B: conv3, 8 waves x 16 oc
    int yl = xc >> 2, xl = xc & 3;
    f32x4 acc3[3];
    #pragma unroll
    for(int yt=0;yt<3;yt++) acc3[yt] = (f32x4){0.f,0.f,0.f,0.f};
    const short8* wb3 = (const short8*)w3bf;
    int arow3 = wv*16 + xc;
    short8 a3 = wb3[arow3*8 + qr];
    for(int t2=0; t2<48; t2++){
        short8 na3;
        if(t2<47){
            int nt = t2+1;
            na3 = wb3[((nt>>1)*128 + arow3)*8 + (nt&1)*4 + qr];
        }
        int tap = t2>>1, ks = t2&1;
        int kh = tap>>2, kw = tap&3;
        int C = xl + kw;
        int q0 = ks*4 + qr;
        #pragma unroll
        for(int yt=0;yt<3;yt++){
            int R = yt*4 + yl + kh;
            int key = ((R&1)<<2) | (C&3);
            short8 bf_ = *(const short8*)(s3in + (R*8+C)*128 + (((q0^key)&7)<<4));
            acc3[yt] = __builtin_amdgcn_mfma_f32_16x16x32_bf16(a3, bf_, acc3[yt], 0,0,0);
        }
        a3 = na3;
    }
    // epilogue: bias + SELU + GN (group = 4 oc = this thread's qr quad)
    int ocb3 = wv*16 + qr*4;
    float c0 = b3[ocb3], c1 = b3[ocb3+1], c2 = b3[ocb3+2], c3 = b3[ocb3+3];
    float ssum=0.f, ssq=0.f;
    #pragma unroll
    for(int yt=0;yt<3;yt++){
        float v0=selu_f(acc3[yt][0]+c0), v1=selu_f(acc3[yt][1]+c1);
        float v2=selu_f(acc3[yt][2]+c2), v3=selu_f(acc3[yt][3]+c3);
        acc3[yt][0]=v0; acc3[yt][1]=v1; acc3[yt][2]=v2; acc3[yt][3]=v3;
        ssum += v0+v1+v2+v3; ssq += v0*v0+v1*v1+v2*v2+v3*v3;
    }
    #pragma unroll
    for(int off=1;off<16;off<<=1){ ssum+=__shfl_xor(ssum,off); ssq+=__shfl_xor(ssq,off); }
    float mean3 = ssum*(1.f/192.f);
    float var3  = ssq*(1.f/192.f) - mean3*mean3;
    float inv3  = rsqrtf(var3 + 1e-5f);
    float* scr = (float*)cs + wv*768;      // wave-private scratch inside dead sinb
    #pragma unroll
    for(int r=0;r<4;r++){
        int oc = ocb3 + r;
        float sc = g3[oc]*inv3, sh = e3[oc] - mean3*sc;
        #pragma unroll
        for(int yt=0;yt<3;yt++)
            scr[(qr*4+r)*48 + (yt*4+yl)*4 + xl] = acc3[yt][r]*sc + sh;
    }
    // wave-local pool 3x2: lane -> oc_l = l>>2 (16), pyw = l&3 (4), x2 in 0..1
    int oc_l = l>>2, pyw = l&3;
    const float* srd = (const float*)cs + wv*768 + oc_l*48;
    float* eo = e0 + (size_t)s*1024 + (wv*16 + oc_l)*8 + pyw*2;
    #pragma unroll
    for(int x2=0;x2<2;x2++){
        float m = srd[(pyw*3)*4 + x2*2];
        m = fmaxf(m, srd[(pyw*3)*4 + x2*2+1]);
        m = fmaxf(m, srd[(pyw*3+1)*4 + x2*2]);
        m = fmaxf(m, srd[(pyw*3+1)*4 + x2*2+1]);
        m = fmaxf(m, srd[(pyw*3+2)*4 + x2*2]);
        m = fmaxf(m, srd[(pyw*3+2)*4 + x2*2+1]);
        eo[x2] = m;
    }
}

// ---------------- FC1 + SELU + l2norm + QKV + PE, batched 4 samples/block.
// e written TRANSPOSED (et[j][s]) — consumed only by colpipe.
__global__ __launch_bounds__(512) void k_fcqkv(
    const float* __restrict__ e0, const float* __restrict__ wt,
    const float* __restrict__ bias, float* __restrict__ et,
    const float* __restrict__ wqt, const float* __restrict__ bq,
    const float* __restrict__ wkt, const float* __restrict__ bk,
    const float* __restrict__ wvt, const float* __restrict__ bv,
    float* __restrict__ q, float* __restrict__ kp, float* __restrict__ v)
{
    int s0 = blockIdx.x*4, tid = threadIdx.x;
    int j = tid & 127, q4 = tid >> 7;
    __shared__ float se[4][1024];
    __shared__ float sp[4][4][128];
    __shared__ float sredn[4][2];
    __shared__ float se2[4][128];
    __shared__ float sp3[3][4][4][128];
    for(int i=tid;i<4096;i+=512){
        int sl = i >> 10, ii = i & 1023;
        se[sl][ii] = e0[(size_t)(s0+sl)*1024 + ii];
    }
    __syncthreads();
    float acc[4] = {0.f,0.f,0.f,0.f};
    const float* wp = wt + (size_t)q4*256*128 + j;
    const int ibase = q4*256;
    #pragma unroll 4
    for(int i=0;i<256;i++){
        float w = wp[(size_t)i*128];
        #pragma unroll
        for(int sl=0;sl<4;sl++) acc[sl] = fmaf(se[sl][ibase+i], w, acc[sl]);
    }
    #pragma unroll
    for(int sl=0;sl<4;sl++) sp[sl][q4][j] = acc[sl];
    __syncthreads();
    int sl2 = q4, lane = tid & 63, wv_ = tid >> 6;
    float vfc = selu_f(bias[j] + sp[sl2][0][j] + sp[sl2][1][j] + sp[sl2][2][j] + sp[sl2][3][j]);
    float a = vfc*vfc;
    #pragma unroll
    for(int o=1;o<64;o<<=1) a += __shfl_xor(a, o);
    if(lane==0) sredn[sl2][wv_&1] = a;
    __syncthreads();
    float den = fmaxf(sqrtf(sredn[sl2][0]+sredn[sl2][1]), 1e-12f);
    float ev = vfc/den;
    se2[sl2][j] = ev;
    et[(size_t)j*1024 + s0+sl2] = ev;
    __syncthreads();
    float aq[4]={0,0,0,0}, ak[4]={0,0,0,0}, av[4]={0,0,0,0};
    int i0b = q4*32;
    #pragma unroll 4
    for(int i=0;i<32;i++){
        float wqv = wqt[(i0b+i)*128 + j];
        float wkv = wkt[(i0b+i)*128 + j];
        float wvv = wvt[(i0b+i)*128 + j];
        #pragma unroll
        for(int sl=0;sl<4;sl++){
            float f = se2[sl][i0b+i];
            aq[sl] = fmaf(f, wqv, aq[sl]);
            ak[sl] = fmaf(f, wkv, ak[sl]);
            av[sl] = fmaf(f, wvv, av[sl]);
        }
    }
    #pragma unroll
    for(int sl=0;sl<4;sl++){
        sp3[0][sl][q4][j] = aq[sl];
        sp3[1][sl][q4][j] = ak[sl];
        sp3[2][sl][q4][j] = av[sl];
    }
    __syncthreads();
    float vq = selu_f(bq[j] + sp3[0][sl2][0][j]+sp3[0][sl2][1][j]+sp3[0][sl2][2][j]+sp3[0][sl2][3][j]);
    float vk = selu_f(bk[j] + sp3[1][sl2][0][j]+sp3[1][sl2][1][j]+sp3[1][sl2][2][j]+sp3[1][sl2][3][j]);
    float vv = selu_f(bv[j] + sp3[2][sl2][0][j]+sp3[2][sl2][1][j]+sp3[2][sl2][2][j]+sp3[2][sl2][3][j]);
    int i2 = j & ~1;
    float dv = __expf(-(float)i2 * 0.07195578412155481f);
    float ang = (float)(s0+sl2) * dv;
    float pe = (j & 1) ? cosf(ang) : sinf(ang);
    q[(size_t)(s0+sl2)*128+j]  = vq;
    kp[(size_t)(s0+sl2)*128+j] = vk + pe;
    v[(size_t)(s0+sl2)*128+j]  = vv;
}

// ---------------- fused attention, batched 4 samples/block; av written transposed
__global__ __launch_bounds__(512) void k_attnav(
    const float* __restrict__ q, const float* __restrict__ kp,
    const float* __restrict__ v, float* __restrict__ avt)
{
    int s0 = blockIdx.x*4, tid = threadIdx.x;
    __shared__ float4 sq4[4][32];
    __shared__ float p[4][1024];
    __shared__ float spart[4][4][128];
    __shared__ float smx[4][2], ssm[4][2];
    ((float*)sq4)[tid] = q[(size_t)s0*128 + tid];
    __syncthreads();
    #pragma unroll
    for(int h=0;h<2;h++){
        int t = tid + h*512;
        const float4* kr = (const float4*)(kp + (size_t)t*128);
        float d[4] = {0.f,0.f,0.f,0.f};
        #pragma unroll 4
        for(int i=0;i<32;i++){
            float4 kv = kr[i];
            #pragma unroll
            for(int sl=0;sl<4;sl++){
                float4 qv = sq4[sl][i];
                d[sl] += kv.x*qv.x + kv.y*qv.y + kv.z*qv.z + kv.w*qv.w;
            }
        }
        #pragma unroll
        for(int sl=0;sl<4;sl++) p[sl][t] = d[sl]*0.08838834764831845f;
    }
    __syncthreads();
    int sl2 = tid>>7, t2 = tid&127, lane = tid&63, wv_ = tid>>6;
    float vals[8];
    float m = -INFINITY;
    #pragma unroll
    for(int k=0;k<8;k++){ vals[k] = p[sl2][t2 + k*128]; m = fmaxf(m, vals[k]); }
    #pragma unroll
    for(int o=1;o<64;o<<=1) m = fmaxf(m, __shfl_xor(m,o));
    if(lane==0) smx[sl2][wv_&1] = m;
    __syncthreads();
    m = fmaxf(smx[sl2][0], smx[sl2][1]);
    float lsum = 0.f;
    #pragma unroll
    for(int k=0;k<8;k++){ vals[k] = __expf(vals[k]-m); lsum += vals[k]; }
    #pragma unroll
    for(int o=1;o<64;o<<=1) lsum += __shfl_xor(lsum,o);
    if(lane==0) ssm[sl2][wv_&1] = lsum;
    __syncthreads();
    float invs = 1.f/(ssm[sl2][0]+ssm[sl2][1]);
    #pragma unroll
    for(int k=0;k<8;k++) p[sl2][t2+k*128] = vals[k]*invs;
    __syncthreads();
    int j = tid & 127, q4 = tid >> 7;
    float acc[4] = {0,0,0,0};
    int t0 = q4*256;
    #pragma unroll 2
    for(int t=t0;t<t0+256;t++){
        float vv = v[(size_t)t*128 + j];
        #pragma unroll
        for(int sl=0;sl<4;sl++) acc[sl] = fmaf(p[sl][t], vv, acc[sl]);
    }
    #pragma unroll
    for(int sl=0;sl<4;sl++) spart[sl][q4][j] = acc[sl];
    __syncthreads();
    avt[(size_t)j*1024 + s0+sl2] = spart[sl2][0][j]+spart[sl2][1][j]+spart[sl2][2][j]+spart[sl2][3][j];
}

// ---------------- column pipeline on TRANSPOSED inputs (coalesced loads)
__global__ __launch_bounds__(1024) void k_colpipe(
    const float* __restrict__ avt, const float* __restrict__ et, float* __restrict__ ea)
{
    int j = blockIdx.x, t = threadIdx.x;
    __shared__ float sred[16];
    int lane = t & 63, w = t >> 6;
    float vv = avt[(size_t)j*1024 + t];
    float ss = vv*vv;
    #pragma unroll
    for(int off=1;off<64;off<<=1) ss += __shfl_xor(ss,off);
    if(lane==0) sred[w]=ss;
    __syncthreads();
    float tot = 0.f;
    #pragma unroll
    for(int i=0;i<16;i++) tot += sred[i];
    float n1 = fmaxf(sqrtf(tot), 1e-12f);
    __syncthreads();
    float o = vv/n1 + et[(size_t)j*1024 + t];
    float ss2 = o*o;
    #pragma unroll
    for(int off=1;off<64;off<<=1) ss2 += __shfl_xor(ss2,off);
    if(lane==0) sred[w]=ss2;
    __syncthreads();
    float tot2 = 0.f;
    #pragma unroll
    for(int i=0;i<16;i++) tot2 += sred[i];
    float n2 = fmaxf(sqrtf(tot2), 1e-12f);
    ea[(size_t)t*128 + j] = o/n2;
}

// ---------------- pairwise d2 (row norms from staged tiles) + global max
__global__ __launch_bounds__(256) void k_gram(
    const float* __restrict__ ea,
    float* __restrict__ d2, unsigned int* __restrict__ maxbits)
{
    int j0 = blockIdx.x*32, i0 = blockIdx.y*32, tid = threadIdx.x;
    __shared__ float sa[32*128];
    __shared__ float sb[32*128];
    __shared__ float sredm[32];
    __shared__ float sqa[32], sqb[32];
    for(int idx=tid;idx<4096;idx+=256){
        sa[idx] = ea[(size_t)i0*128 + idx];
        sb[idx] = ea[(size_t)j0*128 + idx];
    }
    __syncthreads();
    {
        int r = tid>>3, seg = tid&7;
        const float* A = sa + r*128 + seg*16;
        const float* B = sb + r*128 + seg*16;
        float pa=0.f, pb=0.f;
        #pragma unroll
        for(int i=0;i<16;i++){ pa = fmaf(A[i],A[i],pa); pb = fmaf(B[i],B[i],pb); }
        #pragma unroll
        for(int o=1;o<8;o<<=1){ pa += __shfl_xor(pa,o); pb += __shfl_xor(pb,o); }
        if(seg==0){ sqa[r]=pa; sqb[r]=pb; }
    }
    __syncthreads();
    float lm = 0.f;
    #pragma unroll
    for(int k2=0;k2<4;k2++){
        int pp = tid + k2*256;
        int li = pp>>5, lj = pp&31;
        const float4* A = (const float4*)(sa + li*128);
        const float4* B = (const float4*)(sb + lj*128);
        float acc=0.f;
        #pragma unroll 8
        for(int i=0;i<32;i++){
            float4 a=A[i], b=B[i];
            acc += a.x*b.x + a.y*b.y + a.z*b.z + a.w*b.w;
        }
        float dd = fmaxf(sqa[li] + sqb[lj] - 2.f*acc, 0.f);
        d2[(size_t)(i0+li)*1024 + j0+lj] = dd;
        lm = fmaxf(lm, dd);
    }
    lm = warp_max(lm);
    __syncthreads();
    if((tid&63)==0) sredm[tid>>6]=lm;
    __syncthreads();
    if(tid==0){
        float mm = fmaxf(fmaxf(sredm[0],sredm[1]),fmaxf(sredm[2],sredm[3]));
        atomicMax(maxbits, __float_as_uint(mm));
    }
}

// ---------------- out = 1 - sqrt(d2+eps)/maxd
__global__ __launch_bounds__(256) void k_final(
    const float* __restrict__ d2, const unsigned int* __restrict__ maxbits, float* __restrict__ out)
{
    int idx = blockIdx.x*256 + threadIdx.x;
    float md = sqrtf(__uint_as_float(*maxbits) + 1e-12f);
    out[idx] = 1.f - sqrtf(d2[idx] + 1e-12f)/md;
}

extern "C" void kernel_launch(void* const* d_in, const int* in_sizes, int n_in,
                              void* d_out, int out_size, void* d_ws, size_t ws_size,
                              hipStream_t stream)
{
    const float* x   = (const float*)d_in[0];
    const float* c1w = (const float*)d_in[1];  const float* c1b = (const float*)d_in[2];
    const float* g1g = (const float*)d_in[3];  const float* g1b = (const float*)d_in[4];
    const float* c2w = (const float*)d_in[5];  const float* c2b = (const float*)d_in[6];
    const float* g2g = (const float*)d_in[7];  const float* g2b = (const float*)d_in[8];
    const float* c3w = (const float*)d_in[9];  const float* c3b = (const float*)d_in[10];
    const float* g3g = (const float*)d_in[11]; const float* g3b = (const float*)d_in[12];
    const float* f1w = (const float*)d_in[13]; const float* f1b = (const float*)d_in[14];
    const float* wq  = (const float*)d_in[15]; const float* bq  = (const float*)d_in[16];
    const float* wk  = (const float*)d_in[17]; const float* bk  = (const float*)d_in[18];
    const float* wv  = (const float*)d_in[19]; const float* bv  = (const float*)d_in[20];

    float* W = (float*)d_ws;
    float* e0   = W;                          // 1,048,576
    float* eab  = W + 2228224;                //   131,072
    float* d2b  = W + 2359296;                // 1,048,576
    unsigned short* buf1 = (unsigned short*)(W + 4194304);  // 18,874,368 bf16 (9,437,184 floats)
    float* wt   = W + 13631488;               //   131,072
    float* wqt  = W + 13762560;
    float* wkt  = W + 13778944;
    float* wvt  = W + 13795328;
    float* et   = W + 13811712;               //   131,072 (transposed e)
    float* qb   = W + 13942784;
    float* kpb  = W + 14073856;
    float* vb   = W + 14204928;
    float* avt  = W + 14336000;               //   131,072 (transposed av)
    unsigned int* maxb = (unsigned int*)(W + 14467072);
    short* w2bf = (short*)(W + 14467088);     // 49,152 bf16
    short* w3bf = (short*)(W + 14491664);     // 196,608 bf16
    short* w1bf = (short*)(W + 14589968);     // 1,024 bf16

    k_prep<<<1670,256,0,stream>>>(f1w, wq, wk, wv, c1w, c2w, c3w,
                                  wt, wqt, wkt, wvt, w1bf, w2bf, w3bf);

    k_conv1m<<<1024,1024,0,stream>>>(x, w1bf, c1b, g1g, g1b, buf1);
    k_conv23<<<1024,512,0,stream>>>(buf1, w2bf, c2b, g2g, g2b,
                                    w3bf, c3b, g3g, g3b, e0);

    k_fcqkv<<<256,512,0,stream>>>(e0, wt, f1b, et, wqt,bq, wkt,bk, wvt,bv, qb,kpb,vb);
    k_attnav<<<256,512,0,stream>>>(qb, kpb, vb, avt);

    hipMemsetAsync(maxb, 0, 4, stream);
    k_colpipe<<<128,1024,0,stream>>>(avt, et, eab);
    k_gram<<<dim3(32,32),256,0,stream>>>(eab, d2b, maxb);
    k_final<<<4096,256,0,stream>>>(d2b, maxb, (float*)d_out);
}